// Round 2
// baseline (345.801 us; speedup 1.0000x reference)
//
#include <hip/hip_runtime.h>
#include <hip/hip_bf16.h>

typedef __bf16 bf16_t;
typedef __bf16 bf16x8 __attribute__((ext_vector_type(8)));
typedef float f32x4 __attribute__((ext_vector_type(4)));
typedef float f32x8v __attribute__((ext_vector_type(8)));

#define B_    2
#define T_    2048
#define C_    1024
#define H_    16
#define D_    64
#define M_    4096      // B*T
#define NQKV_ 3072
#define BKP   72        // 64 + 8 pad: 144B row stride -> ~conflict-free b128 frag reads

static __device__ __forceinline__ float  bf2f(bf16_t x) { return (float)x; }
static __device__ __forceinline__ bf16_t f2bf(float x)  { return (bf16_t)x; }

// ---------------- RoPE cos/sin table: [T][32] float2 ----------------
__global__ __launch_bounds__(256) void rope_tab_k(float2* __restrict__ tab) {
  int i = blockIdx.x * 256 + threadIdx.x;      // < T_*32
  int tpos = i >> 5, d = i & 31;
  float fr = exp2f(-(float)d * (13.287712379549449f / 32.0f));  // 10000^(-d/32)
  float ang = (float)tpos * fr;
  tab[i] = make_float2(cosf(ang), sinf(ang));
}

// ---------------- transpose + fp32->bf16 (in: R x Ccols fp32 -> out: Ccols x R bf16) ----
__global__ __launch_bounds__(256) void transpose_f32_bf16(const float* __restrict__ in,
                                                          bf16_t* __restrict__ out,
                                                          int R, int Ccols) {
  __shared__ bf16_t tile[32][33];
  int tx = threadIdx.x & 31, ty = threadIdx.x >> 5;
  int c0 = blockIdx.x * 32, r0 = blockIdx.y * 32;
#pragma unroll
  for (int j = 0; j < 4; ++j)
    tile[ty + j * 8][tx] = f2bf(in[(size_t)(r0 + ty + j * 8) * Ccols + c0 + tx]);
  __syncthreads();
#pragma unroll
  for (int j = 0; j < 4; ++j)
    out[(size_t)(c0 + ty + j * 8) * R + r0 + tx] = tile[tx][ty + j * 8];
}

// ------- shared 128x128 MFMA GEMM core (A: MxK rowmaj fp32|bf16, Bt: NxK rowmaj bf16) ----
template <typename AT>
__device__ __forceinline__ void gemm_core(const AT* __restrict__ A,
                                          const bf16_t* __restrict__ Bt,
                                          int m0, int n0,
                                          bf16_t* lA, bf16_t* lB,
                                          f32x4 acc[4][4]) {
  const int t    = threadIdx.x;
  const int lane = t & 63, w = t >> 6;
  const int wr = (w >> 1) * 64, wc = (w & 1) * 64;
  const int l15 = lane & 15, g4 = lane >> 4;

  const f32x4 z4 = {0.f, 0.f, 0.f, 0.f};
#pragma unroll
  for (int i = 0; i < 4; ++i)
#pragma unroll
    for (int j = 0; j < 4; ++j) acc[i][j] = z4;

  const int srow = t >> 3;          // + 32*j
  const int scol = (t & 7) * 8;

  f32x8v fa[4];       // fp32-A path
  uint4  ha[4];       // bf16-A path
  uint4  rb[4];
#pragma unroll
  for (int j = 0; j < 4; ++j) {
    if constexpr (sizeof(AT) == 4)
      fa[j] = *(const f32x8v*)(A + (size_t)(m0 + srow + 32 * j) * C_ + scol);
    else
      ha[j] = *(const uint4*)(A + (size_t)(m0 + srow + 32 * j) * C_ + scol);
    rb[j] = *(const uint4*)(Bt + (size_t)(n0 + srow + 32 * j) * C_ + scol);
  }

  for (int kt = 0; kt < C_ / 64; ++kt) {
    __syncthreads();
#pragma unroll
    for (int j = 0; j < 4; ++j) {
      if constexpr (sizeof(AT) == 4) {
        bf16x8 h;
#pragma unroll
        for (int i = 0; i < 8; ++i) h[i] = f2bf(fa[j][i]);
        *(bf16x8*)&lA[(srow + 32 * j) * BKP + scol] = h;
      } else {
        *(uint4*)&lA[(srow + 32 * j) * BKP + scol] = ha[j];
      }
      *(uint4*)&lB[(srow + 32 * j) * BKP + scol] = rb[j];
    }
    __syncthreads();
    if (kt + 1 < C_ / 64) {
      const int k0 = (kt + 1) * 64;
#pragma unroll
      for (int j = 0; j < 4; ++j) {
        if constexpr (sizeof(AT) == 4)
          fa[j] = *(const f32x8v*)(A + (size_t)(m0 + srow + 32 * j) * C_ + k0 + scol);
        else
          ha[j] = *(const uint4*)(A + (size_t)(m0 + srow + 32 * j) * C_ + k0 + scol);
        rb[j] = *(const uint4*)(Bt + (size_t)(n0 + srow + 32 * j) * C_ + k0 + scol);
      }
    }
#pragma unroll
    for (int ks = 0; ks < 2; ++ks) {
      bf16x8 af[4], bfv[4];
#pragma unroll
      for (int mi = 0; mi < 4; ++mi)
        af[mi] = *(const bf16x8*)&lA[(wr + mi * 16 + l15) * BKP + ks * 32 + g4 * 8];
#pragma unroll
      for (int ni = 0; ni < 4; ++ni)
        bfv[ni] = *(const bf16x8*)&lB[(wc + ni * 16 + l15) * BKP + ks * 32 + g4 * 8];
#pragma unroll
      for (int mi = 0; mi < 4; ++mi)
#pragma unroll
        for (int ni = 0; ni < 4; ++ni)
          acc[mi][ni] = __builtin_amdgcn_mfma_f32_16x16x32_bf16(af[mi], bfv[ni],
                                                                acc[mi][ni], 0, 0, 0);
    }
  }
}

// ---------------- GEMM1: qkv = x @ w_attn + b_attn, fused RoPE, split to q/k/v ----------
__global__ __launch_bounds__(256) void qkv_gemm(const float* __restrict__ x,
                                                const bf16_t* __restrict__ wT,
                                                const float* __restrict__ bias,
                                                const float2* __restrict__ rtab,
                                                bf16_t* __restrict__ qo,
                                                bf16_t* __restrict__ ko,
                                                bf16_t* __restrict__ vo) {
  __shared__ __align__(16) bf16_t lA[128 * BKP];
  __shared__ __align__(16) bf16_t lB[128 * BKP];
  f32x4 acc[4][4];
  const int m0 = blockIdx.x * 128, n0 = blockIdx.y * 128;
  gemm_core<float>(x, wT, m0, n0, lA, lB, acc);

  const int t = threadIdx.x;
  const int lane = t & 63, w = t >> 6;
  const int wr = (w >> 1) * 64, wc = (w & 1) * 64;
  const int l15 = lane & 15, g4 = lane >> 4;
  const int ng  = n0 + wc;              // 64-aligned -> single (sel, head) per wave
  const int sel = ng >> 10;
  const int h   = (ng & 1023) >> 6;

  if (sel < 2) {
    bf16_t* outp = (sel == 0) ? qo : ko;
    const float qs = (sel == 0) ? 0.125f : 1.0f;   // D^-0.5 folded into q
#pragma unroll
    for (int mi = 0; mi < 4; ++mi) {
      const int rowb = m0 + wr + mi * 16 + g4 * 4;
#pragma unroll
      for (int ni = 0; ni < 2; ++ni) {
        const int d1 = ni * 16 + l15;        // 0..31; partner is d1+32 (frag ni+2)
        const float b1 = bias[ng + d1];
        const float b2 = bias[ng + d1 + 32];
#pragma unroll
        for (int r = 0; r < 4; ++r) {
          const int row  = rowb + r;
          const int tpos = row & (T_ - 1);
          const int bb   = row >> 11;
          const float2 cs = rtab[tpos * 32 + d1];
          const float x1 = acc[mi][ni][r]     + b1;
          const float x2 = acc[mi][ni + 2][r] + b2;
          const float o1 = (x1 * cs.x - x2 * cs.y) * qs;
          const float o2 = (x1 * cs.y + x2 * cs.x) * qs;
          const size_t base = ((size_t)(bb * H_ + h) * T_ + tpos) * D_;
          outp[base + d1]      = f2bf(o1);
          outp[base + d1 + 32] = f2bf(o2);
        }
      }
    }
  } else {
#pragma unroll
    for (int mi = 0; mi < 4; ++mi) {
      const int rowb = m0 + wr + mi * 16 + g4 * 4;
#pragma unroll
      for (int ni = 0; ni < 4; ++ni) {
        const int d = ni * 16 + l15;
        const float b1 = bias[ng + d];
#pragma unroll
        for (int r = 0; r < 4; ++r) {
          const int row  = rowb + r;
          const int tpos = row & (T_ - 1);
          const int bb   = row >> 11;
          const size_t base = ((size_t)(bb * H_ + h) * T_ + tpos) * D_;
          vo[base + d] = f2bf(acc[mi][ni][r] + b1);
        }
      }
    }
  }
}

// ---------------- flash attention: block = 64 q-rows (4 waves x 16), KBLK=32 ----------
__global__ __launch_bounds__(256) void attn_fwd(const bf16_t* __restrict__ q,
                                                const bf16_t* __restrict__ k,
                                                const bf16_t* __restrict__ v,
                                                bf16_t* __restrict__ y) {
  __shared__ __align__(16) bf16_t Ks[32 * BKP];
  __shared__ __align__(16) bf16_t Vt[64 * 40];       // V transposed [d][kk], kk XOR-swizzled
  __shared__ __align__(16) bf16_t Pl[4][16 * 40];
  const int t = threadIdx.x;
  const int lane = t & 63, w = t >> 6;
  const int l15 = lane & 15, g4 = lane >> 4;
  const int qb = blockIdx.x * 64;
  const int bh = blockIdx.y;
  const size_t hb = (size_t)bh * T_ * D_;

  const int qrow = qb + w * 16 + l15;
  bf16x8 qf[2];
  qf[0] = *(const bf16x8*)(q + hb + (size_t)qrow * D_ + g4 * 8);
  qf[1] = *(const bf16x8*)(q + hb + (size_t)qrow * D_ + 32 + g4 * 8);

  const f32x4 z4 = {0.f, 0.f, 0.f, 0.f};
  f32x4 o[4];
#pragma unroll
  for (int i = 0; i < 4; ++i) o[i] = z4;
  float mx[4] = {-1e30f, -1e30f, -1e30f, -1e30f};
  float L[4]  = {0.f, 0.f, 0.f, 0.f};

  const int skk  = t >> 3;
  const int sd0  = (t & 7) * 8;
  const int kswz = skk ^ ((t & 3) << 3);   // swizzle kk bits 3..4 by (d>>3)&3
  const int rowb = qb + w * 16 + g4 * 4;

  const int ntiles = (qb >> 5) + 2;
  for (int it = 0; it < ntiles; ++it) {
    const int kb = it * 32;
    uint4 kvv = *(const uint4*)(k + hb + (size_t)(kb + skk) * D_ + sd0);
    uint4 vvv = *(const uint4*)(v + hb + (size_t)(kb + skk) * D_ + sd0);
    __syncthreads();
    *(uint4*)&Ks[skk * BKP + sd0] = kvv;
    const bf16_t* vb = (const bf16_t*)&vvv;
#pragma unroll
    for (int i = 0; i < 8; ++i)
      Vt[(sd0 + i) * 40 + kswz] = vb[i];
    __syncthreads();

    f32x4 s0 = z4, s1 = z4;
#pragma unroll
    for (int ks = 0; ks < 2; ++ks) {
      bf16x8 kf0 = *(const bf16x8*)&Ks[l15 * BKP        + ks * 32 + g4 * 8];
      bf16x8 kf1 = *(const bf16x8*)&Ks[(16 + l15) * BKP + ks * 32 + g4 * 8];
      s0 = __builtin_amdgcn_mfma_f32_16x16x32_bf16(qf[ks], kf0, s0, 0, 0, 0);
      s1 = __builtin_amdgcn_mfma_f32_16x16x32_bf16(qf[ks], kf1, s1, 0, 0, 0);
    }

    const int key0 = kb + l15, key1 = key0 + 16;
#pragma unroll
    for (int r = 0; r < 4; ++r) {
      if (key0 > rowb + r) s0[r] = -1e30f;
      if (key1 > rowb + r) s1[r] = -1e30f;
    }

#pragma unroll
    for (int r = 0; r < 4; ++r) {
      float tm = fmaxf(s0[r], s1[r]);
      tm = fmaxf(tm, __shfl_xor(tm, 1));
      tm = fmaxf(tm, __shfl_xor(tm, 2));
      tm = fmaxf(tm, __shfl_xor(tm, 4));
      tm = fmaxf(tm, __shfl_xor(tm, 8));
      const float mn = fmaxf(mx[r], tm);
      const float e0 = expf(s0[r] - mn);
      const float e1 = expf(s1[r] - mn);
      float rs = e0 + e1;
      rs += __shfl_xor(rs, 1);
      rs += __shfl_xor(rs, 2);
      rs += __shfl_xor(rs, 4);
      rs += __shfl_xor(rs, 8);
      const float sc = expf(mx[r] - mn);
      L[r] = L[r] * sc + rs;
      mx[r] = mn;
#pragma unroll
      for (int nf = 0; nf < 4; ++nf) o[nf][r] *= sc;
      Pl[w][(g4 * 4 + r) * 40 + l15]      = f2bf(e0);
      Pl[w][(g4 * 4 + r) * 40 + 16 + l15] = f2bf(e1);
    }

    bf16x8 ap = *(const bf16x8*)&Pl[w][l15 * 40 + g4 * 8];
#pragma unroll
    for (int nf = 0; nf < 4; ++nf) {
      const int d = nf * 16 + l15;
      const int vswz = (g4 * 8) ^ (((d >> 3) & 3) << 3);
      bf16x8 vf = *(const bf16x8*)&Vt[d * 40 + vswz];
      o[nf] = __builtin_amdgcn_mfma_f32_16x16x32_bf16(ap, vf, o[nf], 0, 0, 0);
    }
  }

  const int bb = bh / H_, hh = bh % H_;
#pragma unroll
  for (int nf = 0; nf < 4; ++nf)
#pragma unroll
    for (int r = 0; r < 4; ++r) {
      const int row = rowb + r;
      const float val = o[nf][r] / L[r];
      y[(size_t)(bb * T_ + row) * C_ + hh * D_ + nf * 16 + l15] = f2bf(val);
    }
}

// ---------------- GEMM2: out = y @ w_proj + b_proj (fp32 out) ----------------
__global__ __launch_bounds__(256) void proj_gemm(const bf16_t* __restrict__ yin,
                                                 const bf16_t* __restrict__ wT,
                                                 const float* __restrict__ bias,
                                                 float* __restrict__ out) {
  __shared__ __align__(16) bf16_t lA[128 * BKP];
  __shared__ __align__(16) bf16_t lB[128 * BKP];
  f32x4 acc[4][4];
  const int m0 = blockIdx.x * 128, n0 = blockIdx.y * 128;
  gemm_core<bf16_t>(yin, wT, m0, n0, lA, lB, acc);

  const int t = threadIdx.x;
  const int lane = t & 63, w = t >> 6;
  const int wr = (w >> 1) * 64, wc = (w & 1) * 64;
  const int l15 = lane & 15, g4 = lane >> 4;
  const int ng = n0 + wc;
#pragma unroll
  for (int mi = 0; mi < 4; ++mi) {
    const int rowb = m0 + wr + mi * 16 + g4 * 4;
#pragma unroll
    for (int ni = 0; ni < 4; ++ni) {
      const int n = ng + ni * 16 + l15;
      const float b1 = bias[n];
#pragma unroll
      for (int r = 0; r < 4; ++r)
        out[(size_t)(rowb + r) * C_ + n] = acc[mi][ni][r] + b1;
    }
  }
}

// ---------------- launch ----------------
extern "C" void kernel_launch(void* const* d_in, const int* in_sizes, int n_in,
                              void* d_out, int out_size, void* d_ws, size_t ws_size,
                              hipStream_t stream) {
  (void)in_sizes; (void)n_in; (void)out_size; (void)ws_size;
  const float* x      = (const float*)d_in[0];
  const float* w_attn = (const float*)d_in[1];
  const float* b_attn = (const float*)d_in[2];
  const float* w_proj = (const float*)d_in[3];
  const float* b_proj = (const float*)d_in[4];
  float* out = (float*)d_out;

  char* ws = (char*)d_ws;
  bf16_t* wTa = (bf16_t*)ws;  ws += (size_t)NQKV_ * C_ * 2;          // 6 MB
  bf16_t* wTp = (bf16_t*)ws;  ws += (size_t)C_ * C_ * 2;             // 2 MB
  bf16_t* qb  = (bf16_t*)ws;  ws += (size_t)B_ * H_ * T_ * D_ * 2;   // 8 MB
  bf16_t* kb  = (bf16_t*)ws;  ws += (size_t)B_ * H_ * T_ * D_ * 2;   // 8 MB
  bf16_t* vb  = (bf16_t*)ws;  ws += (size_t)B_ * H_ * T_ * D_ * 2;   // 8 MB
  bf16_t* yb  = (bf16_t*)ws;  ws += (size_t)B_ * T_ * C_ * 2;        // 8 MB
  float2* rtab = (float2*)ws; ws += (size_t)T_ * 32 * sizeof(float2);// 0.5 MB

  rope_tab_k<<<dim3(T_ * 32 / 256), 256, 0, stream>>>(rtab);
  transpose_f32_bf16<<<dim3(NQKV_ / 32, C_ / 32), 256, 0, stream>>>(w_attn, wTa, C_, NQKV_);
  transpose_f32_bf16<<<dim3(C_ / 32,   C_ / 32), 256, 0, stream>>>(w_proj, wTp, C_, C_);
  qkv_gemm<<<dim3(M_ / 128, NQKV_ / 128), 256, 0, stream>>>(x, wTa, b_attn, rtab, qb, kb, vb);
  attn_fwd<<<dim3(T_ / 64, B_ * H_), 256, 0, stream>>>(qb, kb, vb, yb);
  proj_gemm<<<dim3(M_ / 128, C_ / 128), 256, 0, stream>>>(yb, wTp, b_proj, out);
}

// Round 5
// 255.733 us; speedup vs baseline: 1.3522x; 1.3522x over previous
//
#include <hip/hip_runtime.h>
#include <hip/hip_bf16.h>

typedef __bf16 bf16_t;
typedef __bf16 bf16x8 __attribute__((ext_vector_type(8)));
typedef float f32x4 __attribute__((ext_vector_type(4)));
typedef float f32x8v __attribute__((ext_vector_type(8)));

#define B_    2
#define T_    2048
#define C_    1024
#define H_    16
#define D_    64
#define M_    4096      // B*T
#define NQKV_ 3072
#define BKP   72        // 64 + 8 pad
#define PLD   72        // attn LDS row stride
#define NQT   32        // T_/64 q-tiles

static __device__ __forceinline__ float  bf2f(bf16_t x) { return (float)x; }
static __device__ __forceinline__ bf16_t f2bf(float x)  { return (bf16_t)x; }

// ---------------- RoPE cos/sin table: [T][32] float2 ----------------
__global__ __launch_bounds__(256) void rope_tab_k(float2* __restrict__ tab) {
  int i = blockIdx.x * 256 + threadIdx.x;      // < T_*32
  int tpos = i >> 5, d = i & 31;
  float fr = exp2f(-(float)d * (13.287712379549449f / 32.0f));  // 10000^(-d/32)
  float ang = (float)tpos * fr;
  tab[i] = make_float2(cosf(ang), sinf(ang));
}

// ---------------- transpose + fp32->bf16 (in: R x Ccols fp32 -> out: Ccols x R bf16) ----
__global__ __launch_bounds__(256) void transpose_f32_bf16(const float* __restrict__ in,
                                                          bf16_t* __restrict__ out,
                                                          int R, int Ccols) {
  __shared__ bf16_t tile[32][33];
  int tx = threadIdx.x & 31, ty = threadIdx.x >> 5;
  int c0 = blockIdx.x * 32, r0 = blockIdx.y * 32;
#pragma unroll
  for (int j = 0; j < 4; ++j)
    tile[ty + j * 8][tx] = f2bf(in[(size_t)(r0 + ty + j * 8) * Ccols + c0 + tx]);
  __syncthreads();
#pragma unroll
  for (int j = 0; j < 4; ++j)
    out[(size_t)(c0 + ty + j * 8) * R + r0 + tx] = tile[tx][ty + j * 8];
}

// ------- shared 128x128 MFMA GEMM core (A: MxK rowmaj fp32|bf16, Bt: NxK rowmaj bf16) ----
template <typename AT>
__device__ __forceinline__ void gemm_core(const AT* __restrict__ A,
                                          const bf16_t* __restrict__ Bt,
                                          int m0, int n0,
                                          bf16_t* lA, bf16_t* lB,
                                          f32x4 acc[4][4]) {
  const int t    = threadIdx.x;
  const int lane = t & 63, w = t >> 6;
  const int wr = (w >> 1) * 64, wc = (w & 1) * 64;
  const int l15 = lane & 15, g4 = lane >> 4;

  const f32x4 z4 = {0.f, 0.f, 0.f, 0.f};
#pragma unroll
  for (int i = 0; i < 4; ++i)
#pragma unroll
    for (int j = 0; j < 4; ++j) acc[i][j] = z4;

  const int srow = t >> 3;          // + 32*j
  const int scol = (t & 7) * 8;

  f32x8v fa[4];       // fp32-A path
  uint4  ha[4];       // bf16-A path
  uint4  rb[4];
#pragma unroll
  for (int j = 0; j < 4; ++j) {
    if constexpr (sizeof(AT) == 4)
      fa[j] = *(const f32x8v*)(A + (size_t)(m0 + srow + 32 * j) * C_ + scol);
    else
      ha[j] = *(const uint4*)(A + (size_t)(m0 + srow + 32 * j) * C_ + scol);
    rb[j] = *(const uint4*)(Bt + (size_t)(n0 + srow + 32 * j) * C_ + scol);
  }

  for (int kt = 0; kt < C_ / 64; ++kt) {
    __syncthreads();
#pragma unroll
    for (int j = 0; j < 4; ++j) {
      if constexpr (sizeof(AT) == 4) {
        bf16x8 h;
#pragma unroll
        for (int i = 0; i < 8; ++i) h[i] = f2bf(fa[j][i]);
        *(bf16x8*)&lA[(srow + 32 * j) * BKP + scol] = h;
      } else {
        *(uint4*)&lA[(srow + 32 * j) * BKP + scol] = ha[j];
      }
      *(uint4*)&lB[(srow + 32 * j) * BKP + scol] = rb[j];
    }
    __syncthreads();
    if (kt + 1 < C_ / 64) {
      const int k0 = (kt + 1) * 64;
#pragma unroll
      for (int j = 0; j < 4; ++j) {
        if constexpr (sizeof(AT) == 4)
          fa[j] = *(const f32x8v*)(A + (size_t)(m0 + srow + 32 * j) * C_ + k0 + scol);
        else
          ha[j] = *(const uint4*)(A + (size_t)(m0 + srow + 32 * j) * C_ + k0 + scol);
        rb[j] = *(const uint4*)(Bt + (size_t)(n0 + srow + 32 * j) * C_ + k0 + scol);
      }
    }
#pragma unroll
    for (int ks = 0; ks < 2; ++ks) {
      bf16x8 af[4], bfv[4];
#pragma unroll
      for (int mi = 0; mi < 4; ++mi)
        af[mi] = *(const bf16x8*)&lA[(wr + mi * 16 + l15) * BKP + ks * 32 + g4 * 8];
#pragma unroll
      for (int ni = 0; ni < 4; ++ni)
        bfv[ni] = *(const bf16x8*)&lB[(wc + ni * 16 + l15) * BKP + ks * 32 + g4 * 8];
#pragma unroll
      for (int mi = 0; mi < 4; ++mi)
#pragma unroll
        for (int ni = 0; ni < 4; ++ni)
          acc[mi][ni] = __builtin_amdgcn_mfma_f32_16x16x32_bf16(af[mi], bfv[ni],
                                                                acc[mi][ni], 0, 0, 0);
    }
  }
}

// ---------------- GEMM1: qkv = x @ w_attn + b_attn, fused RoPE, split to q/k/v ----------
__global__ __launch_bounds__(256) void qkv_gemm(const float* __restrict__ x,
                                                const bf16_t* __restrict__ wT,
                                                const float* __restrict__ bias,
                                                const float2* __restrict__ rtab,
                                                bf16_t* __restrict__ qo,
                                                bf16_t* __restrict__ ko,
                                                bf16_t* __restrict__ vo) {
  __shared__ __align__(16) bf16_t lA[128 * BKP];
  __shared__ __align__(16) bf16_t lB[128 * BKP];
  f32x4 acc[4][4];
  const int m0 = blockIdx.x * 128, n0 = blockIdx.y * 128;
  gemm_core<float>(x, wT, m0, n0, lA, lB, acc);

  const int t = threadIdx.x;
  const int lane = t & 63, w = t >> 6;
  const int wr = (w >> 1) * 64, wc = (w & 1) * 64;
  const int l15 = lane & 15, g4 = lane >> 4;
  const int ng  = n0 + wc;              // 64-aligned -> single (sel, head) per wave
  const int sel = ng >> 10;
  const int h   = (ng & 1023) >> 6;

  if (sel < 2) {
    bf16_t* outp = (sel == 0) ? qo : ko;
    const float qs = (sel == 0) ? 0.125f : 1.0f;   // D^-0.5 folded into q
#pragma unroll
    for (int mi = 0; mi < 4; ++mi) {
      const int rowb = m0 + wr + mi * 16 + g4 * 4;
#pragma unroll
      for (int ni = 0; ni < 2; ++ni) {
        const int d1 = ni * 16 + l15;        // 0..31; partner is d1+32 (frag ni+2)
        const float b1 = bias[ng + d1];
        const float b2 = bias[ng + d1 + 32];
#pragma unroll
        for (int r = 0; r < 4; ++r) {
          const int row  = rowb + r;
          const int tpos = row & (T_ - 1);
          const int bb   = row >> 11;
          const float2 cs = rtab[tpos * 32 + d1];
          const float x1 = acc[mi][ni][r]     + b1;
          const float x2 = acc[mi][ni + 2][r] + b2;
          const float o1 = (x1 * cs.x - x2 * cs.y) * qs;
          const float o2 = (x1 * cs.y + x2 * cs.x) * qs;
          const size_t base = ((size_t)(bb * H_ + h) * T_ + tpos) * D_;
          outp[base + d1]      = f2bf(o1);
          outp[base + d1 + 32] = f2bf(o2);
        }
      }
    }
  } else {
#pragma unroll
    for (int mi = 0; mi < 4; ++mi) {
      const int rowb = m0 + wr + mi * 16 + g4 * 4;
#pragma unroll
      for (int ni = 0; ni < 4; ++ni) {
        const int d = ni * 16 + l15;
        const float b1 = bias[ng + d];
#pragma unroll
        for (int r = 0; r < 4; ++r) {
          const int row  = rowb + r;
          const int tpos = row & (T_ - 1);
          const int bb   = row >> 11;
          const size_t base = ((size_t)(bb * H_ + h) * T_ + tpos) * D_;
          vo[base + d] = f2bf(acc[mi][ni][r] + b1);
        }
      }
    }
  }
}

// ---- flash attention: 64 q-rows (4 waves x 16), KBLK=64, balanced grid ----
__global__ __launch_bounds__(256) void attn_fwd(const bf16_t* __restrict__ q,
                                                const bf16_t* __restrict__ k,
                                                const bf16_t* __restrict__ v,
                                                bf16_t* __restrict__ y) {
  __shared__ __align__(16) bf16_t Ks[64 * BKP];        // K rows [key][d]
  __shared__ __align__(16) bf16_t Vt[64 * PLD];        // V^T [d][key ^ swz]
  __shared__ __align__(16) bf16_t Pl[4][16 * PLD];     // per-wave P [qrow][key]
  const int t = threadIdx.x;
  const int lane = t & 63, w = t >> 6;
  const int l15 = lane & 15, g4 = lane >> 4;

  // causal load-balance pairing: consecutive g pairs (qt, NQT-1-qt)
  const int f  = blockIdx.x;
  const int bh = f & 31;
  const int g  = f >> 5;
  const int qt = (g & 1) ? (NQT - 1 - (g >> 1)) : (g >> 1);
  const int qb = qt * 64;
  const size_t hb = (size_t)bh * T_ * D_;

  const int qrow = qb + w * 16 + l15;
  bf16x8 qf[2];
  qf[0] = *(const bf16x8*)(q + hb + (size_t)qrow * D_ + g4 * 8);
  qf[1] = *(const bf16x8*)(q + hb + (size_t)qrow * D_ + 32 + g4 * 8);

  const f32x4 z4 = {0.f, 0.f, 0.f, 0.f};
  f32x4 o[4];
#pragma unroll
  for (int i = 0; i < 4; ++i) o[i] = z4;
  float mx[4] = {-1e30f, -1e30f, -1e30f, -1e30f};
  float L[4]  = {0.f, 0.f, 0.f, 0.f};

  const int skk  = t >> 3;                 // 0..31 (+32 second pass)
  const int sd0  = (t & 7) * 8;
  const int swzs = (t & 3) << 3;           // V write swizzle = ((sd0>>3)&3)<<3
  const int rowb = qb + w * 16 + g4 * 4;

  const int ntiles = qt + 1;

  // preload tile 0
  uint4 kv0 = *(const uint4*)(k + hb + (size_t)skk * D_ + sd0);
  uint4 kv1 = *(const uint4*)(k + hb + (size_t)(skk + 32) * D_ + sd0);
  uint4 vv0 = *(const uint4*)(v + hb + (size_t)skk * D_ + sd0);
  uint4 vv1 = *(const uint4*)(v + hb + (size_t)(skk + 32) * D_ + sd0);

  for (int it = 0; it < ntiles; ++it) {
    const int kb = it * 64;
    __syncthreads();
    *(uint4*)&Ks[skk * BKP + sd0]        = kv0;
    *(uint4*)&Ks[(skk + 32) * BKP + sd0] = kv1;
    {
      const bf16_t* vb0 = (const bf16_t*)&vv0;
      const bf16_t* vb1 = (const bf16_t*)&vv1;
#pragma unroll
      for (int i = 0; i < 8; ++i) {
        Vt[(sd0 + i) * PLD + (skk ^ swzs)]        = vb0[i];
        Vt[(sd0 + i) * PLD + ((skk + 32) ^ swzs)] = vb1[i];
      }
    }
    __syncthreads();

    if (it + 1 < ntiles) {
      // FIX vs round 3/4: include the per-thread key row (skk) in the prefetch address
      const size_t nb = hb + (size_t)(kb + 64 + skk) * D_ + sd0;
      kv0 = *(const uint4*)(k + nb);
      kv1 = *(const uint4*)(k + nb + 32 * D_);
      vv0 = *(const uint4*)(v + nb);
      vv1 = *(const uint4*)(v + nb + 32 * D_);
    }

    // ---- QK^T: S[q=g4*4+r][key=kb+c*16+l15] ----
    f32x4 s[4];
#pragma unroll
    for (int c = 0; c < 4; ++c) s[c] = z4;
#pragma unroll
    for (int ks = 0; ks < 2; ++ks)
#pragma unroll
      for (int c = 0; c < 4; ++c) {
        bf16x8 kf = *(const bf16x8*)&Ks[(c * 16 + l15) * BKP + ks * 32 + g4 * 8];
        s[c] = __builtin_amdgcn_mfma_f32_16x16x32_bf16(qf[ks], kf, s[c], 0, 0, 0);
      }

    // ---- causal mask: every tile (round-2 known-good semantics) ----
#pragma unroll
    for (int c = 0; c < 4; ++c) {
      const int key = kb + c * 16 + l15;
#pragma unroll
      for (int r = 0; r < 4; ++r)
        if (key > rowb + r) s[c][r] = -1e30f;
    }

    // ---- online softmax (expf, unconditional rescale — round-2 numerics) ----
#pragma unroll
    for (int r = 0; r < 4; ++r) {
      float tm = fmaxf(fmaxf(s[0][r], s[1][r]), fmaxf(s[2][r], s[3][r]));
      tm = fmaxf(tm, __shfl_xor(tm, 1));
      tm = fmaxf(tm, __shfl_xor(tm, 2));
      tm = fmaxf(tm, __shfl_xor(tm, 4));
      tm = fmaxf(tm, __shfl_xor(tm, 8));
      const float mn = fmaxf(mx[r], tm);
      const float e0 = expf(s[0][r] - mn);
      const float e1 = expf(s[1][r] - mn);
      const float e2 = expf(s[2][r] - mn);
      const float e3 = expf(s[3][r] - mn);
      float rs = (e0 + e1) + (e2 + e3);
      rs += __shfl_xor(rs, 1);
      rs += __shfl_xor(rs, 2);
      rs += __shfl_xor(rs, 4);
      rs += __shfl_xor(rs, 8);
      const float sc = expf(mx[r] - mn);
      L[r] = L[r] * sc + rs;
      mx[r] = mn;
#pragma unroll
      for (int nf = 0; nf < 4; ++nf) o[nf][r] *= sc;
      const int prow = (g4 * 4 + r) * PLD;
      Pl[w][prow + l15]      = f2bf(e0);
      Pl[w][prow + 16 + l15] = f2bf(e1);
      Pl[w][prow + 32 + l15] = f2bf(e2);
      Pl[w][prow + 48 + l15] = f2bf(e3);
    }

    // ---- PV: o[q][d] += P[q][key] V[key][d] ----
    bf16x8 ap0 = *(const bf16x8*)&Pl[w][l15 * PLD + g4 * 8];
    bf16x8 ap1 = *(const bf16x8*)&Pl[w][l15 * PLD + 32 + g4 * 8];
#pragma unroll
    for (int nf = 0; nf < 4; ++nf) {
      const int d = nf * 16 + l15;
      const int vswz = ((d >> 3) & 3) << 3;
      bf16x8 vf0 = *(const bf16x8*)&Vt[d * PLD + ((g4 * 8) ^ vswz)];
      bf16x8 vf1 = *(const bf16x8*)&Vt[d * PLD + (32 + ((g4 * 8) ^ vswz))];
      o[nf] = __builtin_amdgcn_mfma_f32_16x16x32_bf16(ap0, vf0, o[nf], 0, 0, 0);
      o[nf] = __builtin_amdgcn_mfma_f32_16x16x32_bf16(ap1, vf1, o[nf], 0, 0, 0);
    }
  }

  const int bb = bh / H_, hh = bh % H_;
  float il[4];
#pragma unroll
  for (int r = 0; r < 4; ++r) il[r] = 1.0f / L[r];
#pragma unroll
  for (int nf = 0; nf < 4; ++nf)
#pragma unroll
    for (int r = 0; r < 4; ++r) {
      const int row = rowb + r;
      y[(size_t)(bb * T_ + row) * C_ + hh * D_ + nf * 16 + l15] = f2bf(o[nf][r] * il[r]);
    }
}

// ---------------- GEMM2: out = y @ w_proj + b_proj (fp32 out) ----------------
__global__ __launch_bounds__(256) void proj_gemm(const bf16_t* __restrict__ yin,
                                                 const bf16_t* __restrict__ wT,
                                                 const float* __restrict__ bias,
                                                 float* __restrict__ out) {
  __shared__ __align__(16) bf16_t lA[128 * BKP];
  __shared__ __align__(16) bf16_t lB[128 * BKP];
  f32x4 acc[4][4];
  const int m0 = blockIdx.x * 128, n0 = blockIdx.y * 128;
  gemm_core<bf16_t>(yin, wT, m0, n0, lA, lB, acc);

  const int t = threadIdx.x;
  const int lane = t & 63, w = t >> 6;
  const int wr = (w >> 1) * 64, wc = (w & 1) * 64;
  const int l15 = lane & 15, g4 = lane >> 4;
  const int ng = n0 + wc;
#pragma unroll
  for (int mi = 0; mi < 4; ++mi) {
    const int rowb = m0 + wr + mi * 16 + g4 * 4;
#pragma unroll
    for (int ni = 0; ni < 4; ++ni) {
      const int n = ng + ni * 16 + l15;
      const float b1 = bias[n];
#pragma unroll
      for (int r = 0; r < 4; ++r)
        out[(size_t)(rowb + r) * C_ + n] = acc[mi][ni][r] + b1;
    }
  }
}

// ---------------- launch ----------------
extern "C" void kernel_launch(void* const* d_in, const int* in_sizes, int n_in,
                              void* d_out, int out_size, void* d_ws, size_t ws_size,
                              hipStream_t stream) {
  (void)in_sizes; (void)n_in; (void)out_size; (void)ws_size;
  const float* x      = (const float*)d_in[0];
  const float* w_attn = (const float*)d_in[1];
  const float* b_attn = (const float*)d_in[2];
  const float* w_proj = (const float*)d_in[3];
  const float* b_proj = (const float*)d_in[4];
  float* out = (float*)d_out;

  char* ws = (char*)d_ws;
  bf16_t* wTa = (bf16_t*)ws;  ws += (size_t)NQKV_ * C_ * 2;          // 6 MB
  bf16_t* wTp = (bf16_t*)ws;  ws += (size_t)C_ * C_ * 2;             // 2 MB
  bf16_t* qb  = (bf16_t*)ws;  ws += (size_t)B_ * H_ * T_ * D_ * 2;   // 8 MB
  bf16_t* kb  = (bf16_t*)ws;  ws += (size_t)B_ * H_ * T_ * D_ * 2;   // 8 MB
  bf16_t* vb  = (bf16_t*)ws;  ws += (size_t)B_ * H_ * T_ * D_ * 2;   // 8 MB
  bf16_t* yb  = (bf16_t*)ws;  ws += (size_t)B_ * T_ * C_ * 2;        // 8 MB
  float2* rtab = (float2*)ws; ws += (size_t)T_ * 32 * sizeof(float2);// 0.5 MB

  rope_tab_k<<<dim3(T_ * 32 / 256), 256, 0, stream>>>(rtab);
  transpose_f32_bf16<<<dim3(NQKV_ / 32, C_ / 32), 256, 0, stream>>>(w_attn, wTa, C_, NQKV_);
  transpose_f32_bf16<<<dim3(C_ / 32,   C_ / 32), 256, 0, stream>>>(w_proj, wTp, C_, C_);
  qkv_gemm<<<dim3(M_ / 128, NQKV_ / 128), 256, 0, stream>>>(x, wTa, b_attn, rtab, qb, kb, vb);
  attn_fwd<<<dim3((T_ / 64) * 32), 256, 0, stream>>>(qb, kb, vb, yb);
  proj_gemm<<<dim3(M_ / 128, C_ / 128), 256, 0, stream>>>(yb, wTp, b_proj, out);
}

// Round 6
// 246.800 us; speedup vs baseline: 1.4011x; 1.0362x over previous
//
#include <hip/hip_runtime.h>
#include <hip/hip_bf16.h>

typedef __bf16 bf16_t;
typedef __bf16 bf16x8 __attribute__((ext_vector_type(8)));
typedef float f32x4 __attribute__((ext_vector_type(4)));
typedef float f32x8v __attribute__((ext_vector_type(8)));

#define B_    2
#define T_    2048
#define C_    1024
#define H_    16
#define D_    64
#define M_    4096      // B*T
#define NQKV_ 3072
#define BKP   72        // GEMM/K LDS row stride (64 + 8 pad)
#define PLD   72        // attn V^T LDS row stride
#define NQT   32        // T_/64 q-tiles

static __device__ __forceinline__ float  bf2f(bf16_t x) { return (float)x; }
static __device__ __forceinline__ bf16_t f2bf(float x)  { return (bf16_t)x; }

// ---------------- RoPE cos/sin table: [T][32] float2 ----------------
__global__ __launch_bounds__(256) void rope_tab_k(float2* __restrict__ tab) {
  int i = blockIdx.x * 256 + threadIdx.x;      // < T_*32
  int tpos = i >> 5, d = i & 31;
  float fr = exp2f(-(float)d * (13.287712379549449f / 32.0f));  // 10000^(-d/32)
  float ang = (float)tpos * fr;
  tab[i] = make_float2(cosf(ang), sinf(ang));
}

// ---------------- x: fp32 -> bf16 bulk convert ----------------
__global__ __launch_bounds__(256) void f32_to_bf16_k(const float* __restrict__ in,
                                                     bf16_t* __restrict__ out) {
  const int i = (blockIdx.x * 256 + threadIdx.x) * 8;
  f32x8v v = *(const f32x8v*)(in + i);
  bf16x8 h;
#pragma unroll
  for (int j = 0; j < 8; ++j) h[j] = f2bf(v[j]);
  *(bf16x8*)(out + i) = h;
}

// ---------------- transpose + fp32->bf16 (in: R x Ccols fp32 -> out: Ccols x R bf16) ----
__global__ __launch_bounds__(256) void transpose_f32_bf16(const float* __restrict__ in,
                                                          bf16_t* __restrict__ out,
                                                          int R, int Ccols) {
  __shared__ bf16_t tile[32][33];
  int tx = threadIdx.x & 31, ty = threadIdx.x >> 5;
  int c0 = blockIdx.x * 32, r0 = blockIdx.y * 32;
#pragma unroll
  for (int j = 0; j < 4; ++j)
    tile[ty + j * 8][tx] = f2bf(in[(size_t)(r0 + ty + j * 8) * Ccols + c0 + tx]);
  __syncthreads();
#pragma unroll
  for (int j = 0; j < 4; ++j)
    out[(size_t)(c0 + ty + j * 8) * R + r0 + tx] = tile[tx][ty + j * 8];
}

// ------- shared 128x128 MFMA GEMM core (A: MxK rowmaj bf16, Bt: NxK rowmaj bf16) ----
__device__ __forceinline__ void gemm_core(const bf16_t* __restrict__ A,
                                          const bf16_t* __restrict__ Bt,
                                          int m0, int n0,
                                          bf16_t* lA, bf16_t* lB,
                                          f32x4 acc[4][4]) {
  const int t    = threadIdx.x;
  const int lane = t & 63, w = t >> 6;
  const int wr = (w >> 1) * 64, wc = (w & 1) * 64;
  const int l15 = lane & 15, g4 = lane >> 4;

  const f32x4 z4 = {0.f, 0.f, 0.f, 0.f};
#pragma unroll
  for (int i = 0; i < 4; ++i)
#pragma unroll
    for (int j = 0; j < 4; ++j) acc[i][j] = z4;

  const int srow = t >> 3;          // + 32*j
  const int scol = (t & 7) * 8;

  uint4 ha[4], rb[4];
#pragma unroll
  for (int j = 0; j < 4; ++j) {
    ha[j] = *(const uint4*)(A  + (size_t)(m0 + srow + 32 * j) * C_ + scol);
    rb[j] = *(const uint4*)(Bt + (size_t)(n0 + srow + 32 * j) * C_ + scol);
  }

  for (int kt = 0; kt < C_ / 64; ++kt) {
    __syncthreads();
#pragma unroll
    for (int j = 0; j < 4; ++j) {
      *(uint4*)&lA[(srow + 32 * j) * BKP + scol] = ha[j];
      *(uint4*)&lB[(srow + 32 * j) * BKP + scol] = rb[j];
    }
    __syncthreads();
    if (kt + 1 < C_ / 64) {
      const int k0 = (kt + 1) * 64;
#pragma unroll
      for (int j = 0; j < 4; ++j) {
        ha[j] = *(const uint4*)(A  + (size_t)(m0 + srow + 32 * j) * C_ + k0 + scol);
        rb[j] = *(const uint4*)(Bt + (size_t)(n0 + srow + 32 * j) * C_ + k0 + scol);
      }
    }
#pragma unroll
    for (int ks = 0; ks < 2; ++ks) {
      bf16x8 af[4], bfv[4];
#pragma unroll
      for (int mi = 0; mi < 4; ++mi)
        af[mi] = *(const bf16x8*)&lA[(wr + mi * 16 + l15) * BKP + ks * 32 + g4 * 8];
#pragma unroll
      for (int ni = 0; ni < 4; ++ni)
        bfv[ni] = *(const bf16x8*)&lB[(wc + ni * 16 + l15) * BKP + ks * 32 + g4 * 8];
#pragma unroll
      for (int mi = 0; mi < 4; ++mi)
#pragma unroll
        for (int ni = 0; ni < 4; ++ni)
          acc[mi][ni] = __builtin_amdgcn_mfma_f32_16x16x32_bf16(af[mi], bfv[ni],
                                                                acc[mi][ni], 0, 0, 0);
    }
  }
}

// ---------------- GEMM1: qkv = x @ w_attn + b_attn, fused RoPE, split to q/k/v ----------
__global__ __launch_bounds__(256) void qkv_gemm(const bf16_t* __restrict__ x,
                                                const bf16_t* __restrict__ wT,
                                                const float* __restrict__ bias,
                                                const float2* __restrict__ rtab,
                                                bf16_t* __restrict__ qo,
                                                bf16_t* __restrict__ ko,
                                                bf16_t* __restrict__ vo) {
  __shared__ __align__(16) bf16_t lA[128 * BKP];
  __shared__ __align__(16) bf16_t lB[128 * BKP];
  f32x4 acc[4][4];
  const int m0 = blockIdx.x * 128, n0 = blockIdx.y * 128;
  gemm_core(x, wT, m0, n0, lA, lB, acc);

  const int t = threadIdx.x;
  const int lane = t & 63, w = t >> 6;
  const int wr = (w >> 1) * 64, wc = (w & 1) * 64;
  const int l15 = lane & 15, g4 = lane >> 4;
  const int ng  = n0 + wc;              // 64-aligned -> single (sel, head) per wave
  const int sel = ng >> 10;
  const int h   = (ng & 1023) >> 6;

  if (sel < 2) {
    bf16_t* outp = (sel == 0) ? qo : ko;
    // q: fold D^-0.5 AND log2(e) (attn uses exp2f)
    const float qs = (sel == 0) ? 0.125f * 1.4426950408889634f : 1.0f;
#pragma unroll
    for (int mi = 0; mi < 4; ++mi) {
      const int rowb = m0 + wr + mi * 16 + g4 * 4;
#pragma unroll
      for (int ni = 0; ni < 2; ++ni) {
        const int d1 = ni * 16 + l15;        // 0..31; partner is d1+32 (frag ni+2)
        const float b1 = bias[ng + d1];
        const float b2 = bias[ng + d1 + 32];
#pragma unroll
        for (int r = 0; r < 4; ++r) {
          const int row  = rowb + r;
          const int tpos = row & (T_ - 1);
          const int bb   = row >> 11;
          const float2 cs = rtab[tpos * 32 + d1];
          const float x1 = acc[mi][ni][r]     + b1;
          const float x2 = acc[mi][ni + 2][r] + b2;
          const float o1 = (x1 * cs.x - x2 * cs.y) * qs;
          const float o2 = (x1 * cs.y + x2 * cs.x) * qs;
          const size_t base = ((size_t)(bb * H_ + h) * T_ + tpos) * D_;
          outp[base + d1]      = f2bf(o1);
          outp[base + d1 + 32] = f2bf(o2);
        }
      }
    }
  } else {
#pragma unroll
    for (int mi = 0; mi < 4; ++mi) {
      const int rowb = m0 + wr + mi * 16 + g4 * 4;
#pragma unroll
      for (int ni = 0; ni < 4; ++ni) {
        const int d = ni * 16 + l15;
        const float b1 = bias[ng + d];
#pragma unroll
        for (int r = 0; r < 4; ++r) {
          const int row  = rowb + r;
          const int tpos = row & (T_ - 1);
          const int bb   = row >> 11;
          const size_t base = ((size_t)(bb * H_ + h) * T_ + tpos) * D_;
          vo[base + d] = f2bf(acc[mi][ni][r] + b1);
        }
      }
    }
  }
}

// ---- flash attention, swapped-QK: 64 q-rows (4 waves x 16), KBLK=64, balanced grid ----
// S = mfma(K, Q): lane (g4,l15) holds S[key=kb+c*16+g4*4+r][q=qb+w*16+l15] -> q lane-local.
// PV key order is a free permutation: kappa(key=16c+4g+r) = 8g+4c+r, so each lane's
// softmax output IS its PV A-fragment (no P LDS round-trip). V^T staged at slot kappa,
// chunk XOR-spread by u=(d>>3)&7 for ~conflict-free scalar writes.
__global__ __launch_bounds__(256) void attn_fwd(const bf16_t* __restrict__ q,
                                                const bf16_t* __restrict__ k,
                                                const bf16_t* __restrict__ v,
                                                bf16_t* __restrict__ y) {
  __shared__ __align__(16) bf16_t Ks[64 * BKP];        // K rows [key][d]
  __shared__ __align__(16) bf16_t Vt[64 * PLD];        // V^T [d][slot(kappa,d)]
  const int t = threadIdx.x;
  const int lane = t & 63, w = t >> 6;
  const int l15 = lane & 15, g4 = lane >> 4;

  // causal load-balance pairing: consecutive g pairs (qt, NQT-1-qt)
  const int f  = blockIdx.x;
  const int bh = f & 31;
  const int g  = f >> 5;
  const int qt = (g & 1) ? (NQT - 1 - (g >> 1)) : (g >> 1);
  const int qb = qt * 64;
  const size_t hb = (size_t)bh * T_ * D_;

  const int qrow = qb + w * 16 + l15;
  bf16x8 qf[2];
  qf[0] = *(const bf16x8*)(q + hb + (size_t)qrow * D_ + g4 * 8);
  qf[1] = *(const bf16x8*)(q + hb + (size_t)qrow * D_ + 32 + g4 * 8);

  const f32x4 z4 = {0.f, 0.f, 0.f, 0.f};
  f32x4 o[4];
#pragma unroll
  for (int i = 0; i < 4; ++i) o[i] = z4;
  float mx = -1e30f, L = 0.f;

  const int skk = t >> 3;                  // key row 0..31 (+32 second pass)
  const int sd0 = (t & 7) * 8;
  const int u   = t & 7;                   // = (d>>3)&7 for all this thread's d rows
  // kappa(key) = 8*((key>>2)&3) + 4*((key>>4)&1) + (key&3); chunk XOR u for bank spread
  const int kh   = ((skk >> 2) & 3) * 8 + ((skk >> 4) & 1) * 4 + (skk & 3);
  const int pos0 = (((kh >> 3) ^ u) << 3) | (kh & 7);
  const int pos1 = ((((kh >> 3) ^ 4) ^ u) << 3) | (kh & 7);
  const int rowb = qb + w * 16 + g4 * 4;

  const int ntiles = qt + 1;

  // preload tile 0
  uint4 kv0 = *(const uint4*)(k + hb + (size_t)skk * D_ + sd0);
  uint4 kv1 = *(const uint4*)(k + hb + (size_t)(skk + 32) * D_ + sd0);
  uint4 vv0 = *(const uint4*)(v + hb + (size_t)skk * D_ + sd0);
  uint4 vv1 = *(const uint4*)(v + hb + (size_t)(skk + 32) * D_ + sd0);

  for (int it = 0; it < ntiles; ++it) {
    const int kb = it * 64;
    __syncthreads();
    *(uint4*)&Ks[skk * BKP + sd0]        = kv0;
    *(uint4*)&Ks[(skk + 32) * BKP + sd0] = kv1;
    {
      const bf16_t* vb0 = (const bf16_t*)&vv0;
      const bf16_t* vb1 = (const bf16_t*)&vv1;
#pragma unroll
      for (int i = 0; i < 8; ++i) {
        const int d = sd0 + i;
        Vt[d * PLD + pos0] = vb0[i];
        Vt[d * PLD + pos1] = vb1[i];
      }
    }
    __syncthreads();

    if (it + 1 < ntiles) {
      const size_t nb = hb + (size_t)(kb + 64 + skk) * D_ + sd0;
      kv0 = *(const uint4*)(k + nb);
      kv1 = *(const uint4*)(k + nb + 32 * D_);
      vv0 = *(const uint4*)(v + nb);
      vv1 = *(const uint4*)(v + nb + 32 * D_);
    }

    // ---- QK^T swapped: s[c][r] = S[key=kb+c*16+g4*4+r][q=qrow] ----
    f32x4 s[4];
#pragma unroll
    for (int c = 0; c < 4; ++c) s[c] = z4;
#pragma unroll
    for (int ks = 0; ks < 2; ++ks)
#pragma unroll
      for (int c = 0; c < 4; ++c) {
        bf16x8 kf = *(const bf16x8*)&Ks[(c * 16 + l15) * BKP + ks * 32 + g4 * 8];
        s[c] = __builtin_amdgcn_mfma_f32_16x16x32_bf16(kf, qf[ks], s[c], 0, 0, 0);
      }

    // ---- causal mask: only the diagonal tile can violate (kb+63 < qb for it<last) ----
    if (it == ntiles - 1) {
#pragma unroll
      for (int c = 0; c < 4; ++c)
#pragma unroll
        for (int r = 0; r < 4; ++r)
          if (kb + c * 16 + g4 * 4 + r > qrow) s[c][r] = -1e30f;
    }

    // ---- online softmax (exp2 domain; all 16 values belong to q=qrow) ----
    float tm = -1e30f;
#pragma unroll
    for (int c = 0; c < 4; ++c)
#pragma unroll
      for (int r = 0; r < 4; ++r) tm = fmaxf(tm, s[c][r]);
    tm = fmaxf(tm, __shfl_xor(tm, 16));
    tm = fmaxf(tm, __shfl_xor(tm, 32));
    const float mn = fmaxf(mx, tm);
    float rs = 0.f;
#pragma unroll
    for (int c = 0; c < 4; ++c)
#pragma unroll
      for (int r = 0; r < 4; ++r) {
        s[c][r] = exp2f(s[c][r] - mn);
        rs += s[c][r];
      }
    rs += __shfl_xor(rs, 16);
    rs += __shfl_xor(rs, 32);
    const float sc = exp2f(mx - mn);
    L = L * sc + rs;
    mx = mn;

    // o rescale: o[nf][r] is q=g4*4+r -> pull sc from lane with l15=g4*4+r
    float scr[4];
#pragma unroll
    for (int r = 0; r < 4; ++r)
      scr[r] = __shfl(sc, (lane & 48) | (g4 * 4 + r));
#pragma unroll
    for (int nf = 0; nf < 4; ++nf)
#pragma unroll
      for (int r = 0; r < 4; ++r) o[nf][r] *= scr[r];

    // ---- P -> PV A-fragments, in-lane (kappa ordering) ----
    bf16x8 ap0, ap1;
#pragma unroll
    for (int r = 0; r < 4; ++r) {
      ap0[r]     = f2bf(s[0][r]);
      ap0[4 + r] = f2bf(s[1][r]);
      ap1[r]     = f2bf(s[2][r]);
      ap1[4 + r] = f2bf(s[3][r]);
    }

    // ---- PV: o[q][d] += P V, keys in kappa order on both operands ----
#pragma unroll
    for (int nf = 0; nf < 4; ++nf) {
      const int d  = nf * 16 + l15;
      const int h3 = (2 * nf + (l15 >> 3)) & 7;   // (d>>3)&7
      bf16x8 vf0 = *(const bf16x8*)&Vt[d * PLD + ((g4 ^ h3) << 3)];
      bf16x8 vf1 = *(const bf16x8*)&Vt[d * PLD + (((g4 + 4) ^ h3) << 3)];
      o[nf] = __builtin_amdgcn_mfma_f32_16x16x32_bf16(ap0, vf0, o[nf], 0, 0, 0);
      o[nf] = __builtin_amdgcn_mfma_f32_16x16x32_bf16(ap1, vf1, o[nf], 0, 0, 0);
    }
  }

  const int bb = bh / H_, hh = bh % H_;
  float il[4];
#pragma unroll
  for (int r = 0; r < 4; ++r)
    il[r] = 1.0f / __shfl(L, (lane & 48) | (g4 * 4 + r));
#pragma unroll
  for (int nf = 0; nf < 4; ++nf)
#pragma unroll
    for (int r = 0; r < 4; ++r) {
      const int row = rowb + r;
      y[(size_t)(bb * T_ + row) * C_ + hh * D_ + nf * 16 + l15] = f2bf(o[nf][r] * il[r]);
    }
}

// ---------------- GEMM2: out = y @ w_proj + b_proj (fp32 out) ----------------
__global__ __launch_bounds__(256) void proj_gemm(const bf16_t* __restrict__ yin,
                                                 const bf16_t* __restrict__ wT,
                                                 const float* __restrict__ bias,
                                                 float* __restrict__ out) {
  __shared__ __align__(16) bf16_t lA[128 * BKP];
  __shared__ __align__(16) bf16_t lB[128 * BKP];
  f32x4 acc[4][4];
  const int m0 = blockIdx.x * 128, n0 = blockIdx.y * 128;
  gemm_core(yin, wT, m0, n0, lA, lB, acc);

  const int t = threadIdx.x;
  const int lane = t & 63, w = t >> 6;
  const int wr = (w >> 1) * 64, wc = (w & 1) * 64;
  const int l15 = lane & 15, g4 = lane >> 4;
  const int ng = n0 + wc;
#pragma unroll
  for (int mi = 0; mi < 4; ++mi) {
    const int rowb = m0 + wr + mi * 16 + g4 * 4;
#pragma unroll
    for (int ni = 0; ni < 4; ++ni) {
      const int n = ng + ni * 16 + l15;
      const float b1 = bias[n];
#pragma unroll
      for (int r = 0; r < 4; ++r)
        out[(size_t)(rowb + r) * C_ + n] = acc[mi][ni][r] + b1;
    }
  }
}

// ---------------- launch ----------------
extern "C" void kernel_launch(void* const* d_in, const int* in_sizes, int n_in,
                              void* d_out, int out_size, void* d_ws, size_t ws_size,
                              hipStream_t stream) {
  (void)in_sizes; (void)n_in; (void)out_size; (void)ws_size;
  const float* x      = (const float*)d_in[0];
  const float* w_attn = (const float*)d_in[1];
  const float* b_attn = (const float*)d_in[2];
  const float* w_proj = (const float*)d_in[3];
  const float* b_proj = (const float*)d_in[4];
  float* out = (float*)d_out;

  char* ws = (char*)d_ws;
  bf16_t* wTa = (bf16_t*)ws;  ws += (size_t)NQKV_ * C_ * 2;          // 6 MB
  bf16_t* wTp = (bf16_t*)ws;  ws += (size_t)C_ * C_ * 2;             // 2 MB
  bf16_t* qb  = (bf16_t*)ws;  ws += (size_t)B_ * H_ * T_ * D_ * 2;   // 8 MB
  bf16_t* kb  = (bf16_t*)ws;  ws += (size_t)B_ * H_ * T_ * D_ * 2;   // 8 MB
  bf16_t* vb  = (bf16_t*)ws;  ws += (size_t)B_ * H_ * T_ * D_ * 2;   // 8 MB
  bf16_t* yb  = (bf16_t*)ws;  ws += (size_t)B_ * T_ * C_ * 2;        // 8 MB
  float2* rtab = (float2*)ws; ws += (size_t)T_ * 32 * sizeof(float2);// 0.5 MB
  // x_bf aliases yb: x_bf is consumed by qkv_gemm (dispatch 4) strictly before
  // attn_fwd (dispatch 5) writes yb. Stream-ordered, deterministic.
  bf16_t* x_bf = yb;

  rope_tab_k<<<dim3(T_ * 32 / 256), 256, 0, stream>>>(rtab);
  transpose_f32_bf16<<<dim3(NQKV_ / 32, C_ / 32), 256, 0, stream>>>(w_attn, wTa, C_, NQKV_);
  transpose_f32_bf16<<<dim3(C_ / 32,   C_ / 32), 256, 0, stream>>>(w_proj, wTp, C_, C_);
  f32_to_bf16_k<<<dim3(M_ * C_ / (256 * 8)), 256, 0, stream>>>(x, x_bf);
  qkv_gemm<<<dim3(M_ / 128, NQKV_ / 128), 256, 0, stream>>>(x_bf, wTa, b_attn, rtab, qb, kb, vb);
  attn_fwd<<<dim3((T_ / 64) * 32), 256, 0, stream>>>(qb, kb, vb, yb);
  proj_gemm<<<dim3(M_ / 128, C_ / 128), 256, 0, stream>>>(yb, wTp, b_proj, out);
}

// Round 7
// 245.812 us; speedup vs baseline: 1.4068x; 1.0040x over previous
//
#include <hip/hip_runtime.h>
#include <hip/hip_bf16.h>

typedef __bf16 bf16_t;
typedef __bf16 bf16x8 __attribute__((ext_vector_type(8)));
typedef float f32x4 __attribute__((ext_vector_type(4)));
typedef float f32x8v __attribute__((ext_vector_type(8)));

#define B_    2
#define T_    2048
#define C_    1024
#define H_    16
#define D_    64
#define M_    4096      // B*T
#define NQKV_ 3072
#define BKP   72        // GEMM/K LDS row stride (64 + 8 pad)
#define PLD   72        // attn V^T LDS row stride
#define SLD   72        // qkv store-stage row stride (144B, 16B-aligned)
#define NQT   32        // T_/64 q-tiles

static __device__ __forceinline__ float  bf2f(bf16_t x) { return (float)x; }
static __device__ __forceinline__ bf16_t f2bf(float x)  { return (bf16_t)x; }

// ---------------- RoPE cos/sin table: [T][32] float2 ----------------
__global__ __launch_bounds__(256) void rope_tab_k(float2* __restrict__ tab) {
  int i = blockIdx.x * 256 + threadIdx.x;      // < T_*32
  int tpos = i >> 5, d = i & 31;
  float fr = exp2f(-(float)d * (13.287712379549449f / 32.0f));  // 10000^(-d/32)
  float ang = (float)tpos * fr;
  tab[i] = make_float2(cosf(ang), sinf(ang));
}

// ---------------- x: fp32 -> bf16 bulk convert ----------------
__global__ __launch_bounds__(256) void f32_to_bf16_k(const float* __restrict__ in,
                                                     bf16_t* __restrict__ out) {
  const int i = (blockIdx.x * 256 + threadIdx.x) * 8;
  f32x8v v = *(const f32x8v*)(in + i);
  bf16x8 h;
#pragma unroll
  for (int j = 0; j < 8; ++j) h[j] = f2bf(v[j]);
  *(bf16x8*)(out + i) = h;
}

// ---------------- transpose + fp32->bf16 (in: R x Ccols fp32 -> out: Ccols x R bf16) ----
__global__ __launch_bounds__(256) void transpose_f32_bf16(const float* __restrict__ in,
                                                          bf16_t* __restrict__ out,
                                                          int R, int Ccols) {
  __shared__ bf16_t tile[32][33];
  int tx = threadIdx.x & 31, ty = threadIdx.x >> 5;
  int c0 = blockIdx.x * 32, r0 = blockIdx.y * 32;
#pragma unroll
  for (int j = 0; j < 4; ++j)
    tile[ty + j * 8][tx] = f2bf(in[(size_t)(r0 + ty + j * 8) * Ccols + c0 + tx]);
  __syncthreads();
#pragma unroll
  for (int j = 0; j < 4; ++j)
    out[(size_t)(c0 + ty + j * 8) * R + r0 + tx] = tile[tx][ty + j * 8];
}

// ------- shared 128x128 MFMA GEMM core (A: MxK rowmaj bf16, Bt: NxK rowmaj bf16) ----
__device__ __forceinline__ void gemm_core(const bf16_t* __restrict__ A,
                                          const bf16_t* __restrict__ Bt,
                                          int m0, int n0,
                                          bf16_t* lA, bf16_t* lB,
                                          f32x4 acc[4][4]) {
  const int t    = threadIdx.x;
  const int lane = t & 63, w = t >> 6;
  const int wr = (w >> 1) * 64, wc = (w & 1) * 64;
  const int l15 = lane & 15, g4 = lane >> 4;

  const f32x4 z4 = {0.f, 0.f, 0.f, 0.f};
#pragma unroll
  for (int i = 0; i < 4; ++i)
#pragma unroll
    for (int j = 0; j < 4; ++j) acc[i][j] = z4;

  const int srow = t >> 3;          // + 32*j
  const int scol = (t & 7) * 8;

  uint4 ha[4], rb[4];
#pragma unroll
  for (int j = 0; j < 4; ++j) {
    ha[j] = *(const uint4*)(A  + (size_t)(m0 + srow + 32 * j) * C_ + scol);
    rb[j] = *(const uint4*)(Bt + (size_t)(n0 + srow + 32 * j) * C_ + scol);
  }

  for (int kt = 0; kt < C_ / 64; ++kt) {
    __syncthreads();
#pragma unroll
    for (int j = 0; j < 4; ++j) {
      *(uint4*)&lA[(srow + 32 * j) * BKP + scol] = ha[j];
      *(uint4*)&lB[(srow + 32 * j) * BKP + scol] = rb[j];
    }
    __syncthreads();
    if (kt + 1 < C_ / 64) {
      const int k0 = (kt + 1) * 64;
#pragma unroll
      for (int j = 0; j < 4; ++j) {
        ha[j] = *(const uint4*)(A  + (size_t)(m0 + srow + 32 * j) * C_ + k0 + scol);
        rb[j] = *(const uint4*)(Bt + (size_t)(n0 + srow + 32 * j) * C_ + k0 + scol);
      }
    }
#pragma unroll
    for (int ks = 0; ks < 2; ++ks) {
      bf16x8 af[4], bfv[4];
#pragma unroll
      for (int mi = 0; mi < 4; ++mi)
        af[mi] = *(const bf16x8*)&lA[(wr + mi * 16 + l15) * BKP + ks * 32 + g4 * 8];
#pragma unroll
      for (int ni = 0; ni < 4; ++ni)
        bfv[ni] = *(const bf16x8*)&lB[(wc + ni * 16 + l15) * BKP + ks * 32 + g4 * 8];
#pragma unroll
      for (int mi = 0; mi < 4; ++mi)
#pragma unroll
        for (int ni = 0; ni < 4; ++ni)
          acc[mi][ni] = __builtin_amdgcn_mfma_f32_16x16x32_bf16(af[mi], bfv[ni],
                                                                acc[mi][ni], 0, 0, 0);
    }
  }
}

// ---------------- GEMM1: qkv = x @ w_attn + b_attn, fused RoPE, split to q/k/v ----------
// Epilogue stages bf16 results in LDS (reusing lA/lB) and emits fully-coalesced
// 1KB-per-instruction stores (8 consecutive tpos rows x 128B within one head plane),
// replacing 64 scalar 2B stores/lane that caused ~7.5x HBM write amplification (r6 PMC).
__global__ __launch_bounds__(256) void qkv_gemm(const bf16_t* __restrict__ x,
                                                const bf16_t* __restrict__ wT,
                                                const float* __restrict__ bias,
                                                const float2* __restrict__ rtab,
                                                bf16_t* __restrict__ qo,
                                                bf16_t* __restrict__ ko,
                                                bf16_t* __restrict__ vo) {
  __shared__ __align__(16) bf16_t smem[2 * 128 * BKP];   // lA|lB, reused as store stage
  f32x4 acc[4][4];
  const int m0 = blockIdx.x * 128, n0 = blockIdx.y * 128;
  gemm_core(x, wT, m0, n0, smem, smem + 128 * BKP, acc);

  const int t = threadIdx.x;
  const int lane = t & 63, w = t >> 6;
  const int wr = (w >> 1) * 64, wc = (w & 1) * 64;
  const int l15 = lane & 15, g4 = lane >> 4;
  const int ng  = n0 + wc;              // 64-aligned -> single (sel, head) per wave
  const int sel = ng >> 10;
  const int h   = (ng & 1023) >> 6;

  __syncthreads();                      // all waves done reading lA/lB
  bf16_t* stg = smem + w * (64 * SLD);  // per-wave 64x64 stage (disjoint regions)

  if (sel < 2) {
    // q: fold D^-0.5 AND log2(e) (attn uses exp2f)
    const float qs = (sel == 0) ? 0.125f * 1.4426950408889634f : 1.0f;
#pragma unroll
    for (int mi = 0; mi < 4; ++mi) {
#pragma unroll
      for (int ni = 0; ni < 2; ++ni) {
        const int d1 = ni * 16 + l15;        // 0..31; partner is d1+32 (frag ni+2)
        const float b1 = bias[ng + d1];
        const float b2 = bias[ng + d1 + 32];
#pragma unroll
        for (int r = 0; r < 4; ++r) {
          const int lrow = mi * 16 + g4 * 4 + r;
          const int tpos = (m0 + wr + lrow) & (T_ - 1);
          const float2 cs = rtab[tpos * 32 + d1];
          const float x1 = acc[mi][ni][r]     + b1;
          const float x2 = acc[mi][ni + 2][r] + b2;
          stg[lrow * SLD + d1]      = f2bf((x1 * cs.x - x2 * cs.y) * qs);
          stg[lrow * SLD + d1 + 32] = f2bf((x1 * cs.y + x2 * cs.x) * qs);
        }
      }
    }
  } else {
#pragma unroll
    for (int mi = 0; mi < 4; ++mi)
#pragma unroll
      for (int ni = 0; ni < 4; ++ni) {
        const int d = ni * 16 + l15;
        const float b1 = bias[ng + d];
#pragma unroll
        for (int r = 0; r < 4; ++r)
          stg[(mi * 16 + g4 * 4 + r) * SLD + d] = f2bf(acc[mi][ni][r] + b1);
      }
  }

  // readback own region (intra-wave dep only; compiler inserts lgkmcnt) + wide stores
  bf16_t* outp = (sel == 0) ? qo : (sel == 1 ? ko : vo);
  const int a  = lane >> 3;        // row-in-group 0..7
  const int b8 = (lane & 7) * 8;   // col chunk (x8 bf16 = 16B)
#pragma unroll
  for (int p = 0; p < 8; ++p) {
    const int lrow = p * 8 + a;
    const int row  = m0 + wr + lrow;
    const int tpos = row & (T_ - 1);
    const int bb   = row >> 11;
    uint4 val = *(const uint4*)&stg[lrow * SLD + b8];
    *(uint4*)(outp + ((size_t)(bb * H_ + h) * T_ + tpos) * D_ + b8) = val;
  }
}

// ---- flash attention, swapped-QK: 64 q-rows (4 waves x 16), KBLK=64, balanced grid ----
// S = mfma(K, Q): lane (g4,l15) holds S[key=kb+c*16+g4*4+r][q=qb+w*16+l15] -> q lane-local.
// PV key order is a free permutation: kappa(key=16c+4g+r) = 8g+4c+r, so each lane's
// softmax output IS its PV A-fragment (no P LDS round-trip). V^T staged at slot kappa,
// chunk XOR-spread by u=(d>>3)&7 for ~conflict-free scalar writes.
__global__ __launch_bounds__(256) void attn_fwd(const bf16_t* __restrict__ q,
                                                const bf16_t* __restrict__ k,
                                                const bf16_t* __restrict__ v,
                                                bf16_t* __restrict__ y) {
  __shared__ __align__(16) bf16_t Ks[64 * BKP];        // K rows [key][d]
  __shared__ __align__(16) bf16_t Vt[64 * PLD];        // V^T [d][slot(kappa,d)]
  const int t = threadIdx.x;
  const int lane = t & 63, w = t >> 6;
  const int l15 = lane & 15, g4 = lane >> 4;

  // causal load-balance pairing: consecutive g pairs (qt, NQT-1-qt)
  const int f  = blockIdx.x;
  const int bh = f & 31;
  const int g  = f >> 5;
  const int qt = (g & 1) ? (NQT - 1 - (g >> 1)) : (g >> 1);
  const int qb = qt * 64;
  const size_t hb = (size_t)bh * T_ * D_;

  const int qrow = qb + w * 16 + l15;
  bf16x8 qf[2];
  qf[0] = *(const bf16x8*)(q + hb + (size_t)qrow * D_ + g4 * 8);
  qf[1] = *(const bf16x8*)(q + hb + (size_t)qrow * D_ + 32 + g4 * 8);

  const f32x4 z4 = {0.f, 0.f, 0.f, 0.f};
  f32x4 o[4];
#pragma unroll
  for (int i = 0; i < 4; ++i) o[i] = z4;
  float mx = -1e30f, L = 0.f;

  const int skk = t >> 3;                  // key row 0..31 (+32 second pass)
  const int sd0 = (t & 7) * 8;
  const int u   = t & 7;                   // = (d>>3)&7 for all this thread's d rows
  // kappa(key) = 8*((key>>2)&3) + 4*((key>>4)&1) + (key&3); chunk XOR u for bank spread
  const int kh   = ((skk >> 2) & 3) * 8 + ((skk >> 4) & 1) * 4 + (skk & 3);
  const int pos0 = (((kh >> 3) ^ u) << 3) | (kh & 7);
  const int pos1 = ((((kh >> 3) ^ 4) ^ u) << 3) | (kh & 7);
  const int rowb = qb + w * 16 + g4 * 4;

  const int ntiles = qt + 1;

  // preload tile 0
  uint4 kv0 = *(const uint4*)(k + hb + (size_t)skk * D_ + sd0);
  uint4 kv1 = *(const uint4*)(k + hb + (size_t)(skk + 32) * D_ + sd0);
  uint4 vv0 = *(const uint4*)(v + hb + (size_t)skk * D_ + sd0);
  uint4 vv1 = *(const uint4*)(v + hb + (size_t)(skk + 32) * D_ + sd0);

  for (int it = 0; it < ntiles; ++it) {
    const int kb = it * 64;
    __syncthreads();
    *(uint4*)&Ks[skk * BKP + sd0]        = kv0;
    *(uint4*)&Ks[(skk + 32) * BKP + sd0] = kv1;
    {
      const bf16_t* vb0 = (const bf16_t*)&vv0;
      const bf16_t* vb1 = (const bf16_t*)&vv1;
#pragma unroll
      for (int i = 0; i < 8; ++i) {
        const int d = sd0 + i;
        Vt[d * PLD + pos0] = vb0[i];
        Vt[d * PLD + pos1] = vb1[i];
      }
    }
    __syncthreads();

    if (it + 1 < ntiles) {
      const size_t nb = hb + (size_t)(kb + 64 + skk) * D_ + sd0;
      kv0 = *(const uint4*)(k + nb);
      kv1 = *(const uint4*)(k + nb + 32 * D_);
      vv0 = *(const uint4*)(v + nb);
      vv1 = *(const uint4*)(v + nb + 32 * D_);
    }

    // ---- QK^T swapped: s[c][r] = S[key=kb+c*16+g4*4+r][q=qrow] ----
    f32x4 s[4];
#pragma unroll
    for (int c = 0; c < 4; ++c) s[c] = z4;
#pragma unroll
    for (int ks = 0; ks < 2; ++ks)
#pragma unroll
      for (int c = 0; c < 4; ++c) {
        bf16x8 kf = *(const bf16x8*)&Ks[(c * 16 + l15) * BKP + ks * 32 + g4 * 8];
        s[c] = __builtin_amdgcn_mfma_f32_16x16x32_bf16(kf, qf[ks], s[c], 0, 0, 0);
      }

    // ---- causal mask: only the diagonal tile can violate (kb+63 < qb for it<last) ----
    if (it == ntiles - 1) {
#pragma unroll
      for (int c = 0; c < 4; ++c)
#pragma unroll
        for (int r = 0; r < 4; ++r)
          if (kb + c * 16 + g4 * 4 + r > qrow) s[c][r] = -1e30f;
    }

    // ---- online softmax (exp2 domain; all 16 values belong to q=qrow) ----
    float tm = -1e30f;
#pragma unroll
    for (int c = 0; c < 4; ++c)
#pragma unroll
      for (int r = 0; r < 4; ++r) tm = fmaxf(tm, s[c][r]);
    tm = fmaxf(tm, __shfl_xor(tm, 16));
    tm = fmaxf(tm, __shfl_xor(tm, 32));
    const float mn = fmaxf(mx, tm);
    float rs = 0.f;
#pragma unroll
    for (int c = 0; c < 4; ++c)
#pragma unroll
      for (int r = 0; r < 4; ++r) {
        s[c][r] = exp2f(s[c][r] - mn);
        rs += s[c][r];
      }
    rs += __shfl_xor(rs, 16);
    rs += __shfl_xor(rs, 32);
    const float sc = exp2f(mx - mn);
    L = L * sc + rs;
    mx = mn;

    // o rescale: o[nf][r] is q=g4*4+r -> pull sc from lane with l15=g4*4+r
    float scr[4];
#pragma unroll
    for (int r = 0; r < 4; ++r)
      scr[r] = __shfl(sc, (lane & 48) | (g4 * 4 + r));
#pragma unroll
    for (int nf = 0; nf < 4; ++nf)
#pragma unroll
      for (int r = 0; r < 4; ++r) o[nf][r] *= scr[r];

    // ---- P -> PV A-fragments, in-lane (kappa ordering) ----
    bf16x8 ap0, ap1;
#pragma unroll
    for (int r = 0; r < 4; ++r) {
      ap0[r]     = f2bf(s[0][r]);
      ap0[4 + r] = f2bf(s[1][r]);
      ap1[r]     = f2bf(s[2][r]);
      ap1[4 + r] = f2bf(s[3][r]);
    }

    // ---- PV: o[q][d] += P V, keys in kappa order on both operands ----
#pragma unroll
    for (int nf = 0; nf < 4; ++nf) {
      const int d  = nf * 16 + l15;
      const int h3 = (2 * nf + (l15 >> 3)) & 7;   // (d>>3)&7
      bf16x8 vf0 = *(const bf16x8*)&Vt[d * PLD + ((g4 ^ h3) << 3)];
      bf16x8 vf1 = *(const bf16x8*)&Vt[d * PLD + (((g4 + 4) ^ h3) << 3)];
      o[nf] = __builtin_amdgcn_mfma_f32_16x16x32_bf16(ap0, vf0, o[nf], 0, 0, 0);
      o[nf] = __builtin_amdgcn_mfma_f32_16x16x32_bf16(ap1, vf1, o[nf], 0, 0, 0);
    }
  }

  const int bb = bh / H_, hh = bh % H_;
  float il[4];
#pragma unroll
  for (int r = 0; r < 4; ++r)
    il[r] = 1.0f / __shfl(L, (lane & 48) | (g4 * 4 + r));
#pragma unroll
  for (int nf = 0; nf < 4; ++nf)
#pragma unroll
    for (int r = 0; r < 4; ++r) {
      const int row = rowb + r;
      y[(size_t)(bb * T_ + row) * C_ + hh * D_ + nf * 16 + l15] = f2bf(o[nf][r] * il[r]);
    }
}

// ---------------- GEMM2: out = y @ w_proj + b_proj (fp32 out) ----------------
__global__ __launch_bounds__(256) void proj_gemm(const bf16_t* __restrict__ yin,
                                                 const bf16_t* __restrict__ wT,
                                                 const float* __restrict__ bias,
                                                 float* __restrict__ out) {
  __shared__ __align__(16) bf16_t lA[128 * BKP];
  __shared__ __align__(16) bf16_t lB[128 * BKP];
  f32x4 acc[4][4];
  const int m0 = blockIdx.x * 128, n0 = blockIdx.y * 128;
  gemm_core(yin, wT, m0, n0, lA, lB, acc);

  const int t = threadIdx.x;
  const int lane = t & 63, w = t >> 6;
  const int wr = (w >> 1) * 64, wc = (w & 1) * 64;
  const int l15 = lane & 15, g4 = lane >> 4;
  const int ng = n0 + wc;
#pragma unroll
  for (int mi = 0; mi < 4; ++mi) {
    const int rowb = m0 + wr + mi * 16 + g4 * 4;
#pragma unroll
    for (int ni = 0; ni < 4; ++ni) {
      const int n = ng + ni * 16 + l15;
      const float b1 = bias[n];
#pragma unroll
      for (int r = 0; r < 4; ++r)
        out[(size_t)(rowb + r) * C_ + n] = acc[mi][ni][r] + b1;
    }
  }
}

// ---------------- launch ----------------
extern "C" void kernel_launch(void* const* d_in, const int* in_sizes, int n_in,
                              void* d_out, int out_size, void* d_ws, size_t ws_size,
                              hipStream_t stream) {
  (void)in_sizes; (void)n_in; (void)out_size; (void)ws_size;
  const float* x      = (const float*)d_in[0];
  const float* w_attn = (const float*)d_in[1];
  const float* b_attn = (const float*)d_in[2];
  const float* w_proj = (const float*)d_in[3];
  const float* b_proj = (const float*)d_in[4];
  float* out = (float*)d_out;

  char* ws = (char*)d_ws;
  bf16_t* wTa = (bf16_t*)ws;  ws += (size_t)NQKV_ * C_ * 2;          // 6 MB
  bf16_t* wTp = (bf16_t*)ws;  ws += (size_t)C_ * C_ * 2;             // 2 MB
  bf16_t* qb  = (bf16_t*)ws;  ws += (size_t)B_ * H_ * T_ * D_ * 2;   // 8 MB
  bf16_t* kb  = (bf16_t*)ws;  ws += (size_t)B_ * H_ * T_ * D_ * 2;   // 8 MB
  bf16_t* vb  = (bf16_t*)ws;  ws += (size_t)B_ * H_ * T_ * D_ * 2;   // 8 MB
  bf16_t* yb  = (bf16_t*)ws;  ws += (size_t)B_ * T_ * C_ * 2;        // 8 MB
  float2* rtab = (float2*)ws; ws += (size_t)T_ * 32 * sizeof(float2);// 0.5 MB
  // x_bf aliases yb: x_bf is consumed by qkv_gemm (dispatch 4) strictly before
  // attn_fwd (dispatch 5) writes yb. Stream-ordered, deterministic.
  bf16_t* x_bf = yb;

  rope_tab_k<<<dim3(T_ * 32 / 256), 256, 0, stream>>>(rtab);
  transpose_f32_bf16<<<dim3(NQKV_ / 32, C_ / 32), 256, 0, stream>>>(w_attn, wTa, C_, NQKV_);
  transpose_f32_bf16<<<dim3(C_ / 32,   C_ / 32), 256, 0, stream>>>(w_proj, wTp, C_, C_);
  f32_to_bf16_k<<<dim3(M_ * C_ / (256 * 8)), 256, 0, stream>>>(x, x_bf);
  qkv_gemm<<<dim3(M_ / 128, NQKV_ / 128), 256, 0, stream>>>(x_bf, wTa, b_attn, rtab, qb, kb, vb);
  attn_fwd<<<dim3((T_ / 64) * 32), 256, 0, stream>>>(qb, kb, vb, yb);
  proj_gemm<<<dim3(M_ / 128, C_ / 128), 256, 0, stream>>>(yb, wTp, b_proj, out);
}

// Round 8
// 166.119 us; speedup vs baseline: 2.0816x; 1.4797x over previous
//
#include <hip/hip_runtime.h>
#include <hip/hip_bf16.h>

typedef __bf16 bf16_t;
typedef __bf16 bf16x8 __attribute__((ext_vector_type(8)));
typedef float f32x4 __attribute__((ext_vector_type(4)));
typedef float f32x8v __attribute__((ext_vector_type(8)));

#define B_    2
#define T_    2048
#define C_    1024
#define H_    16
#define D_    64
#define M_    4096      // B*T
#define NQKV_ 3072
#define BKP   72        // attn K LDS row stride (64 + 8 pad)
#define PLD   72        // attn V^T LDS row stride
#define NQT   32        // T_/64 q-tiles

static __device__ __forceinline__ float  bf2f(bf16_t x) { return (float)x; }
static __device__ __forceinline__ bf16_t f2bf(float x)  { return (bf16_t)x; }

// async global->LDS, 16B per lane; LDS dest is wave-uniform base + lane*16 (HW rule)
typedef const __attribute__((address_space(1))) void gas_void;
typedef __attribute__((address_space(3))) void las_void;
static __device__ __forceinline__ void gld16(const void* g, void* l) {
  __builtin_amdgcn_global_load_lds((gas_void*)g, (las_void*)l, 16, 0, 0);
}

// ---------------- RoPE cos/sin table: [T][32] float2 ----------------
__global__ __launch_bounds__(256) void rope_tab_k(float2* __restrict__ tab) {
  int i = blockIdx.x * 256 + threadIdx.x;      // < T_*32
  int tpos = i >> 5, d = i & 31;
  float fr = exp2f(-(float)d * (13.287712379549449f / 32.0f));  // 10000^(-d/32)
  float ang = (float)tpos * fr;
  tab[i] = make_float2(cosf(ang), sinf(ang));
}

// ---------------- x: fp32 -> bf16 bulk convert ----------------
__global__ __launch_bounds__(256) void f32_to_bf16_k(const float* __restrict__ in,
                                                     bf16_t* __restrict__ out) {
  const int i = (blockIdx.x * 256 + threadIdx.x) * 8;
  f32x8v v = *(const f32x8v*)(in + i);
  bf16x8 h;
#pragma unroll
  for (int j = 0; j < 8; ++j) h[j] = f2bf(v[j]);
  *(bf16x8*)(out + i) = h;
}

// ---------------- transpose + fp32->bf16 (in: R x Ccols fp32 -> out: Ccols x R bf16) ----
__global__ __launch_bounds__(256) void transpose_f32_bf16(const float* __restrict__ in,
                                                          bf16_t* __restrict__ out,
                                                          int R, int Ccols) {
  __shared__ bf16_t tile[32][33];
  int tx = threadIdx.x & 31, ty = threadIdx.x >> 5;
  int c0 = blockIdx.x * 32, r0 = blockIdx.y * 32;
#pragma unroll
  for (int j = 0; j < 4; ++j)
    tile[ty + j * 8][tx] = f2bf(in[(size_t)(r0 + ty + j * 8) * Ccols + c0 + tx]);
  __syncthreads();
#pragma unroll
  for (int j = 0; j < 4; ++j)
    out[(size_t)(c0 + ty + j * 8) * R + r0 + tx] = tile[tx][ty + j * 8];
}

// ------- 128x128 MFMA GEMM core, m97 structure: global_load_lds(16B) staging into
// ------- UNPADDED [128][64] LDS tiles, 2-barrier K-loop (A,Bt row-major bf16, K=C_) ----
__device__ __forceinline__ void gemm_core(const bf16_t* __restrict__ A,
                                          const bf16_t* __restrict__ Bt,
                                          int m0, int n0,
                                          bf16_t* lA, bf16_t* lB,
                                          f32x4 acc[4][4]) {
  const int t    = threadIdx.x;
  const int lane = t & 63, w = t >> 6;
  const int wr = (w >> 1) * 64, wc = (w & 1) * 64;
  const int l15 = lane & 15, g4 = lane >> 4;

  const f32x4 z4 = {0.f, 0.f, 0.f, 0.f};
#pragma unroll
  for (int i = 0; i < 4; ++i)
#pragma unroll
    for (int j = 0; j < 4; ++j) acc[i][j] = z4;

  // wave w stages rows [w*32, w*32+32) of each tile; per call: 8 rows x 128B = 1KB
  const int srow = w * 32 + (lane >> 3);
  const int sel8 = (lane & 7) * 8;
  const bf16_t* gA = A  + (size_t)(m0 + srow) * C_ + sel8;
  const bf16_t* gB = Bt + (size_t)(n0 + srow) * C_ + sel8;
  bf16_t* dA = lA + (w * 32) * 64;     // wave-uniform LDS base
  bf16_t* dB = lB + (w * 32) * 64;

  for (int kt = 0; kt < C_ / 64; ++kt) {
    const int k0 = kt * 64;
    __syncthreads();                   // prev tile's reads complete
#pragma unroll
    for (int j = 0; j < 4; ++j) {
      gld16(gA + (size_t)(j * 8) * C_ + k0, dA + j * 8 * 64);
      gld16(gB + (size_t)(j * 8) * C_ + k0, dB + j * 8 * 64);
    }
    __syncthreads();                   // compiler drains vmcnt(0) before barrier
#pragma unroll
    for (int ks = 0; ks < 2; ++ks) {
      bf16x8 af[4], bfv[4];
#pragma unroll
      for (int mi = 0; mi < 4; ++mi)
        af[mi] = *(const bf16x8*)&lA[(wr + mi * 16 + l15) * 64 + ks * 32 + g4 * 8];
#pragma unroll
      for (int ni = 0; ni < 4; ++ni)
        bfv[ni] = *(const bf16x8*)&lB[(wc + ni * 16 + l15) * 64 + ks * 32 + g4 * 8];
#pragma unroll
      for (int mi = 0; mi < 4; ++mi)
#pragma unroll
        for (int ni = 0; ni < 4; ++ni)
          acc[mi][ni] = __builtin_amdgcn_mfma_f32_16x16x32_bf16(af[mi], bfv[ni],
                                                                acc[mi][ni], 0, 0, 0);
    }
  }
}

// ---------------- GEMM1: qkv = x @ w_attn + b_attn, fused RoPE, split to q/k/v ----------
// 1D grid + bijective XCD swizzle (768 = 8 XCD x 96; n-major chunks for B-panel L2 reuse)
__global__ __launch_bounds__(256) void qkv_gemm(const bf16_t* __restrict__ x,
                                                const bf16_t* __restrict__ wT,
                                                const float* __restrict__ bias,
                                                const float2* __restrict__ rtab,
                                                bf16_t* __restrict__ qo,
                                                bf16_t* __restrict__ ko,
                                                bf16_t* __restrict__ vo) {
  __shared__ __align__(16) bf16_t smem[2 * 128 * 64];   // lA|lB, reused as store stage
  f32x4 acc[4][4];
  const int bid = blockIdx.x;
  const int swz = (bid & 7) * 96 + (bid >> 3);
  const int m0 = (swz & 31) * 128, n0 = (swz >> 5) * 128;
  gemm_core(x, wT, m0, n0, smem, smem + 128 * 64, acc);

  const int t = threadIdx.x;
  const int lane = t & 63, w = t >> 6;
  const int wr = (w >> 1) * 64, wc = (w & 1) * 64;
  const int l15 = lane & 15, g4 = lane >> 4;
  const int ng  = n0 + wc;              // 64-aligned -> single (sel, head) per wave
  const int sel = ng >> 10;
  const int h   = (ng & 1023) >> 6;

  __syncthreads();                      // all waves done reading lA/lB
  bf16_t* stg = smem + w * (64 * 64);   // per-wave 64x64 stage (disjoint regions)

  if (sel < 2) {
    // q: fold D^-0.5 AND log2(e) (attn uses exp2f)
    const float qs = (sel == 0) ? 0.125f * 1.4426950408889634f : 1.0f;
#pragma unroll
    for (int mi = 0; mi < 4; ++mi) {
#pragma unroll
      for (int ni = 0; ni < 2; ++ni) {
        const int d1 = ni * 16 + l15;        // 0..31; partner is d1+32 (frag ni+2)
        const float b1 = bias[ng + d1];
        const float b2 = bias[ng + d1 + 32];
#pragma unroll
        for (int r = 0; r < 4; ++r) {
          const int lrow = mi * 16 + g4 * 4 + r;
          const int tpos = (m0 + wr + lrow) & (T_ - 1);
          const float2 cs = rtab[tpos * 32 + d1];
          const float x1 = acc[mi][ni][r]     + b1;
          const float x2 = acc[mi][ni + 2][r] + b2;
          stg[lrow * 64 + d1]      = f2bf((x1 * cs.x - x2 * cs.y) * qs);
          stg[lrow * 64 + d1 + 32] = f2bf((x1 * cs.y + x2 * cs.x) * qs);
        }
      }
    }
  } else {
#pragma unroll
    for (int mi = 0; mi < 4; ++mi)
#pragma unroll
      for (int ni = 0; ni < 4; ++ni) {
        const int d = ni * 16 + l15;
        const float b1 = bias[ng + d];
#pragma unroll
        for (int r = 0; r < 4; ++r)
          stg[(mi * 16 + g4 * 4 + r) * 64 + d] = f2bf(acc[mi][ni][r] + b1);
      }
  }

  // readback own region (intra-wave dep only) + 1KB-per-instruction stores
  bf16_t* outp = (sel == 0) ? qo : (sel == 1 ? ko : vo);
  const int a  = lane >> 3;        // row-in-group 0..7
  const int b8 = (lane & 7) * 8;   // col chunk (x8 bf16 = 16B)
#pragma unroll
  for (int p = 0; p < 8; ++p) {
    const int lrow = p * 8 + a;
    const int row  = m0 + wr + lrow;
    const int tpos = row & (T_ - 1);
    const int bb   = row >> 11;
    uint4 val = *(const uint4*)&stg[lrow * 64 + b8];
    *(uint4*)(outp + ((size_t)(bb * H_ + h) * T_ + tpos) * D_ + b8) = val;
  }
}

// ---- flash attention, swapped-QK: 64 q-rows (4 waves x 16), KBLK=64, balanced grid ----
// S = mfma(K, Q): lane (g4,l15) holds S[key=kb+c*16+g4*4+r][q=qb+w*16+l15] -> q lane-local.
// PV key order is a free permutation: kappa(key=16c+4g+r) = 8g+4c+r, so each lane's
// softmax output IS its PV A-fragment (no P LDS round-trip). V^T staged at slot kappa,
// chunk XOR-spread by u=(d>>3)&7 for ~conflict-free scalar writes.
__global__ __launch_bounds__(256) void attn_fwd(const bf16_t* __restrict__ q,
                                                const bf16_t* __restrict__ k,
                                                const bf16_t* __restrict__ v,
                                                bf16_t* __restrict__ y) {
  __shared__ __align__(16) bf16_t Ks[64 * BKP];        // K rows [key][d]
  __shared__ __align__(16) bf16_t Vt[64 * PLD];        // V^T [d][slot(kappa,d)]
  const int t = threadIdx.x;
  const int lane = t & 63, w = t >> 6;
  const int l15 = lane & 15, g4 = lane >> 4;

  // causal load-balance pairing: consecutive g pairs (qt, NQT-1-qt)
  const int f  = blockIdx.x;
  const int bh = f & 31;
  const int g  = f >> 5;
  const int qt = (g & 1) ? (NQT - 1 - (g >> 1)) : (g >> 1);
  const int qb = qt * 64;
  const size_t hb = (size_t)bh * T_ * D_;

  const int qrow = qb + w * 16 + l15;
  bf16x8 qf[2];
  qf[0] = *(const bf16x8*)(q + hb + (size_t)qrow * D_ + g4 * 8);
  qf[1] = *(const bf16x8*)(q + hb + (size_t)qrow * D_ + 32 + g4 * 8);

  const f32x4 z4 = {0.f, 0.f, 0.f, 0.f};
  f32x4 o[4];
#pragma unroll
  for (int i = 0; i < 4; ++i) o[i] = z4;
  float mx = -1e30f, L = 0.f;

  const int skk = t >> 3;                  // key row 0..31 (+32 second pass)
  const int sd0 = (t & 7) * 8;
  const int u   = t & 7;                   // = (d>>3)&7 for all this thread's d rows
  // kappa(key) = 8*((key>>2)&3) + 4*((key>>4)&1) + (key&3); chunk XOR u for bank spread
  const int kh   = ((skk >> 2) & 3) * 8 + ((skk >> 4) & 1) * 4 + (skk & 3);
  const int pos0 = (((kh >> 3) ^ u) << 3) | (kh & 7);
  const int pos1 = ((((kh >> 3) ^ 4) ^ u) << 3) | (kh & 7);
  const int rowb = qb + w * 16 + g4 * 4;

  const int ntiles = qt + 1;

  // preload tile 0
  uint4 kv0 = *(const uint4*)(k + hb + (size_t)skk * D_ + sd0);
  uint4 kv1 = *(const uint4*)(k + hb + (size_t)(skk + 32) * D_ + sd0);
  uint4 vv0 = *(const uint4*)(v + hb + (size_t)skk * D_ + sd0);
  uint4 vv1 = *(const uint4*)(v + hb + (size_t)(skk + 32) * D_ + sd0);

  for (int it = 0; it < ntiles; ++it) {
    const int kb = it * 64;
    __syncthreads();
    *(uint4*)&Ks[skk * BKP + sd0]        = kv0;
    *(uint4*)&Ks[(skk + 32) * BKP + sd0] = kv1;
    {
      const bf16_t* vb0 = (const bf16_t*)&vv0;
      const bf16_t* vb1 = (const bf16_t*)&vv1;
#pragma unroll
      for (int i = 0; i < 8; ++i) {
        const int d = sd0 + i;
        Vt[d * PLD + pos0] = vb0[i];
        Vt[d * PLD + pos1] = vb1[i];
      }
    }
    __syncthreads();

    if (it + 1 < ntiles) {
      const size_t nb = hb + (size_t)(kb + 64 + skk) * D_ + sd0;
      kv0 = *(const uint4*)(k + nb);
      kv1 = *(const uint4*)(k + nb + 32 * D_);
      vv0 = *(const uint4*)(v + nb);
      vv1 = *(const uint4*)(v + nb + 32 * D_);
    }

    // ---- QK^T swapped: s[c][r] = S[key=kb+c*16+g4*4+r][q=qrow] ----
    f32x4 s[4];
#pragma unroll
    for (int c = 0; c < 4; ++c) s[c] = z4;
#pragma unroll
    for (int ks = 0; ks < 2; ++ks)
#pragma unroll
      for (int c = 0; c < 4; ++c) {
        bf16x8 kf = *(const bf16x8*)&Ks[(c * 16 + l15) * BKP + ks * 32 + g4 * 8];
        s[c] = __builtin_amdgcn_mfma_f32_16x16x32_bf16(kf, qf[ks], s[c], 0, 0, 0);
      }

    // ---- causal mask: only the diagonal tile can violate (kb+63 < qb for it<last) ----
    if (it == ntiles - 1) {
#pragma unroll
      for (int c = 0; c < 4; ++c)
#pragma unroll
        for (int r = 0; r < 4; ++r)
          if (kb + c * 16 + g4 * 4 + r > qrow) s[c][r] = -1e30f;
    }

    // ---- online softmax (exp2 domain; all 16 values belong to q=qrow) ----
    float tm = -1e30f;
#pragma unroll
    for (int c = 0; c < 4; ++c)
#pragma unroll
      for (int r = 0; r < 4; ++r) tm = fmaxf(tm, s[c][r]);
    tm = fmaxf(tm, __shfl_xor(tm, 16));
    tm = fmaxf(tm, __shfl_xor(tm, 32));
    const float mn = fmaxf(mx, tm);
    float rs = 0.f;
#pragma unroll
    for (int c = 0; c < 4; ++c)
#pragma unroll
      for (int r = 0; r < 4; ++r) {
        s[c][r] = exp2f(s[c][r] - mn);
        rs += s[c][r];
      }
    rs += __shfl_xor(rs, 16);
    rs += __shfl_xor(rs, 32);
    const float sc = exp2f(mx - mn);
    L = L * sc + rs;
    mx = mn;

    // o rescale: o[nf][r] is q=g4*4+r -> pull sc from lane with l15=g4*4+r
    float scr[4];
#pragma unroll
    for (int r = 0; r < 4; ++r)
      scr[r] = __shfl(sc, (lane & 48) | (g4 * 4 + r));
#pragma unroll
    for (int nf = 0; nf < 4; ++nf)
#pragma unroll
      for (int r = 0; r < 4; ++r) o[nf][r] *= scr[r];

    // ---- P -> PV A-fragments, in-lane (kappa ordering) ----
    bf16x8 ap0, ap1;
#pragma unroll
    for (int r = 0; r < 4; ++r) {
      ap0[r]     = f2bf(s[0][r]);
      ap0[4 + r] = f2bf(s[1][r]);
      ap1[r]     = f2bf(s[2][r]);
      ap1[4 + r] = f2bf(s[3][r]);
    }

    // ---- PV: o[q][d] += P V, keys in kappa order on both operands ----
#pragma unroll
    for (int nf = 0; nf < 4; ++nf) {
      const int d  = nf * 16 + l15;
      const int h3 = (2 * nf + (l15 >> 3)) & 7;   // (d>>3)&7
      bf16x8 vf0 = *(const bf16x8*)&Vt[d * PLD + ((g4 ^ h3) << 3)];
      bf16x8 vf1 = *(const bf16x8*)&Vt[d * PLD + (((g4 + 4) ^ h3) << 3)];
      o[nf] = __builtin_amdgcn_mfma_f32_16x16x32_bf16(ap0, vf0, o[nf], 0, 0, 0);
      o[nf] = __builtin_amdgcn_mfma_f32_16x16x32_bf16(ap1, vf1, o[nf], 0, 0, 0);
    }
  }

  const int bb = bh / H_, hh = bh % H_;
  float il[4];
#pragma unroll
  for (int r = 0; r < 4; ++r)
    il[r] = 1.0f / __shfl(L, (lane & 48) | (g4 * 4 + r));
#pragma unroll
  for (int nf = 0; nf < 4; ++nf)
#pragma unroll
    for (int r = 0; r < 4; ++r) {
      const int row = rowb + r;
      y[(size_t)(bb * T_ + row) * C_ + hh * D_ + nf * 16 + l15] = f2bf(o[nf][r] * il[r]);
    }
}

// ---------------- GEMM2: out = y @ w_proj + b_proj (fp32 out) ----------------
// 1D grid + XCD swizzle (256 = 8 XCD x 32; one n-tile per XCD)
__global__ __launch_bounds__(256) void proj_gemm(const bf16_t* __restrict__ yin,
                                                 const bf16_t* __restrict__ wT,
                                                 const float* __restrict__ bias,
                                                 float* __restrict__ out) {
  __shared__ __align__(16) bf16_t lA[128 * 64];
  __shared__ __align__(16) bf16_t lB[128 * 64];
  f32x4 acc[4][4];
  const int bid = blockIdx.x;
  const int swz = (bid & 7) * 32 + (bid >> 3);
  const int m0 = (swz & 31) * 128, n0 = (swz >> 5) * 128;
  gemm_core(yin, wT, m0, n0, lA, lB, acc);

  const int t = threadIdx.x;
  const int lane = t & 63, w = t >> 6;
  const int wr = (w >> 1) * 64, wc = (w & 1) * 64;
  const int l15 = lane & 15, g4 = lane >> 4;
  const int ng = n0 + wc;
#pragma unroll
  for (int mi = 0; mi < 4; ++mi) {
    const int rowb = m0 + wr + mi * 16 + g4 * 4;
#pragma unroll
    for (int ni = 0; ni < 4; ++ni) {
      const int n = ng + ni * 16 + l15;
      const float b1 = bias[n];
#pragma unroll
      for (int r = 0; r < 4; ++r)
        out[(size_t)(rowb + r) * C_ + n] = acc[mi][ni][r] + b1;
    }
  }
}

// ---------------- launch ----------------
extern "C" void kernel_launch(void* const* d_in, const int* in_sizes, int n_in,
                              void* d_out, int out_size, void* d_ws, size_t ws_size,
                              hipStream_t stream) {
  (void)in_sizes; (void)n_in; (void)out_size; (void)ws_size;
  const float* x      = (const float*)d_in[0];
  const float* w_attn = (const float*)d_in[1];
  const float* b_attn = (const float*)d_in[2];
  const float* w_proj = (const float*)d_in[3];
  const float* b_proj = (const float*)d_in[4];
  float* out = (float*)d_out;

  char* ws = (char*)d_ws;
  bf16_t* wTa = (bf16_t*)ws;  ws += (size_t)NQKV_ * C_ * 2;          // 6 MB
  bf16_t* wTp = (bf16_t*)ws;  ws += (size_t)C_ * C_ * 2;             // 2 MB
  bf16_t* qb  = (bf16_t*)ws;  ws += (size_t)B_ * H_ * T_ * D_ * 2;   // 8 MB
  bf16_t* kb  = (bf16_t*)ws;  ws += (size_t)B_ * H_ * T_ * D_ * 2;   // 8 MB
  bf16_t* vb  = (bf16_t*)ws;  ws += (size_t)B_ * H_ * T_ * D_ * 2;   // 8 MB
  bf16_t* yb  = (bf16_t*)ws;  ws += (size_t)B_ * T_ * C_ * 2;        // 8 MB
  float2* rtab = (float2*)ws; ws += (size_t)T_ * 32 * sizeof(float2);// 0.5 MB
  // x_bf aliases yb: x_bf is consumed by qkv_gemm (dispatch 4) strictly before
  // attn_fwd (dispatch 5) writes yb. Stream-ordered, deterministic.
  bf16_t* x_bf = yb;

  rope_tab_k<<<dim3(T_ * 32 / 256), 256, 0, stream>>>(rtab);
  transpose_f32_bf16<<<dim3(NQKV_ / 32, C_ / 32), 256, 0, stream>>>(w_attn, wTa, C_, NQKV_);
  transpose_f32_bf16<<<dim3(C_ / 32,   C_ / 32), 256, 0, stream>>>(w_proj, wTp, C_, C_);
  f32_to_bf16_k<<<dim3(M_ * C_ / (256 * 8)), 256, 0, stream>>>(x, x_bf);
  qkv_gemm<<<dim3((M_ / 128) * (NQKV_ / 128)), 256, 0, stream>>>(x_bf, wTa, b_attn, rtab, qb, kb, vb);
  attn_fwd<<<dim3((T_ / 64) * 32), 256, 0, stream>>>(qb, kb, vb, yb);
  proj_gemm<<<dim3((M_ / 128) * (C_ / 128)), 256, 0, stream>>>(yb, wTp, b_proj, out);
}

// Round 9
// 159.889 us; speedup vs baseline: 2.1628x; 1.0390x over previous
//
#include <hip/hip_runtime.h>
#include <hip/hip_bf16.h>

typedef __bf16 bf16_t;
typedef __bf16 bf16x8 __attribute__((ext_vector_type(8)));
typedef float f32x4 __attribute__((ext_vector_type(4)));
typedef float f32x8v __attribute__((ext_vector_type(8)));

#define B_    2
#define T_    2048
#define C_    1024
#define H_    16
#define D_    64
#define M_    4096      // B*T
#define NQKV_ 3072
#define PLD   72        // attn V^T LDS row stride
#define NQT   32        // T_/64 q-tiles

static __device__ __forceinline__ float  bf2f(bf16_t x) { return (float)x; }
static __device__ __forceinline__ bf16_t f2bf(float x)  { return (bf16_t)x; }

// async global->LDS, 16B per lane; LDS dest is wave-uniform base + lane*16 (HW rule)
typedef const __attribute__((address_space(1))) void gas_void;
typedef __attribute__((address_space(3))) void las_void;
static __device__ __forceinline__ void gld16(const void* g, void* l) {
  __builtin_amdgcn_global_load_lds((gas_void*)g, (las_void*)l, 16, 0, 0);
}

// ---------------- RoPE cos/sin table: [T][32] float2 ----------------
__global__ __launch_bounds__(256) void rope_tab_k(float2* __restrict__ tab) {
  int i = blockIdx.x * 256 + threadIdx.x;      // < T_*32
  int tpos = i >> 5, d = i & 31;
  float fr = exp2f(-(float)d * (13.287712379549449f / 32.0f));  // 10000^(-d/32)
  float ang = (float)tpos * fr;
  tab[i] = make_float2(cosf(ang), sinf(ang));
}

// ---------------- x: fp32 -> bf16 bulk convert ----------------
__global__ __launch_bounds__(256) void f32_to_bf16_k(const float* __restrict__ in,
                                                     bf16_t* __restrict__ out) {
  const int i = (blockIdx.x * 256 + threadIdx.x) * 8;
  f32x8v v = *(const f32x8v*)(in + i);
  bf16x8 h;
#pragma unroll
  for (int j = 0; j < 8; ++j) h[j] = f2bf(v[j]);
  *(bf16x8*)(out + i) = h;
}

// ---------------- transpose + fp32->bf16 (in: R x Ccols fp32 -> out: Ccols x R bf16) ----
__global__ __launch_bounds__(256) void transpose_f32_bf16(const float* __restrict__ in,
                                                          bf16_t* __restrict__ out,
                                                          int R, int Ccols) {
  __shared__ bf16_t tile[32][33];
  int tx = threadIdx.x & 31, ty = threadIdx.x >> 5;
  int c0 = blockIdx.x * 32, r0 = blockIdx.y * 32;
#pragma unroll
  for (int j = 0; j < 4; ++j)
    tile[ty + j * 8][tx] = f2bf(in[(size_t)(r0 + ty + j * 8) * Ccols + c0 + tx]);
  __syncthreads();
#pragma unroll
  for (int j = 0; j < 4; ++j)
    out[(size_t)(c0 + ty + j * 8) * R + r0 + tx] = tile[tx][ty + j * 8];
}

// ------- 128x128 MFMA GEMM core, m97 structure: global_load_lds(16B) staging into
// ------- UNPADDED [128][64] LDS tiles, 2-barrier K-loop (A,Bt row-major bf16, K=C_) ----
__device__ __forceinline__ void gemm_core(const bf16_t* __restrict__ A,
                                          const bf16_t* __restrict__ Bt,
                                          int m0, int n0,
                                          bf16_t* lA, bf16_t* lB,
                                          f32x4 acc[4][4]) {
  const int t    = threadIdx.x;
  const int lane = t & 63, w = t >> 6;
  const int wr = (w >> 1) * 64, wc = (w & 1) * 64;
  const int l15 = lane & 15, g4 = lane >> 4;

  const f32x4 z4 = {0.f, 0.f, 0.f, 0.f};
#pragma unroll
  for (int i = 0; i < 4; ++i)
#pragma unroll
    for (int j = 0; j < 4; ++j) acc[i][j] = z4;

  // wave w stages rows [w*32, w*32+32) of each tile; per call: 8 rows x 128B = 1KB
  const int srow = w * 32 + (lane >> 3);
  const int sel8 = (lane & 7) * 8;
  const bf16_t* gA = A  + (size_t)(m0 + srow) * C_ + sel8;
  const bf16_t* gB = Bt + (size_t)(n0 + srow) * C_ + sel8;
  bf16_t* dA = lA + (w * 32) * 64;     // wave-uniform LDS base
  bf16_t* dB = lB + (w * 32) * 64;

  for (int kt = 0; kt < C_ / 64; ++kt) {
    const int k0 = kt * 64;
    __syncthreads();                   // prev tile's reads complete
#pragma unroll
    for (int j = 0; j < 4; ++j) {
      gld16(gA + (size_t)(j * 8) * C_ + k0, dA + j * 8 * 64);
      gld16(gB + (size_t)(j * 8) * C_ + k0, dB + j * 8 * 64);
    }
    __syncthreads();                   // compiler drains vmcnt(0) before barrier
#pragma unroll
    for (int ks = 0; ks < 2; ++ks) {
      bf16x8 af[4], bfv[4];
#pragma unroll
      for (int mi = 0; mi < 4; ++mi)
        af[mi] = *(const bf16x8*)&lA[(wr + mi * 16 + l15) * 64 + ks * 32 + g4 * 8];
#pragma unroll
      for (int ni = 0; ni < 4; ++ni)
        bfv[ni] = *(const bf16x8*)&lB[(wc + ni * 16 + l15) * 64 + ks * 32 + g4 * 8];
#pragma unroll
      for (int mi = 0; mi < 4; ++mi)
#pragma unroll
        for (int ni = 0; ni < 4; ++ni)
          acc[mi][ni] = __builtin_amdgcn_mfma_f32_16x16x32_bf16(af[mi], bfv[ni],
                                                                acc[mi][ni], 0, 0, 0);
    }
  }
}

// ---------------- GEMM1: qkv = x @ w_attn + b_attn, fused RoPE, split to q/k/v ----------
// 1D grid + bijective XCD swizzle (768 = 8 XCD x 96; n-major chunks for B-panel L2 reuse)
__global__ __launch_bounds__(256) void qkv_gemm(const bf16_t* __restrict__ x,
                                                const bf16_t* __restrict__ wT,
                                                const float* __restrict__ bias,
                                                const float2* __restrict__ rtab,
                                                bf16_t* __restrict__ qo,
                                                bf16_t* __restrict__ ko,
                                                bf16_t* __restrict__ vo) {
  __shared__ __align__(16) bf16_t smem[2 * 128 * 64];   // lA|lB, reused as store stage
  f32x4 acc[4][4];
  const int bid = blockIdx.x;
  const int swz = (bid & 7) * 96 + (bid >> 3);
  const int m0 = (swz & 31) * 128, n0 = (swz >> 5) * 128;
  gemm_core(x, wT, m0, n0, smem, smem + 128 * 64, acc);

  const int t = threadIdx.x;
  const int lane = t & 63, w = t >> 6;
  const int wr = (w >> 1) * 64, wc = (w & 1) * 64;
  const int l15 = lane & 15, g4 = lane >> 4;
  const int ng  = n0 + wc;              // 64-aligned -> single (sel, head) per wave
  const int sel = ng >> 10;
  const int h   = (ng & 1023) >> 6;

  __syncthreads();                      // all waves done reading lA/lB
  bf16_t* stg = smem + w * (64 * 64);   // per-wave 64x64 stage (disjoint regions)

  if (sel < 2) {
    // q: fold D^-0.5 AND log2(e) (attn uses exp2f)
    const float qs = (sel == 0) ? 0.125f * 1.4426950408889634f : 1.0f;
#pragma unroll
    for (int mi = 0; mi < 4; ++mi) {
#pragma unroll
      for (int ni = 0; ni < 2; ++ni) {
        const int d1 = ni * 16 + l15;        // 0..31; partner is d1+32 (frag ni+2)
        const float b1 = bias[ng + d1];
        const float b2 = bias[ng + d1 + 32];
#pragma unroll
        for (int r = 0; r < 4; ++r) {
          const int lrow = mi * 16 + g4 * 4 + r;
          const int tpos = (m0 + wr + lrow) & (T_ - 1);
          const float2 cs = rtab[tpos * 32 + d1];
          const float x1 = acc[mi][ni][r]     + b1;
          const float x2 = acc[mi][ni + 2][r] + b2;
          stg[lrow * 64 + d1]      = f2bf((x1 * cs.x - x2 * cs.y) * qs);
          stg[lrow * 64 + d1 + 32] = f2bf((x1 * cs.y + x2 * cs.x) * qs);
        }
      }
    }
  } else {
#pragma unroll
    for (int mi = 0; mi < 4; ++mi)
#pragma unroll
      for (int ni = 0; ni < 4; ++ni) {
        const int d = ni * 16 + l15;
        const float b1 = bias[ng + d];
#pragma unroll
        for (int r = 0; r < 4; ++r)
          stg[(mi * 16 + g4 * 4 + r) * 64 + d] = f2bf(acc[mi][ni][r] + b1);
      }
  }

  // readback own region (intra-wave dep only) + 1KB-per-instruction stores
  bf16_t* outp = (sel == 0) ? qo : (sel == 1 ? ko : vo);
  const int a  = lane >> 3;        // row-in-group 0..7
  const int b8 = (lane & 7) * 8;   // col chunk (x8 bf16 = 16B)
#pragma unroll
  for (int p = 0; p < 8; ++p) {
    const int lrow = p * 8 + a;
    const int row  = m0 + wr + lrow;
    const int tpos = row & (T_ - 1);
    const int bb   = row >> 11;
    uint4 val = *(const uint4*)&stg[lrow * 64 + b8];
    *(uint4*)(outp + ((size_t)(bb * H_ + h) * T_ + tpos) * D_ + b8) = val;
  }
}

// ---- flash attention, swapped-QK: 64 q-rows (4 waves x 16), KBLK=64 ----
// CU-balanced grid: 4 co-resident blocks per CU sum to exactly 66 tile-units
// (qt = [p, 31-p, (p+16)&31, (15-p)&31] for j = f>>8, p = (f>>3)&31);
// bh = (f&7)*4 + j keeps 4 heads per XCD (K/V panel 2MB < 4MB L2).
// Ks: unpadded [64][64] + XOR swizzle (chunk ^= (row&7)) -> kf reads 2-way max (free).
// Defer-max (THR=8, exp2 domain): skip o/L rescale unless wave max growth > 8.
__global__ __launch_bounds__(256) void attn_fwd(const bf16_t* __restrict__ q,
                                                const bf16_t* __restrict__ k,
                                                const bf16_t* __restrict__ v,
                                                bf16_t* __restrict__ y) {
  __shared__ __align__(16) bf16_t Ks[64 * 64];         // K rows [key][d], XOR-swizzled
  __shared__ __align__(16) bf16_t Vt[64 * PLD];        // V^T [d][slot(kappa,d)]
  const int t = threadIdx.x;
  const int lane = t & 63, w = t >> 6;
  const int l15 = lane & 15, g4 = lane >> 4;

  const int f = blockIdx.x;
  const int j = f >> 8;                 // 0..3
  const int p = (f >> 3) & 31;
  int qt;
  if      (j == 0) qt = p;
  else if (j == 1) qt = 31 - p;
  else if (j == 2) qt = (p + 16) & 31;
  else             qt = (15 - p) & 31;
  const int bh = (f & 7) * 4 + j;
  const int qb = qt * 64;
  const size_t hb = (size_t)bh * T_ * D_;

  const int qrow = qb + w * 16 + l15;
  bf16x8 qf[2];
  qf[0] = *(const bf16x8*)(q + hb + (size_t)qrow * D_ + g4 * 8);
  qf[1] = *(const bf16x8*)(q + hb + (size_t)qrow * D_ + 32 + g4 * 8);

  const f32x4 z4 = {0.f, 0.f, 0.f, 0.f};
  f32x4 o[4];
#pragma unroll
  for (int i = 0; i < 4; ++i) o[i] = z4;
  float mx = -1e30f, L = 0.f;

  const int skk = t >> 3;                  // key row 0..31 (+32 second pass)
  const int sd0 = (t & 7) * 8;
  const int u   = t & 7;                   // = (d>>3)&7 for all this thread's d rows
  const int ksw = sd0 ^ ((skk & 7) * 8);   // Ks swizzled col (same for skk+32)
  // kappa(key) = 8*((key>>2)&3) + 4*((key>>4)&1) + (key&3); chunk XOR u for bank spread
  const int kh   = ((skk >> 2) & 3) * 8 + ((skk >> 4) & 1) * 4 + (skk & 3);
  const int pos0 = (((kh >> 3) ^ u) << 3) | (kh & 7);
  const int pos1 = ((((kh >> 3) ^ 4) ^ u) << 3) | (kh & 7);
  const int rowb = qb + w * 16 + g4 * 4;

  const int ntiles = qt + 1;

  // preload tile 0
  uint4 kv0 = *(const uint4*)(k + hb + (size_t)skk * D_ + sd0);
  uint4 kv1 = *(const uint4*)(k + hb + (size_t)(skk + 32) * D_ + sd0);
  uint4 vv0 = *(const uint4*)(v + hb + (size_t)skk * D_ + sd0);
  uint4 vv1 = *(const uint4*)(v + hb + (size_t)(skk + 32) * D_ + sd0);

  for (int it = 0; it < ntiles; ++it) {
    const int kb = it * 64;
    __syncthreads();
    *(uint4*)&Ks[skk * 64 + ksw]        = kv0;
    *(uint4*)&Ks[(skk + 32) * 64 + ksw] = kv1;
    {
      const bf16_t* vb0 = (const bf16_t*)&vv0;
      const bf16_t* vb1 = (const bf16_t*)&vv1;
#pragma unroll
      for (int i = 0; i < 8; ++i) {
        const int d = sd0 + i;
        Vt[d * PLD + pos0] = vb0[i];
        Vt[d * PLD + pos1] = vb1[i];
      }
    }
    __syncthreads();

    if (it + 1 < ntiles) {
      const size_t nb = hb + (size_t)(kb + 64 + skk) * D_ + sd0;
      kv0 = *(const uint4*)(k + nb);
      kv1 = *(const uint4*)(k + nb + 32 * D_);
      vv0 = *(const uint4*)(v + nb);
      vv1 = *(const uint4*)(v + nb + 32 * D_);
    }

    // ---- QK^T swapped: s[c][r] = S[key=kb+c*16+g4*4+r][q=qrow] ----
    f32x4 s[4];
#pragma unroll
    for (int c = 0; c < 4; ++c) s[c] = z4;
#pragma unroll
    for (int ks = 0; ks < 2; ++ks)
#pragma unroll
      for (int c = 0; c < 4; ++c) {
        const int kr = c * 16 + l15;
        bf16x8 kf = *(const bf16x8*)&Ks[kr * 64 + ((ks * 32 + g4 * 8) ^ ((kr & 7) * 8))];
        s[c] = __builtin_amdgcn_mfma_f32_16x16x32_bf16(kf, qf[ks], s[c], 0, 0, 0);
      }

    // ---- causal mask: only the diagonal tile can violate (kb+63 < qb for it<last) ----
    if (it == ntiles - 1) {
#pragma unroll
      for (int c = 0; c < 4; ++c)
#pragma unroll
        for (int r = 0; r < 4; ++r)
          if (kb + c * 16 + g4 * 4 + r > qrow) s[c][r] = -1e30f;
    }

    // ---- online softmax (exp2 domain; defer-max THR=8) ----
    float tm = -1e30f;
#pragma unroll
    for (int c = 0; c < 4; ++c)
#pragma unroll
      for (int r = 0; r < 4; ++r) tm = fmaxf(tm, s[c][r]);
    tm = fmaxf(tm, __shfl_xor(tm, 16));
    tm = fmaxf(tm, __shfl_xor(tm, 32));
    if (!__all(tm - mx <= 8.0f)) {        // wave-uniform; rare after warm-up
      const float mnew = fmaxf(mx, tm);
      const float sc = exp2f(mx - mnew);  // first tile: exp2(-inf)=0 zeroes L,o
      L *= sc;
      float scr[4];
#pragma unroll
      for (int r = 0; r < 4; ++r)
        scr[r] = __shfl(sc, (lane & 48) | (g4 * 4 + r));
#pragma unroll
      for (int nf = 0; nf < 4; ++nf)
#pragma unroll
        for (int r = 0; r < 4; ++r) o[nf][r] *= scr[r];
      mx = mnew;
    }
    float rs = 0.f;
#pragma unroll
    for (int c = 0; c < 4; ++c)
#pragma unroll
      for (int r = 0; r < 4; ++r) {
        s[c][r] = exp2f(s[c][r] - mx);    // bounded by 2^8
        rs += s[c][r];
      }
    rs += __shfl_xor(rs, 16);
    rs += __shfl_xor(rs, 32);
    L += rs;

    // ---- P -> PV A-fragments, in-lane (kappa ordering) ----
    bf16x8 ap0, ap1;
#pragma unroll
    for (int r = 0; r < 4; ++r) {
      ap0[r]     = f2bf(s[0][r]);
      ap0[4 + r] = f2bf(s[1][r]);
      ap1[r]     = f2bf(s[2][r]);
      ap1[4 + r] = f2bf(s[3][r]);
    }

    // ---- PV: o[q][d] += P V, keys in kappa order on both operands ----
#pragma unroll
    for (int nf = 0; nf < 4; ++nf) {
      const int d  = nf * 16 + l15;
      const int h3 = (2 * nf + (l15 >> 3)) & 7;   // (d>>3)&7
      bf16x8 vf0 = *(const bf16x8*)&Vt[d * PLD + ((g4 ^ h3) << 3)];
      bf16x8 vf1 = *(const bf16x8*)&Vt[d * PLD + (((g4 + 4) ^ h3) << 3)];
      o[nf] = __builtin_amdgcn_mfma_f32_16x16x32_bf16(ap0, vf0, o[nf], 0, 0, 0);
      o[nf] = __builtin_amdgcn_mfma_f32_16x16x32_bf16(ap1, vf1, o[nf], 0, 0, 0);
    }
  }

  const int bb = bh / H_, hh = bh % H_;
  float il[4];
#pragma unroll
  for (int r = 0; r < 4; ++r)
    il[r] = 1.0f / __shfl(L, (lane & 48) | (g4 * 4 + r));
#pragma unroll
  for (int nf = 0; nf < 4; ++nf)
#pragma unroll
    for (int r = 0; r < 4; ++r) {
      const int row = rowb + r;
      y[(size_t)(bb * T_ + row) * C_ + hh * D_ + nf * 16 + l15] = f2bf(o[nf][r] * il[r]);
    }
}

// ---------------- GEMM2: out = y @ w_proj + b_proj (fp32 out) ----------------
// 1D grid + XCD swizzle (256 = 8 XCD x 32; one n-tile per XCD)
__global__ __launch_bounds__(256) void proj_gemm(const bf16_t* __restrict__ yin,
                                                 const bf16_t* __restrict__ wT,
                                                 const float* __restrict__ bias,
                                                 float* __restrict__ out) {
  __shared__ __align__(16) bf16_t lA[128 * 64];
  __shared__ __align__(16) bf16_t lB[128 * 64];
  f32x4 acc[4][4];
  const int bid = blockIdx.x;
  const int swz = (bid & 7) * 32 + (bid >> 3);
  const int m0 = (swz & 31) * 128, n0 = (swz >> 5) * 128;
  gemm_core(yin, wT, m0, n0, lA, lB, acc);

  const int t = threadIdx.x;
  const int lane = t & 63, w = t >> 6;
  const int wr = (w >> 1) * 64, wc = (w & 1) * 64;
  const int l15 = lane & 15, g4 = lane >> 4;
  const int ng = n0 + wc;
#pragma unroll
  for (int mi = 0; mi < 4; ++mi) {
    const int rowb = m0 + wr + mi * 16 + g4 * 4;
#pragma unroll
    for (int ni = 0; ni < 4; ++ni) {
      const int n = ng + ni * 16 + l15;
      const float b1 = bias[n];
#pragma unroll
      for (int r = 0; r < 4; ++r)
        out[(size_t)(rowb + r) * C_ + n] = acc[mi][ni][r] + b1;
    }
  }
}

// ---------------- launch ----------------
extern "C" void kernel_launch(void* const* d_in, const int* in_sizes, int n_in,
                              void* d_out, int out_size, void* d_ws, size_t ws_size,
                              hipStream_t stream) {
  (void)in_sizes; (void)n_in; (void)out_size; (void)ws_size;
  const float* x      = (const float*)d_in[0];
  const float* w_attn = (const float*)d_in[1];
  const float* b_attn = (const float*)d_in[2];
  const float* w_proj = (const float*)d_in[3];
  const float* b_proj = (const float*)d_in[4];
  float* out = (float*)d_out;

  char* ws = (char*)d_ws;
  bf16_t* wTa = (bf16_t*)ws;  ws += (size_t)NQKV_ * C_ * 2;          // 6 MB
  bf16_t* wTp = (bf16_t*)ws;  ws += (size_t)C_ * C_ * 2;             // 2 MB
  bf16_t* qb  = (bf16_t*)ws;  ws += (size_t)B_ * H_ * T_ * D_ * 2;   // 8 MB
  bf16_t* kb  = (bf16_t*)ws;  ws += (size_t)B_ * H_ * T_ * D_ * 2;   // 8 MB
  bf16_t* vb  = (bf16_t*)ws;  ws += (size_t)B_ * H_ * T_ * D_ * 2;   // 8 MB
  bf16_t* yb  = (bf16_t*)ws;  ws += (size_t)B_ * T_ * C_ * 2;        // 8 MB
  float2* rtab = (float2*)ws; ws += (size_t)T_ * 32 * sizeof(float2);// 0.5 MB
  // x_bf aliases yb: x_bf is consumed by qkv_gemm (dispatch 4) strictly before
  // attn_fwd (dispatch 5) writes yb. Stream-ordered, deterministic.
  bf16_t* x_bf = yb;

  rope_tab_k<<<dim3(T_ * 32 / 256), 256, 0, stream>>>(rtab);
  transpose_f32_bf16<<<dim3(NQKV_ / 32, C_ / 32), 256, 0, stream>>>(w_attn, wTa, C_, NQKV_);
  transpose_f32_bf16<<<dim3(C_ / 32,   C_ / 32), 256, 0, stream>>>(w_proj, wTp, C_, C_);
  f32_to_bf16_k<<<dim3(M_ * C_ / (256 * 8)), 256, 0, stream>>>(x, x_bf);
  qkv_gemm<<<dim3((M_ / 128) * (NQKV_ / 128)), 256, 0, stream>>>(x_bf, wTa, b_attn, rtab, qb, kb, vb);
  attn_fwd<<<dim3((T_ / 64) * 32), 256, 0, stream>>>(qb, kb, vb, yb);
  proj_gemm<<<dim3((M_ / 128) * (C_ / 128)), 256, 0, stream>>>(yb, wTp, b_proj, out);
}

// Round 10
// 142.064 us; speedup vs baseline: 2.4341x; 1.1255x over previous
//
#include <hip/hip_runtime.h>
#include <hip/hip_bf16.h>

typedef __bf16 bf16_t;
typedef __bf16 bf16x8 __attribute__((ext_vector_type(8)));
typedef float f32x4 __attribute__((ext_vector_type(4)));
typedef float f32x8v __attribute__((ext_vector_type(8)));

#define B_    2
#define T_    2048
#define C_    1024
#define H_    16
#define D_    64
#define M_    4096      // B*T
#define NQKV_ 3072
#define PLD   72        // attn V^T LDS row stride
#define NQT2  16        // T_/128 q-tiles (attn)

static __device__ __forceinline__ float  bf2f(bf16_t x) { return (float)x; }
static __device__ __forceinline__ bf16_t f2bf(float x)  { return (bf16_t)x; }

// async global->LDS, 16B per lane; LDS dest is wave-uniform base + lane*16 (HW rule)
typedef const __attribute__((address_space(1))) void gas_void;
typedef __attribute__((address_space(3))) void las_void;
static __device__ __forceinline__ void gld16(const void* g, void* l) {
  __builtin_amdgcn_global_load_lds((gas_void*)g, (las_void*)l, 16, 0, 0);
}

// ---------------- RoPE cos/sin table: [T][32] float2 ----------------
__global__ __launch_bounds__(256) void rope_tab_k(float2* __restrict__ tab) {
  int i = blockIdx.x * 256 + threadIdx.x;      // < T_*32
  int tpos = i >> 5, d = i & 31;
  float fr = exp2f(-(float)d * (13.287712379549449f / 32.0f));  // 10000^(-d/32)
  float ang = (float)tpos * fr;
  tab[i] = make_float2(cosf(ang), sinf(ang));
}

// ---------------- x: fp32 -> bf16 bulk convert ----------------
__global__ __launch_bounds__(256) void f32_to_bf16_k(const float* __restrict__ in,
                                                     bf16_t* __restrict__ out) {
  const int i = (blockIdx.x * 256 + threadIdx.x) * 8;
  f32x8v v = *(const f32x8v*)(in + i);
  bf16x8 h;
#pragma unroll
  for (int j = 0; j < 8; ++j) h[j] = f2bf(v[j]);
  *(bf16x8*)(out + i) = h;
}

// ---------------- transpose + fp32->bf16 (in: R x Ccols fp32 -> out: Ccols x R bf16) ----
__global__ __launch_bounds__(256) void transpose_f32_bf16(const float* __restrict__ in,
                                                          bf16_t* __restrict__ out,
                                                          int R, int Ccols) {
  __shared__ bf16_t tile[32][33];
  int tx = threadIdx.x & 31, ty = threadIdx.x >> 5;
  int c0 = blockIdx.x * 32, r0 = blockIdx.y * 32;
#pragma unroll
  for (int j = 0; j < 4; ++j)
    tile[ty + j * 8][tx] = f2bf(in[(size_t)(r0 + ty + j * 8) * Ccols + c0 + tx]);
  __syncthreads();
#pragma unroll
  for (int j = 0; j < 4; ++j)
    out[(size_t)(c0 + ty + j * 8) * R + r0 + tx] = tile[tx][ty + j * 8];
}

// ------- 128x128 MFMA GEMM core, m97 structure: global_load_lds(16B) staging into
// ------- UNPADDED [128][64] LDS tiles, 2-barrier K-loop (A,Bt row-major bf16, K=C_) ----
__device__ __forceinline__ void gemm_core(const bf16_t* __restrict__ A,
                                          const bf16_t* __restrict__ Bt,
                                          int m0, int n0,
                                          bf16_t* lA, bf16_t* lB,
                                          f32x4 acc[4][4]) {
  const int t    = threadIdx.x;
  const int lane = t & 63, w = t >> 6;
  const int wr = (w >> 1) * 64, wc = (w & 1) * 64;
  const int l15 = lane & 15, g4 = lane >> 4;

  const f32x4 z4 = {0.f, 0.f, 0.f, 0.f};
#pragma unroll
  for (int i = 0; i < 4; ++i)
#pragma unroll
    for (int j = 0; j < 4; ++j) acc[i][j] = z4;

  // wave w stages rows [w*32, w*32+32) of each tile; per call: 8 rows x 128B = 1KB
  const int srow = w * 32 + (lane >> 3);
  const int sel8 = (lane & 7) * 8;
  const bf16_t* gA = A  + (size_t)(m0 + srow) * C_ + sel8;
  const bf16_t* gB = Bt + (size_t)(n0 + srow) * C_ + sel8;
  bf16_t* dA = lA + (w * 32) * 64;     // wave-uniform LDS base
  bf16_t* dB = lB + (w * 32) * 64;

  for (int kt = 0; kt < C_ / 64; ++kt) {
    const int k0 = kt * 64;
    __syncthreads();                   // prev tile's reads complete
#pragma unroll
    for (int j = 0; j < 4; ++j) {
      gld16(gA + (size_t)(j * 8) * C_ + k0, dA + j * 8 * 64);
      gld16(gB + (size_t)(j * 8) * C_ + k0, dB + j * 8 * 64);
    }
    __syncthreads();                   // compiler drains vmcnt(0) before barrier
#pragma unroll
    for (int ks = 0; ks < 2; ++ks) {
      bf16x8 af[4], bfv[4];
#pragma unroll
      for (int mi = 0; mi < 4; ++mi)
        af[mi] = *(const bf16x8*)&lA[(wr + mi * 16 + l15) * 64 + ks * 32 + g4 * 8];
#pragma unroll
      for (int ni = 0; ni < 4; ++ni)
        bfv[ni] = *(const bf16x8*)&lB[(wc + ni * 16 + l15) * 64 + ks * 32 + g4 * 8];
#pragma unroll
      for (int mi = 0; mi < 4; ++mi)
#pragma unroll
        for (int ni = 0; ni < 4; ++ni)
          acc[mi][ni] = __builtin_amdgcn_mfma_f32_16x16x32_bf16(af[mi], bfv[ni],
                                                                acc[mi][ni], 0, 0, 0);
    }
  }
}

// ---------------- GEMM1: qkv = x @ w_attn + b_attn, fused RoPE, split to q/k/v ----------
// 1D grid + bijective XCD swizzle (768 = 8 XCD x 96; n-major chunks for B-panel L2 reuse)
__global__ __launch_bounds__(256) void qkv_gemm(const bf16_t* __restrict__ x,
                                                const bf16_t* __restrict__ wT,
                                                const float* __restrict__ bias,
                                                const float2* __restrict__ rtab,
                                                bf16_t* __restrict__ qo,
                                                bf16_t* __restrict__ ko,
                                                bf16_t* __restrict__ vo) {
  __shared__ __align__(16) bf16_t smem[2 * 128 * 64];   // lA|lB, reused as store stage
  f32x4 acc[4][4];
  const int bid = blockIdx.x;
  const int swz = (bid & 7) * 96 + (bid >> 3);
  const int m0 = (swz & 31) * 128, n0 = (swz >> 5) * 128;
  gemm_core(x, wT, m0, n0, smem, smem + 128 * 64, acc);

  const int t = threadIdx.x;
  const int lane = t & 63, w = t >> 6;
  const int wr = (w >> 1) * 64, wc = (w & 1) * 64;
  const int l15 = lane & 15, g4 = lane >> 4;
  const int ng  = n0 + wc;              // 64-aligned -> single (sel, head) per wave
  const int sel = ng >> 10;
  const int h   = (ng & 1023) >> 6;

  __syncthreads();                      // all waves done reading lA/lB
  bf16_t* stg = smem + w * (64 * 64);   // per-wave 64x64 stage (disjoint regions)

  if (sel < 2) {
    // q: fold D^-0.5 AND log2(e) (attn uses exp2f)
    const float qs = (sel == 0) ? 0.125f * 1.4426950408889634f : 1.0f;
#pragma unroll
    for (int mi = 0; mi < 4; ++mi) {
#pragma unroll
      for (int ni = 0; ni < 2; ++ni) {
        const int d1 = ni * 16 + l15;        // 0..31; partner is d1+32 (frag ni+2)
        const float b1 = bias[ng + d1];
        const float b2 = bias[ng + d1 + 32];
#pragma unroll
        for (int r = 0; r < 4; ++r) {
          const int lrow = mi * 16 + g4 * 4 + r;
          const int tpos = (m0 + wr + lrow) & (T_ - 1);
          const float2 cs = rtab[tpos * 32 + d1];
          const float x1 = acc[mi][ni][r]     + b1;
          const float x2 = acc[mi][ni + 2][r] + b2;
          stg[lrow * 64 + d1]      = f2bf((x1 * cs.x - x2 * cs.y) * qs);
          stg[lrow * 64 + d1 + 32] = f2bf((x1 * cs.y + x2 * cs.x) * qs);
        }
      }
    }
  } else {
#pragma unroll
    for (int mi = 0; mi < 4; ++mi)
#pragma unroll
      for (int ni = 0; ni < 4; ++ni) {
        const int d = ni * 16 + l15;
        const float b1 = bias[ng + d];
#pragma unroll
        for (int r = 0; r < 4; ++r)
          stg[(mi * 16 + g4 * 4 + r) * 64 + d] = f2bf(acc[mi][ni][r] + b1);
      }
  }

  // readback own region (intra-wave dep only) + 1KB-per-instruction stores
  bf16_t* outp = (sel == 0) ? qo : (sel == 1 ? ko : vo);
  const int a  = lane >> 3;        // row-in-group 0..7
  const int b8 = (lane & 7) * 8;   // col chunk (x8 bf16 = 16B)
#pragma unroll
  for (int p = 0; p < 8; ++p) {
    const int lrow = p * 8 + a;
    const int row  = m0 + wr + lrow;
    const int tpos = row & (T_ - 1);
    const int bb   = row >> 11;
    uint4 val = *(const uint4*)&stg[lrow * 64 + b8];
    *(uint4*)(outp + ((size_t)(bb * H_ + h) * T_ + tpos) * D_ + b8) = val;
  }
}

// ---- flash attention, swapped-QK: 128 q-rows (8 waves x 16), KBLK=64 ----
// 512 threads: per-tile staging spread over 2x the threads AND block-tile count
// halved vs QBLK=64 -> per-(q,key) staging cost ~2x lower (r9 PMC: staging was
// the VALU/LDS bound). Grid 512 = {j,p,bh}: qt = j?15-p:p -> co-resident CU pair
// {c, c+256} has constant work (34 tile-units) and the SAME head (K/V L2 reuse).
// Ks: unpadded [64][64] + XOR swizzle. Vt: kappa-slot layout, in-lane P frags.
// Defer-max THR=8 (exp2 domain). Last tile: waves 0-3 fully masked -> skip compute.
__global__ __launch_bounds__(512) void attn_fwd(const bf16_t* __restrict__ q,
                                                const bf16_t* __restrict__ k,
                                                const bf16_t* __restrict__ v,
                                                bf16_t* __restrict__ y) {
  __shared__ __align__(16) bf16_t Ks[64 * 64];         // K rows [key][d], XOR-swizzled
  __shared__ __align__(16) bf16_t Vt[64 * PLD];        // V^T [d][slot(kappa,d)]
  const int t = threadIdx.x;
  const int lane = t & 63, w = t >> 6;                 // w: 0..7
  const int l15 = lane & 15, g4 = lane >> 4;

  const int f   = blockIdx.x;
  const int idx = f & 255;
  const int bh  = idx & 31;
  const int p   = idx >> 5;                            // 0..7
  const int qt  = (f >> 8) ? (15 - p) : p;             // bijective over 0..15
  const int qb  = qt * 128;
  const size_t hb = (size_t)bh * T_ * D_;

  const int qrow = qb + w * 16 + l15;
  bf16x8 qf[2];
  qf[0] = *(const bf16x8*)(q + hb + (size_t)qrow * D_ + g4 * 8);
  qf[1] = *(const bf16x8*)(q + hb + (size_t)qrow * D_ + 32 + g4 * 8);

  const f32x4 z4 = {0.f, 0.f, 0.f, 0.f};
  f32x4 o[4];
#pragma unroll
  for (int i = 0; i < 4; ++i) o[i] = z4;
  float mx = -1e30f, L = 0.f;

  const int skk = t >> 3;                  // key row 0..63 (full tile, one pass)
  const int sd0 = (t & 7) * 8;
  const int u   = t & 7;                   // = (d>>3)&7 for all this thread's d rows
  const int ksw = sd0 ^ ((skk & 7) * 8);   // Ks swizzled col
  // kappa slot for key=skk: slot = 32*c1 + 8*g + 4*c0 + r  (c=skk>>4, g=(skk>>2)&3, r=skk&3)
  const int slot = ((skk >> 5) & 1) * 32 + ((skk >> 2) & 3) * 8 + ((skk >> 4) & 1) * 4 + (skk & 3);
  const int pos  = (((slot >> 3) ^ u) << 3) | (slot & 7);
  const int rowb = qb + w * 16 + g4 * 4;

  const int ntiles = 2 * qt + 2;

  // preload tile 0
  uint4 kv = *(const uint4*)(k + hb + (size_t)skk * D_ + sd0);
  uint4 vv = *(const uint4*)(v + hb + (size_t)skk * D_ + sd0);

  for (int it = 0; it < ntiles; ++it) {
    const int kb = it * 64;
    __syncthreads();
    *(uint4*)&Ks[skk * 64 + ksw] = kv;
    {
      const bf16_t* vb = (const bf16_t*)&vv;
#pragma unroll
      for (int i = 0; i < 8; ++i)
        Vt[(sd0 + i) * PLD + pos] = vb[i];
    }
    __syncthreads();

    if (it + 1 < ntiles) {
      const size_t nb = hb + (size_t)(kb + 64 + skk) * D_ + sd0;
      kv = *(const uint4*)(k + nb);
      vv = *(const uint4*)(v + nb);
    }

    const bool last = (it == ntiles - 1);
    if (last && w < 4) continue;          // rows < kb: fully masked tile (barriers stay aligned)

    // ---- QK^T swapped: s[c][r] = S[key=kb+c*16+g4*4+r][q=qrow] ----
    f32x4 s[4];
#pragma unroll
    for (int c = 0; c < 4; ++c) s[c] = z4;
#pragma unroll
    for (int ks = 0; ks < 2; ++ks)
#pragma unroll
      for (int c = 0; c < 4; ++c) {
        const int kr = c * 16 + l15;
        bf16x8 kf = *(const bf16x8*)&Ks[kr * 64 + ((ks * 32 + g4 * 8) ^ ((kr & 7) * 8))];
        s[c] = __builtin_amdgcn_mfma_f32_16x16x32_bf16(kf, qf[ks], s[c], 0, 0, 0);
      }

    // ---- causal mask: only the two diagonal-adjacent tiles can violate ----
    if (last || (it == ntiles - 2 && w < 4)) {
#pragma unroll
      for (int c = 0; c < 4; ++c)
#pragma unroll
        for (int r = 0; r < 4; ++r)
          if (kb + c * 16 + g4 * 4 + r > qrow) s[c][r] = -1e30f;
    }

    // ---- online softmax (exp2 domain; defer-max THR=8) ----
    float tm = -1e30f;
#pragma unroll
    for (int c = 0; c < 4; ++c)
#pragma unroll
      for (int r = 0; r < 4; ++r) tm = fmaxf(tm, s[c][r]);
    tm = fmaxf(tm, __shfl_xor(tm, 16));
    tm = fmaxf(tm, __shfl_xor(tm, 32));
    if (!__all(tm - mx <= 8.0f)) {        // wave-uniform; rare after warm-up
      const float mnew = fmaxf(mx, tm);
      const float sc = exp2f(mx - mnew);  // first tile: exp2(-inf)=0 zeroes L,o
      L *= sc;
      float scr[4];
#pragma unroll
      for (int r = 0; r < 4; ++r)
        scr[r] = __shfl(sc, (lane & 48) | (g4 * 4 + r));
#pragma unroll
      for (int nf = 0; nf < 4; ++nf)
#pragma unroll
        for (int r = 0; r < 4; ++r) o[nf][r] *= scr[r];
      mx = mnew;
    }
    float rs = 0.f;
#pragma unroll
    for (int c = 0; c < 4; ++c)
#pragma unroll
      for (int r = 0; r < 4; ++r) {
        s[c][r] = exp2f(s[c][r] - mx);    // bounded by 2^8
        rs += s[c][r];
      }
    rs += __shfl_xor(rs, 16);
    rs += __shfl_xor(rs, 32);
    L += rs;

    // ---- P -> PV A-fragments, in-lane (kappa ordering) ----
    bf16x8 ap0, ap1;
#pragma unroll
    for (int r = 0; r < 4; ++r) {
      ap0[r]     = f2bf(s[0][r]);
      ap0[4 + r] = f2bf(s[1][r]);
      ap1[r]     = f2bf(s[2][r]);
      ap1[4 + r] = f2bf(s[3][r]);
    }

    // ---- PV: o[q][d] += P V, keys in kappa order on both operands ----
#pragma unroll
    for (int nf = 0; nf < 4; ++nf) {
      const int d  = nf * 16 + l15;
      const int h3 = (2 * nf + (l15 >> 3)) & 7;   // (d>>3)&7
      bf16x8 vf0 = *(const bf16x8*)&Vt[d * PLD + ((g4 ^ h3) << 3)];
      bf16x8 vf1 = *(const bf16x8*)&Vt[d * PLD + (((g4 + 4) ^ h3) << 3)];
      o[nf] = __builtin_amdgcn_mfma_f32_16x16x32_bf16(ap0, vf0, o[nf], 0, 0, 0);
      o[nf] = __builtin_amdgcn_mfma_f32_16x16x32_bf16(ap1, vf1, o[nf], 0, 0, 0);
    }
  }

  const int bb = bh / H_, hh = bh % H_;
  float il[4];
#pragma unroll
  for (int r = 0; r < 4; ++r)
    il[r] = 1.0f / __shfl(L, (lane & 48) | (g4 * 4 + r));
#pragma unroll
  for (int nf = 0; nf < 4; ++nf)
#pragma unroll
    for (int r = 0; r < 4; ++r) {
      const int row = rowb + r;
      y[(size_t)(bb * T_ + row) * C_ + hh * D_ + nf * 16 + l15] = f2bf(o[nf][r] * il[r]);
    }
}

// ---------------- GEMM2: out = y @ w_proj + b_proj (fp32 out) ----------------
// 1D grid + XCD swizzle (256 = 8 XCD x 32; one n-tile per XCD)
__global__ __launch_bounds__(256) void proj_gemm(const bf16_t* __restrict__ yin,
                                                 const bf16_t* __restrict__ wT,
                                                 const float* __restrict__ bias,
                                                 float* __restrict__ out) {
  __shared__ __align__(16) bf16_t lA[128 * 64];
  __shared__ __align__(16) bf16_t lB[128 * 64];
  f32x4 acc[4][4];
  const int bid = blockIdx.x;
  const int swz = (bid & 7) * 32 + (bid >> 3);
  const int m0 = (swz & 31) * 128, n0 = (swz >> 5) * 128;
  gemm_core(yin, wT, m0, n0, lA, lB, acc);

  const int t = threadIdx.x;
  const int lane = t & 63, w = t >> 6;
  const int wr = (w >> 1) * 64, wc = (w & 1) * 64;
  const int l15 = lane & 15, g4 = lane >> 4;
  const int ng = n0 + wc;
#pragma unroll
  for (int mi = 0; mi < 4; ++mi) {
    const int rowb = m0 + wr + mi * 16 + g4 * 4;
#pragma unroll
    for (int ni = 0; ni < 4; ++ni) {
      const int n = ng + ni * 16 + l15;
      const float b1 = bias[n];
#pragma unroll
      for (int r = 0; r < 4; ++r)
        out[(size_t)(rowb + r) * C_ + n] = acc[mi][ni][r] + b1;
    }
  }
}

// ---------------- launch ----------------
extern "C" void kernel_launch(void* const* d_in, const int* in_sizes, int n_in,
                              void* d_out, int out_size, void* d_ws, size_t ws_size,
                              hipStream_t stream) {
  (void)in_sizes; (void)n_in; (void)out_size; (void)ws_size;
  const float* x      = (const float*)d_in[0];
  const float* w_attn = (const float*)d_in[1];
  const float* b_attn = (const float*)d_in[2];
  const float* w_proj = (const float*)d_in[3];
  const float* b_proj = (const float*)d_in[4];
  float* out = (float*)d_out;

  char* ws = (char*)d_ws;
  bf16_t* wTa = (bf16_t*)ws;  ws += (size_t)NQKV_ * C_ * 2;          // 6 MB
  bf16_t* wTp = (bf16_t*)ws;  ws += (size_t)C_ * C_ * 2;             // 2 MB
  bf16_t* qb  = (bf16_t*)ws;  ws += (size_t)B_ * H_ * T_ * D_ * 2;   // 8 MB
  bf16_t* kb  = (bf16_t*)ws;  ws += (size_t)B_ * H_ * T_ * D_ * 2;   // 8 MB
  bf16_t* vb  = (bf16_t*)ws;  ws += (size_t)B_ * H_ * T_ * D_ * 2;   // 8 MB
  bf16_t* yb  = (bf16_t*)ws;  ws += (size_t)B_ * T_ * C_ * 2;        // 8 MB
  float2* rtab = (float2*)ws; ws += (size_t)T_ * 32 * sizeof(float2);// 0.5 MB
  // x_bf aliases yb: x_bf is consumed by qkv_gemm (dispatch 4) strictly before
  // attn_fwd (dispatch 5) writes yb. Stream-ordered, deterministic.
  bf16_t* x_bf = yb;

  rope_tab_k<<<dim3(T_ * 32 / 256), 256, 0, stream>>>(rtab);
  transpose_f32_bf16<<<dim3(NQKV_ / 32, C_ / 32), 256, 0, stream>>>(w_attn, wTa, C_, NQKV_);
  transpose_f32_bf16<<<dim3(C_ / 32,   C_ / 32), 256, 0, stream>>>(w_proj, wTp, C_, C_);
  f32_to_bf16_k<<<dim3(M_ * C_ / (256 * 8)), 256, 0, stream>>>(x, x_bf);
  qkv_gemm<<<dim3((M_ / 128) * (NQKV_ / 128)), 256, 0, stream>>>(x_bf, wTa, b_attn, rtab, qb, kb, vb);
  attn_fwd<<<dim3(NQT2 * 32), 512, 0, stream>>>(qb, kb, vb, yb);
  proj_gemm<<<dim3((M_ / 128) * (C_ / 128)), 256, 0, stream>>>(yb, wTp, b_proj, out);
}

// Round 11
// 123.281 us; speedup vs baseline: 2.8050x; 1.1524x over previous
//
#include <hip/hip_runtime.h>
#include <hip/hip_bf16.h>

typedef __bf16 bf16_t;
typedef __bf16 bf16x8 __attribute__((ext_vector_type(8)));
typedef float f32x4 __attribute__((ext_vector_type(4)));
typedef float f32x8v __attribute__((ext_vector_type(8)));

#define B_    2
#define T_    2048
#define C_    1024
#define H_    16
#define D_    64
#define M_    4096      // B*T
#define NQKV_ 3072
#define PLD   72        // attn V^T LDS row stride
#define NQT2  16        // T_/128 q-tiles (attn)
#define GTILE (128 * 64)   // one GEMM LDS tile (elements)

static __device__ __forceinline__ float  bf2f(bf16_t x) { return (float)x; }
static __device__ __forceinline__ bf16_t f2bf(float x)  { return (bf16_t)x; }

// async global->LDS, 16B per lane; LDS dest is wave-uniform base + lane*16 (HW rule)
typedef const __attribute__((address_space(1))) void gas_void;
typedef __attribute__((address_space(3))) void las_void;
static __device__ __forceinline__ void gld16(const void* g, void* l) {
  __builtin_amdgcn_global_load_lds((gas_void*)g, (las_void*)l, 16, 0, 0);
}

// ---------------- RoPE cos/sin table: [T][32] float2 ----------------
__global__ __launch_bounds__(256) void rope_tab_k(float2* __restrict__ tab) {
  int i = blockIdx.x * 256 + threadIdx.x;      // < T_*32
  int tpos = i >> 5, d = i & 31;
  float fr = exp2f(-(float)d * (13.287712379549449f / 32.0f));  // 10000^(-d/32)
  float ang = (float)tpos * fr;
  tab[i] = make_float2(cosf(ang), sinf(ang));
}

// ---------------- x: fp32 -> bf16 bulk convert ----------------
__global__ __launch_bounds__(256) void f32_to_bf16_k(const float* __restrict__ in,
                                                     bf16_t* __restrict__ out) {
  const int i = (blockIdx.x * 256 + threadIdx.x) * 8;
  f32x8v v = *(const f32x8v*)(in + i);
  bf16x8 h;
#pragma unroll
  for (int j = 0; j < 8; ++j) h[j] = f2bf(v[j]);
  *(bf16x8*)(out + i) = h;
}

// ---------------- transpose + fp32->bf16 (in: R x Ccols fp32 -> out: Ccols x R bf16) ----
__global__ __launch_bounds__(256) void transpose_f32_bf16(const float* __restrict__ in,
                                                          bf16_t* __restrict__ out,
                                                          int R, int Ccols) {
  __shared__ bf16_t tile[32][33];
  int tx = threadIdx.x & 31, ty = threadIdx.x >> 5;
  int c0 = blockIdx.x * 32, r0 = blockIdx.y * 32;
#pragma unroll
  for (int j = 0; j < 4; ++j)
    tile[ty + j * 8][tx] = f2bf(in[(size_t)(r0 + ty + j * 8) * Ccols + c0 + tx]);
  __syncthreads();
#pragma unroll
  for (int j = 0; j < 4; ++j)
    out[(size_t)(c0 + ty + j * 8) * R + r0 + tx] = tile[tx][ty + j * 8];
}

// ------- 128x128 MFMA GEMM core, 2-phase prefetch (T3-minimum): double-buffered
// ------- global_load_lds(16B) staging; next tile's loads issued BEFORE compute so
// ------- the per-K-step __syncthreads vmcnt-drain waits only the residual latency.
// ------- sm layout: [buf0A | buf0B | buf1A | buf1B], each GTILE elements (64KB total).
__device__ __forceinline__ void gemm_core(const bf16_t* __restrict__ A,
                                          const bf16_t* __restrict__ Bt,
                                          int m0, int n0,
                                          bf16_t* sm,
                                          f32x4 acc[4][4]) {
  const int t    = threadIdx.x;
  const int lane = t & 63, w = t >> 6;
  const int wr = (w >> 1) * 64, wc = (w & 1) * 64;
  const int l15 = lane & 15, g4 = lane >> 4;

  const f32x4 z4 = {0.f, 0.f, 0.f, 0.f};
#pragma unroll
  for (int i = 0; i < 4; ++i)
#pragma unroll
    for (int j = 0; j < 4; ++j) acc[i][j] = z4;

  // wave w stages rows [w*32, w*32+32) of each tile; per stage: 8 rows x 128B = 1KB/lane-group
  const int srow = w * 32 + (lane >> 3);
  const int sel8 = (lane & 7) * 8;
  const bf16_t* gA = A  + (size_t)(m0 + srow) * C_ + sel8;
  const bf16_t* gB = Bt + (size_t)(n0 + srow) * C_ + sel8;
  const int dOff = (w * 32) * 64;      // wave-uniform within-tile LDS offset

  // prologue: stage tile 0 into buffer 0
#pragma unroll
  for (int j = 0; j < 4; ++j) {
    gld16(gA + (size_t)(j * 8) * C_, sm + dOff + j * 8 * 64);
    gld16(gB + (size_t)(j * 8) * C_, sm + GTILE + dOff + j * 8 * 64);
  }
  __syncthreads();

  int cur = 0;
  for (int kt = 0; kt < C_ / 64; ++kt) {
    // issue next tile's loads early (into the other buffer) -> overlap with compute
    if (kt + 1 < C_ / 64) {
      const int k0 = (kt + 1) * 64;
      bf16_t* nA = sm + (cur ^ 1) * (2 * GTILE);
      bf16_t* nB = nA + GTILE;
#pragma unroll
      for (int j = 0; j < 4; ++j) {
        gld16(gA + (size_t)(j * 8) * C_ + k0, nA + dOff + j * 8 * 64);
        gld16(gB + (size_t)(j * 8) * C_ + k0, nB + dOff + j * 8 * 64);
      }
    }
    const bf16_t* lA = sm + cur * (2 * GTILE);
    const bf16_t* lB = lA + GTILE;
#pragma unroll
    for (int ks = 0; ks < 2; ++ks) {
      bf16x8 af[4], bfv[4];
#pragma unroll
      for (int mi = 0; mi < 4; ++mi)
        af[mi] = *(const bf16x8*)&lA[(wr + mi * 16 + l15) * 64 + ks * 32 + g4 * 8];
#pragma unroll
      for (int ni = 0; ni < 4; ++ni)
        bfv[ni] = *(const bf16x8*)&lB[(wc + ni * 16 + l15) * 64 + ks * 32 + g4 * 8];
#pragma unroll
      for (int mi = 0; mi < 4; ++mi)
#pragma unroll
        for (int ni = 0; ni < 4; ++ni)
          acc[mi][ni] = __builtin_amdgcn_mfma_f32_16x16x32_bf16(af[mi], bfv[ni],
                                                                acc[mi][ni], 0, 0, 0);
    }
    __syncthreads();      // drains vmcnt (prefetch residual) + protects buffer swap
    cur ^= 1;
  }
}

// ---------------- GEMM1: qkv = x @ w_attn + b_attn, fused RoPE, split to q/k/v ----------
// 1D grid + bijective XCD swizzle (768 = 8 XCD x 96; n-major chunks for B-panel L2 reuse)
__global__ __launch_bounds__(256) void qkv_gemm(const bf16_t* __restrict__ x,
                                                const bf16_t* __restrict__ wT,
                                                const float* __restrict__ bias,
                                                const float2* __restrict__ rtab,
                                                bf16_t* __restrict__ qo,
                                                bf16_t* __restrict__ ko,
                                                bf16_t* __restrict__ vo) {
  __shared__ __align__(16) bf16_t smem[4 * GTILE];   // dbuf tiles; reused as store stage
  f32x4 acc[4][4];
  const int bid = blockIdx.x;
  const int swz = (bid & 7) * 96 + (bid >> 3);
  const int m0 = (swz & 31) * 128, n0 = (swz >> 5) * 128;
  gemm_core(x, wT, m0, n0, smem, acc);

  const int t = threadIdx.x;
  const int lane = t & 63, w = t >> 6;
  const int wr = (w >> 1) * 64, wc = (w & 1) * 64;
  const int l15 = lane & 15, g4 = lane >> 4;
  const int ng  = n0 + wc;              // 64-aligned -> single (sel, head) per wave
  const int sel = ng >> 10;
  const int h   = (ng & 1023) >> 6;

  __syncthreads();                      // all waves done reading LDS tiles
  bf16_t* stg = smem + w * (64 * 64);   // per-wave 64x64 stage (disjoint regions)

  if (sel < 2) {
    // q: fold D^-0.5 AND log2(e) (attn uses exp2f)
    const float qs = (sel == 0) ? 0.125f * 1.4426950408889634f : 1.0f;
#pragma unroll
    for (int mi = 0; mi < 4; ++mi) {
#pragma unroll
      for (int ni = 0; ni < 2; ++ni) {
        const int d1 = ni * 16 + l15;        // 0..31; partner is d1+32 (frag ni+2)
        const float b1 = bias[ng + d1];
        const float b2 = bias[ng + d1 + 32];
#pragma unroll
        for (int r = 0; r < 4; ++r) {
          const int lrow = mi * 16 + g4 * 4 + r;
          const int tpos = (m0 + wr + lrow) & (T_ - 1);
          const float2 cs = rtab[tpos * 32 + d1];
          const float x1 = acc[mi][ni][r]     + b1;
          const float x2 = acc[mi][ni + 2][r] + b2;
          stg[lrow * 64 + d1]      = f2bf((x1 * cs.x - x2 * cs.y) * qs);
          stg[lrow * 64 + d1 + 32] = f2bf((x1 * cs.y + x2 * cs.x) * qs);
        }
      }
    }
  } else {
#pragma unroll
    for (int mi = 0; mi < 4; ++mi)
#pragma unroll
      for (int ni = 0; ni < 4; ++ni) {
        const int d = ni * 16 + l15;
        const float b1 = bias[ng + d];
#pragma unroll
        for (int r = 0; r < 4; ++r)
          stg[(mi * 16 + g4 * 4 + r) * 64 + d] = f2bf(acc[mi][ni][r] + b1);
      }
  }

  // readback own region (intra-wave dep only) + 1KB-per-instruction stores
  bf16_t* outp = (sel == 0) ? qo : (sel == 1 ? ko : vo);
  const int a  = lane >> 3;        // row-in-group 0..7
  const int b8 = (lane & 7) * 8;   // col chunk (x8 bf16 = 16B)
#pragma unroll
  for (int p = 0; p < 8; ++p) {
    const int lrow = p * 8 + a;
    const int row  = m0 + wr + lrow;
    const int tpos = row & (T_ - 1);
    const int bb   = row >> 11;
    uint4 val = *(const uint4*)&stg[lrow * 64 + b8];
    *(uint4*)(outp + ((size_t)(bb * H_ + h) * T_ + tpos) * D_ + b8) = val;
  }
}

// ---- flash attention, swapped-QK: 128 q-rows (8 waves x 16), KBLK=64 ----
// (unchanged from round 10 — verified at < 67 us)
__global__ __launch_bounds__(512) void attn_fwd(const bf16_t* __restrict__ q,
                                                const bf16_t* __restrict__ k,
                                                const bf16_t* __restrict__ v,
                                                bf16_t* __restrict__ y) {
  __shared__ __align__(16) bf16_t Ks[64 * 64];         // K rows [key][d], XOR-swizzled
  __shared__ __align__(16) bf16_t Vt[64 * PLD];        // V^T [d][slot(kappa,d)]
  const int t = threadIdx.x;
  const int lane = t & 63, w = t >> 6;                 // w: 0..7
  const int l15 = lane & 15, g4 = lane >> 4;

  const int f   = blockIdx.x;
  const int idx = f & 255;
  const int bh  = idx & 31;
  const int p   = idx >> 5;                            // 0..7
  const int qt  = (f >> 8) ? (15 - p) : p;             // bijective over 0..15
  const int qb  = qt * 128;
  const size_t hb = (size_t)bh * T_ * D_;

  const int qrow = qb + w * 16 + l15;
  bf16x8 qf[2];
  qf[0] = *(const bf16x8*)(q + hb + (size_t)qrow * D_ + g4 * 8);
  qf[1] = *(const bf16x8*)(q + hb + (size_t)qrow * D_ + 32 + g4 * 8);

  const f32x4 z4 = {0.f, 0.f, 0.f, 0.f};
  f32x4 o[4];
#pragma unroll
  for (int i = 0; i < 4; ++i) o[i] = z4;
  float mx = -1e30f, L = 0.f;

  const int skk = t >> 3;                  // key row 0..63 (full tile, one pass)
  const int sd0 = (t & 7) * 8;
  const int u   = t & 7;                   // = (d>>3)&7 for all this thread's d rows
  const int ksw = sd0 ^ ((skk & 7) * 8);   // Ks swizzled col
  // kappa slot for key=skk: slot = 32*c1 + 8*g + 4*c0 + r
  const int slot = ((skk >> 5) & 1) * 32 + ((skk >> 2) & 3) * 8 + ((skk >> 4) & 1) * 4 + (skk & 3);
  const int pos  = (((slot >> 3) ^ u) << 3) | (slot & 7);
  const int rowb = qb + w * 16 + g4 * 4;

  const int ntiles = 2 * qt + 2;

  // preload tile 0
  uint4 kv = *(const uint4*)(k + hb + (size_t)skk * D_ + sd0);
  uint4 vv = *(const uint4*)(v + hb + (size_t)skk * D_ + sd0);

  for (int it = 0; it < ntiles; ++it) {
    const int kb = it * 64;
    __syncthreads();
    *(uint4*)&Ks[skk * 64 + ksw] = kv;
    {
      const bf16_t* vb = (const bf16_t*)&vv;
#pragma unroll
      for (int i = 0; i < 8; ++i)
        Vt[(sd0 + i) * PLD + pos] = vb[i];
    }
    __syncthreads();

    if (it + 1 < ntiles) {
      const size_t nb = hb + (size_t)(kb + 64 + skk) * D_ + sd0;
      kv = *(const uint4*)(k + nb);
      vv = *(const uint4*)(v + nb);
    }

    const bool last = (it == ntiles - 1);
    if (last && w < 4) continue;          // rows < kb: fully masked tile (barriers stay aligned)

    // ---- QK^T swapped: s[c][r] = S[key=kb+c*16+g4*4+r][q=qrow] ----
    f32x4 s[4];
#pragma unroll
    for (int c = 0; c < 4; ++c) s[c] = z4;
#pragma unroll
    for (int ks = 0; ks < 2; ++ks)
#pragma unroll
      for (int c = 0; c < 4; ++c) {
        const int kr = c * 16 + l15;
        bf16x8 kf = *(const bf16x8*)&Ks[kr * 64 + ((ks * 32 + g4 * 8) ^ ((kr & 7) * 8))];
        s[c] = __builtin_amdgcn_mfma_f32_16x16x32_bf16(kf, qf[ks], s[c], 0, 0, 0);
      }

    // ---- causal mask: only the two diagonal-adjacent tiles can violate ----
    if (last || (it == ntiles - 2 && w < 4)) {
#pragma unroll
      for (int c = 0; c < 4; ++c)
#pragma unroll
        for (int r = 0; r < 4; ++r)
          if (kb + c * 16 + g4 * 4 + r > qrow) s[c][r] = -1e30f;
    }

    // ---- online softmax (exp2 domain; defer-max THR=8) ----
    float tm = -1e30f;
#pragma unroll
    for (int c = 0; c < 4; ++c)
#pragma unroll
      for (int r = 0; r < 4; ++r) tm = fmaxf(tm, s[c][r]);
    tm = fmaxf(tm, __shfl_xor(tm, 16));
    tm = fmaxf(tm, __shfl_xor(tm, 32));
    if (!__all(tm - mx <= 8.0f)) {        // wave-uniform; rare after warm-up
      const float mnew = fmaxf(mx, tm);
      const float sc = exp2f(mx - mnew);  // first tile: exp2(-inf)=0 zeroes L,o
      L *= sc;
      float scr[4];
#pragma unroll
      for (int r = 0; r < 4; ++r)
        scr[r] = __shfl(sc, (lane & 48) | (g4 * 4 + r));
#pragma unroll
      for (int nf = 0; nf < 4; ++nf)
#pragma unroll
        for (int r = 0; r < 4; ++r) o[nf][r] *= scr[r];
      mx = mnew;
    }
    float rs = 0.f;
#pragma unroll
    for (int c = 0; c < 4; ++c)
#pragma unroll
      for (int r = 0; r < 4; ++r) {
        s[c][r] = exp2f(s[c][r] - mx);    // bounded by 2^8
        rs += s[c][r];
      }
    rs += __shfl_xor(rs, 16);
    rs += __shfl_xor(rs, 32);
    L += rs;

    // ---- P -> PV A-fragments, in-lane (kappa ordering) ----
    bf16x8 ap0, ap1;
#pragma unroll
    for (int r = 0; r < 4; ++r) {
      ap0[r]     = f2bf(s[0][r]);
      ap0[4 + r] = f2bf(s[1][r]);
      ap1[r]     = f2bf(s[2][r]);
      ap1[4 + r] = f2bf(s[3][r]);
    }

    // ---- PV: o[q][d] += P V, keys in kappa order on both operands ----
#pragma unroll
    for (int nf = 0; nf < 4; ++nf) {
      const int d  = nf * 16 + l15;
      const int h3 = (2 * nf + (l15 >> 3)) & 7;   // (d>>3)&7
      bf16x8 vf0 = *(const bf16x8*)&Vt[d * PLD + ((g4 ^ h3) << 3)];
      bf16x8 vf1 = *(const bf16x8*)&Vt[d * PLD + (((g4 + 4) ^ h3) << 3)];
      o[nf] = __builtin_amdgcn_mfma_f32_16x16x32_bf16(ap0, vf0, o[nf], 0, 0, 0);
      o[nf] = __builtin_amdgcn_mfma_f32_16x16x32_bf16(ap1, vf1, o[nf], 0, 0, 0);
    }
  }

  const int bb = bh / H_, hh = bh % H_;
  float il[4];
#pragma unroll
  for (int r = 0; r < 4; ++r)
    il[r] = 1.0f / __shfl(L, (lane & 48) | (g4 * 4 + r));
#pragma unroll
  for (int nf = 0; nf < 4; ++nf)
#pragma unroll
    for (int r = 0; r < 4; ++r) {
      const int row = rowb + r;
      y[(size_t)(bb * T_ + row) * C_ + hh * D_ + nf * 16 + l15] = f2bf(o[nf][r] * il[r]);
    }
}

// ---------------- GEMM2: out = y @ w_proj + b_proj (fp32 out) ----------------
// 1D grid + XCD swizzle (256 = 8 XCD x 32; one n-tile per XCD)
__global__ __launch_bounds__(256) void proj_gemm(const bf16_t* __restrict__ yin,
                                                 const bf16_t* __restrict__ wT,
                                                 const float* __restrict__ bias,
                                                 float* __restrict__ out) {
  __shared__ __align__(16) bf16_t smem[4 * GTILE];
  f32x4 acc[4][4];
  const int bid = blockIdx.x;
  const int swz = (bid & 7) * 32 + (bid >> 3);
  const int m0 = (swz & 31) * 128, n0 = (swz >> 5) * 128;
  gemm_core(yin, wT, m0, n0, smem, acc);

  const int t = threadIdx.x;
  const int lane = t & 63, w = t >> 6;
  const int wr = (w >> 1) * 64, wc = (w & 1) * 64;
  const int l15 = lane & 15, g4 = lane >> 4;
  const int ng = n0 + wc;
#pragma unroll
  for (int mi = 0; mi < 4; ++mi) {
    const int rowb = m0 + wr + mi * 16 + g4 * 4;
#pragma unroll
    for (int ni = 0; ni < 4; ++ni) {
      const int n = ng + ni * 16 + l15;
      const float b1 = bias[n];
#pragma unroll
      for (int r = 0; r < 4; ++r)
        out[(size_t)(rowb + r) * C_ + n] = acc[mi][ni][r] + b1;
    }
  }
}

// ---------------- launch ----------------
extern "C" void kernel_launch(void* const* d_in, const int* in_sizes, int n_in,
                              void* d_out, int out_size, void* d_ws, size_t ws_size,
                              hipStream_t stream) {
  (void)in_sizes; (void)n_in; (void)out_size; (void)ws_size;
  const float* x      = (const float*)d_in[0];
  const float* w_attn = (const float*)d_in[1];
  const float* b_attn = (const float*)d_in[2];
  const float* w_proj = (const float*)d_in[3];
  const float* b_proj = (const float*)d_in[4];
  float* out = (float*)d_out;

  char* ws = (char*)d_ws;
  bf16_t* wTa = (bf16_t*)ws;  ws += (size_t)NQKV_ * C_ * 2;          // 6 MB
  bf16_t* wTp = (bf16_t*)ws;  ws += (size_t)C_ * C_ * 2;             // 2 MB
  bf16_t* qb  = (bf16_t*)ws;  ws += (size_t)B_ * H_ * T_ * D_ * 2;   // 8 MB
  bf16_t* kb  = (bf16_t*)ws;  ws += (size_t)B_ * H_ * T_ * D_ * 2;   // 8 MB
  bf16_t* vb  = (bf16_t*)ws;  ws += (size_t)B_ * H_ * T_ * D_ * 2;   // 8 MB
  bf16_t* yb  = (bf16_t*)ws;  ws += (size_t)B_ * T_ * C_ * 2;        // 8 MB
  float2* rtab = (float2*)ws; ws += (size_t)T_ * 32 * sizeof(float2);// 0.5 MB
  // x_bf aliases yb: x_bf is consumed by qkv_gemm (dispatch 4) strictly before
  // attn_fwd (dispatch 5) writes yb. Stream-ordered, deterministic.
  bf16_t* x_bf = yb;

  rope_tab_k<<<dim3(T_ * 32 / 256), 256, 0, stream>>>(rtab);
  transpose_f32_bf16<<<dim3(NQKV_ / 32, C_ / 32), 256, 0, stream>>>(w_attn, wTa, C_, NQKV_);
  transpose_f32_bf16<<<dim3(C_ / 32,   C_ / 32), 256, 0, stream>>>(w_proj, wTp, C_, C_);
  f32_to_bf16_k<<<dim3(M_ * C_ / (256 * 8)), 256, 0, stream>>>(x, x_bf);
  qkv_gemm<<<dim3((M_ / 128) * (NQKV_ / 128)), 256, 0, stream>>>(x_bf, wTa, b_attn, rtab, qb, kb, vb);
  attn_fwd<<<dim3(NQT2 * 32), 512, 0, stream>>>(qb, kb, vb, yb);
  proj_gemm<<<dim3((M_ / 128) * (C_ / 128)), 256, 0, stream>>>(yb, wTp, b_proj, out);
}

// Round 12
// 118.340 us; speedup vs baseline: 2.9221x; 1.0418x over previous
//
#include <hip/hip_runtime.h>
#include <hip/hip_bf16.h>

typedef __bf16 bf16_t;
typedef __bf16 bf16x8 __attribute__((ext_vector_type(8)));
typedef float f32x4 __attribute__((ext_vector_type(4)));
typedef float f32x8v __attribute__((ext_vector_type(8)));

#define B_    2
#define T_    2048
#define C_    1024
#define H_    16
#define D_    64
#define M_    4096      // B*T
#define NQKV_ 3072
#define PLD   72        // attn V^T LDS row stride
#define NQT2  16        // T_/128 q-tiles (attn)
#define GTILE (128 * 64)   // proj GEMM LDS tile (elements)
#define SLOTE 16384        // qkv ring slot elements (A 256x32 + B 256x32)

static __device__ __forceinline__ float  bf2f(bf16_t x) { return (float)x; }
static __device__ __forceinline__ bf16_t f2bf(float x)  { return (bf16_t)x; }

// async global->LDS, 16B per lane; LDS dest is wave-uniform base + lane*16 (HW rule)
typedef const __attribute__((address_space(1))) void gas_void;
typedef __attribute__((address_space(3))) void las_void;
static __device__ __forceinline__ void gld16(const void* g, void* l) {
  __builtin_amdgcn_global_load_lds((gas_void*)g, (las_void*)l, 16, 0, 0);
}

// ---------------- RoPE cos/sin table: [T][32] float2 ----------------
__global__ __launch_bounds__(256) void rope_tab_k(float2* __restrict__ tab) {
  int i = blockIdx.x * 256 + threadIdx.x;      // < T_*32
  int tpos = i >> 5, d = i & 31;
  float fr = exp2f(-(float)d * (13.287712379549449f / 32.0f));  // 10000^(-d/32)
  float ang = (float)tpos * fr;
  tab[i] = make_float2(cosf(ang), sinf(ang));
}

// ---------------- x: fp32 -> bf16 bulk convert ----------------
__global__ __launch_bounds__(256) void f32_to_bf16_k(const float* __restrict__ in,
                                                     bf16_t* __restrict__ out) {
  const int i = (blockIdx.x * 256 + threadIdx.x) * 8;
  f32x8v v = *(const f32x8v*)(in + i);
  bf16x8 h;
#pragma unroll
  for (int j = 0; j < 8; ++j) h[j] = f2bf(v[j]);
  *(bf16x8*)(out + i) = h;
}

// ---------------- transpose + fp32->bf16 (in: R x Ccols fp32 -> out: Ccols x R bf16) ----
__global__ __launch_bounds__(256) void transpose_f32_bf16(const float* __restrict__ in,
                                                          bf16_t* __restrict__ out,
                                                          int R, int Ccols) {
  __shared__ bf16_t tile[32][33];
  int tx = threadIdx.x & 31, ty = threadIdx.x >> 5;
  int c0 = blockIdx.x * 32, r0 = blockIdx.y * 32;
#pragma unroll
  for (int j = 0; j < 4; ++j)
    tile[ty + j * 8][tx] = f2bf(in[(size_t)(r0 + ty + j * 8) * Ccols + c0 + tx]);
  __syncthreads();
#pragma unroll
  for (int j = 0; j < 4; ++j)
    out[(size_t)(c0 + ty + j * 8) * R + r0 + tx] = tile[tx][ty + j * 8];
}

// ------- proj GEMM core (r11-verified): 128x128, dbuf global_load_lds, 2-barrier ----
__device__ __forceinline__ void gemm_core(const bf16_t* __restrict__ A,
                                          const bf16_t* __restrict__ Bt,
                                          int m0, int n0,
                                          bf16_t* sm,
                                          f32x4 acc[4][4]) {
  const int t    = threadIdx.x;
  const int lane = t & 63, w = t >> 6;
  const int wr = (w >> 1) * 64, wc = (w & 1) * 64;
  const int l15 = lane & 15, g4 = lane >> 4;

  const f32x4 z4 = {0.f, 0.f, 0.f, 0.f};
#pragma unroll
  for (int i = 0; i < 4; ++i)
#pragma unroll
    for (int j = 0; j < 4; ++j) acc[i][j] = z4;

  const int srow = w * 32 + (lane >> 3);
  const int sel8 = (lane & 7) * 8;
  const bf16_t* gA = A  + (size_t)(m0 + srow) * C_ + sel8;
  const bf16_t* gB = Bt + (size_t)(n0 + srow) * C_ + sel8;
  const int dOff = (w * 32) * 64;

#pragma unroll
  for (int j = 0; j < 4; ++j) {
    gld16(gA + (size_t)(j * 8) * C_, sm + dOff + j * 8 * 64);
    gld16(gB + (size_t)(j * 8) * C_, sm + GTILE + dOff + j * 8 * 64);
  }
  __syncthreads();

  int cur = 0;
  for (int kt = 0; kt < C_ / 64; ++kt) {
    if (kt + 1 < C_ / 64) {
      const int k0 = (kt + 1) * 64;
      bf16_t* nA = sm + (cur ^ 1) * (2 * GTILE);
      bf16_t* nB = nA + GTILE;
#pragma unroll
      for (int j = 0; j < 4; ++j) {
        gld16(gA + (size_t)(j * 8) * C_ + k0, nA + dOff + j * 8 * 64);
        gld16(gB + (size_t)(j * 8) * C_ + k0, nB + dOff + j * 8 * 64);
      }
    }
    const bf16_t* lA = sm + cur * (2 * GTILE);
    const bf16_t* lB = lA + GTILE;
#pragma unroll
    for (int ks = 0; ks < 2; ++ks) {
      bf16x8 af[4], bfv[4];
#pragma unroll
      for (int mi = 0; mi < 4; ++mi)
        af[mi] = *(const bf16x8*)&lA[(wr + mi * 16 + l15) * 64 + ks * 32 + g4 * 8];
#pragma unroll
      for (int ni = 0; ni < 4; ++ni)
        bfv[ni] = *(const bf16x8*)&lB[(wc + ni * 16 + l15) * 64 + ks * 32 + g4 * 8];
#pragma unroll
      for (int mi = 0; mi < 4; ++mi)
#pragma unroll
        for (int ni = 0; ni < 4; ++ni)
          acc[mi][ni] = __builtin_amdgcn_mfma_f32_16x16x32_bf16(af[mi], bfv[ni],
                                                                acc[mi][ni], 0, 0, 0);
    }
    __syncthreads();
    cur ^= 1;
  }
}

// ---------------- GEMM1: qkv, 256x256 tile, 4-slot LDS ring, counted vmcnt depth-2 ----
// 512 thr / 8 waves (2M x 4N), BK=32, 32 K-steps. Ring slot = A[256][32] + B[256][32].
// iter h: vmcnt(4) retires STAGE(h) (exactly 4 younger loads = STAGE(h+1); in-order
// retirement, m135) -> raw s_barrier -> issue STAGE(h+2) -> ds_read + 32 MFMA.
// Stage->consume = 2 iters (~2500cy) >> HBM latency -> wait ~free. Grid 192 = 8 XCD x 24.
__global__ __launch_bounds__(512, 2) void qkv_gemm(const bf16_t* __restrict__ x,
                                                   const bf16_t* __restrict__ wT,
                                                   const float* __restrict__ bias,
                                                   const float2* __restrict__ rtab,
                                                   bf16_t* __restrict__ qo,
                                                   bf16_t* __restrict__ ko,
                                                   bf16_t* __restrict__ vo) {
  __shared__ __align__(16) bf16_t sm[4 * SLOTE];       // 128 KB ring; reused as store stage
  const int t = threadIdx.x;
  const int lane = t & 63, w = t >> 6;                 // 8 waves
  const int l15 = lane & 15, g4 = lane >> 4;
  const int wr = (w >> 2) * 128, wc = (w & 3) * 64;    // 2M x 4N

  const int bid = blockIdx.x;                          // 192 = 16m x 12n tiles
  const int swz = (bid & 7) * 24 + (bid >> 3);         // XCD-chunked, n-major
  const int m0 = (swz & 15) * 256, n0 = (swz >> 4) * 256;

  const f32x4 z4 = {0.f, 0.f, 0.f, 0.f};
  f32x4 acc[8][4];
#pragma unroll
  for (int i = 0; i < 8; ++i)
#pragma unroll
    for (int j = 0; j < 4; ++j) acc[i][j] = z4;

  // staging: wave w covers rows w*32..w*32+31 of both A and B tiles
  const int sr  = (lane >> 2);            // 0..15 row within 16-row gld16 group
  const int sc8 = (lane & 3) * 8;         // k-chunk (16B)
  const bf16_t* gA = x  + (size_t)(m0 + w * 32 + sr) * C_ + sc8;
  const bf16_t* gB = wT + (size_t)(n0 + w * 32 + sr) * C_ + sc8;

#define QKV_STAGE(h)                                                            \
  {                                                                             \
    bf16_t* sl = sm + ((h) & 3) * SLOTE;                                        \
    const size_t kofs = (size_t)(h) * 32;                                       \
    gld16(gA + kofs,            sl + (w * 32) * 32);                            \
    gld16(gA + 16 * C_ + kofs,  sl + (w * 32 + 16) * 32);                       \
    gld16(gB + kofs,            sl + 8192 + (w * 32) * 32);                     \
    gld16(gB + 16 * C_ + kofs,  sl + 8192 + (w * 32 + 16) * 32);                \
  }

  QKV_STAGE(0);
  QKV_STAGE(1);

  for (int h = 0; h < 32; ++h) {
    if (h < 31) asm volatile("s_waitcnt vmcnt(4)" ::: "memory");
    else        asm volatile("s_waitcnt vmcnt(0)" ::: "memory");
    __builtin_amdgcn_sched_barrier(0);
    __builtin_amdgcn_s_barrier();
    __builtin_amdgcn_sched_barrier(0);
    if (h + 2 < 32) QKV_STAGE(h + 2);

    const bf16_t* sl = sm + (h & 3) * SLOTE;
    bf16x8 af[8], bfv[4];
#pragma unroll
    for (int mi = 0; mi < 8; ++mi)
      af[mi] = *(const bf16x8*)&sl[(wr + mi * 16 + l15) * 32 + g4 * 8];
#pragma unroll
    for (int ni = 0; ni < 4; ++ni)
      bfv[ni] = *(const bf16x8*)&sl[8192 + (wc + ni * 16 + l15) * 32 + g4 * 8];
#pragma unroll
    for (int mi = 0; mi < 8; ++mi)
#pragma unroll
      for (int ni = 0; ni < 4; ++ni)
        acc[mi][ni] = __builtin_amdgcn_mfma_f32_16x16x32_bf16(af[mi], bfv[ni],
                                                              acc[mi][ni], 0, 0, 0);
  }
#undef QKV_STAGE

  __syncthreads();                       // all compute done; reuse sm as store stage
  bf16_t* stg = sm + w * 8192;           // per-wave 128x64 stage

  const int ng  = n0 + wc;               // 64-aligned -> single (sel, head) per wave
  const int sel = ng >> 10;
  const int h2  = (ng & 1023) >> 6;

  if (sel < 2) {
    const float qs = (sel == 0) ? 0.125f * 1.4426950408889634f : 1.0f;
#pragma unroll
    for (int mi = 0; mi < 8; ++mi) {
#pragma unroll
      for (int ni = 0; ni < 2; ++ni) {
        const int d1 = ni * 16 + l15;
        const float b1 = bias[ng + d1];
        const float b2 = bias[ng + d1 + 32];
#pragma unroll
        for (int r = 0; r < 4; ++r) {
          const int lrow = mi * 16 + g4 * 4 + r;
          const int tpos = (m0 + wr + lrow) & (T_ - 1);
          const float2 cs = rtab[tpos * 32 + d1];
          const float x1 = acc[mi][ni][r]     + b1;
          const float x2 = acc[mi][ni + 2][r] + b2;
          stg[lrow * 64 + d1]      = f2bf((x1 * cs.x - x2 * cs.y) * qs);
          stg[lrow * 64 + d1 + 32] = f2bf((x1 * cs.y + x2 * cs.x) * qs);
        }
      }
    }
  } else {
#pragma unroll
    for (int mi = 0; mi < 8; ++mi)
#pragma unroll
      for (int ni = 0; ni < 4; ++ni) {
        const int d = ni * 16 + l15;
        const float b1 = bias[ng + d];
#pragma unroll
        for (int r = 0; r < 4; ++r)
          stg[(mi * 16 + g4 * 4 + r) * 64 + d] = f2bf(acc[mi][ni][r] + b1);
      }
  }

  bf16_t* outp = (sel == 0) ? qo : (sel == 1 ? ko : vo);
  const int a  = lane >> 3;
  const int b8 = (lane & 7) * 8;
#pragma unroll
  for (int p = 0; p < 16; ++p) {
    const int lrow = p * 8 + a;
    const int row  = m0 + wr + lrow;
    const int tpos = row & (T_ - 1);
    const int bb   = row >> 11;
    uint4 val = *(const uint4*)&stg[lrow * 64 + b8];
    *(uint4*)(outp + ((size_t)(bb * H_ + h2) * T_ + tpos) * D_ + b8) = val;
  }
}

// ---- flash attention, swapped-QK: 128 q-rows (8 waves x 16), KBLK=64 ----
// (unchanged from round 10 — verified, < 60 us)
__global__ __launch_bounds__(512) void attn_fwd(const bf16_t* __restrict__ q,
                                                const bf16_t* __restrict__ k,
                                                const bf16_t* __restrict__ v,
                                                bf16_t* __restrict__ y) {
  __shared__ __align__(16) bf16_t Ks[64 * 64];         // K rows [key][d], XOR-swizzled
  __shared__ __align__(16) bf16_t Vt[64 * PLD];        // V^T [d][slot(kappa,d)]
  const int t = threadIdx.x;
  const int lane = t & 63, w = t >> 6;                 // w: 0..7
  const int l15 = lane & 15, g4 = lane >> 4;

  const int f   = blockIdx.x;
  const int idx = f & 255;
  const int bh  = idx & 31;
  const int p   = idx >> 5;                            // 0..7
  const int qt  = (f >> 8) ? (15 - p) : p;             // bijective over 0..15
  const int qb  = qt * 128;
  const size_t hb = (size_t)bh * T_ * D_;

  const int qrow = qb + w * 16 + l15;
  bf16x8 qf[2];
  qf[0] = *(const bf16x8*)(q + hb + (size_t)qrow * D_ + g4 * 8);
  qf[1] = *(const bf16x8*)(q + hb + (size_t)qrow * D_ + 32 + g4 * 8);

  const f32x4 z4 = {0.f, 0.f, 0.f, 0.f};
  f32x4 o[4];
#pragma unroll
  for (int i = 0; i < 4; ++i) o[i] = z4;
  float mx = -1e30f, L = 0.f;

  const int skk = t >> 3;                  // key row 0..63 (full tile, one pass)
  const int sd0 = (t & 7) * 8;
  const int u   = t & 7;                   // = (d>>3)&7 for all this thread's d rows
  const int ksw = sd0 ^ ((skk & 7) * 8);   // Ks swizzled col
  // kappa slot for key=skk: slot = 32*c1 + 8*g + 4*c0 + r
  const int slot = ((skk >> 5) & 1) * 32 + ((skk >> 2) & 3) * 8 + ((skk >> 4) & 1) * 4 + (skk & 3);
  const int pos  = (((slot >> 3) ^ u) << 3) | (slot & 7);
  const int rowb = qb + w * 16 + g4 * 4;

  const int ntiles = 2 * qt + 2;

  // preload tile 0
  uint4 kv = *(const uint4*)(k + hb + (size_t)skk * D_ + sd0);
  uint4 vv = *(const uint4*)(v + hb + (size_t)skk * D_ + sd0);

  for (int it = 0; it < ntiles; ++it) {
    const int kb = it * 64;
    __syncthreads();
    *(uint4*)&Ks[skk * 64 + ksw] = kv;
    {
      const bf16_t* vb = (const bf16_t*)&vv;
#pragma unroll
      for (int i = 0; i < 8; ++i)
        Vt[(sd0 + i) * PLD + pos] = vb[i];
    }
    __syncthreads();

    if (it + 1 < ntiles) {
      const size_t nb = hb + (size_t)(kb + 64 + skk) * D_ + sd0;
      kv = *(const uint4*)(k + nb);
      vv = *(const uint4*)(v + nb);
    }

    const bool last = (it == ntiles - 1);
    if (last && w < 4) continue;          // rows < kb: fully masked tile (barriers stay aligned)

    // ---- QK^T swapped: s[c][r] = S[key=kb+c*16+g4*4+r][q=qrow] ----
    f32x4 s[4];
#pragma unroll
    for (int c = 0; c < 4; ++c) s[c] = z4;
#pragma unroll
    for (int ks = 0; ks < 2; ++ks)
#pragma unroll
      for (int c = 0; c < 4; ++c) {
        const int kr = c * 16 + l15;
        bf16x8 kf = *(const bf16x8*)&Ks[kr * 64 + ((ks * 32 + g4 * 8) ^ ((kr & 7) * 8))];
        s[c] = __builtin_amdgcn_mfma_f32_16x16x32_bf16(kf, qf[ks], s[c], 0, 0, 0);
      }

    // ---- causal mask: only the two diagonal-adjacent tiles can violate ----
    if (last || (it == ntiles - 2 && w < 4)) {
#pragma unroll
      for (int c = 0; c < 4; ++c)
#pragma unroll
        for (int r = 0; r < 4; ++r)
          if (kb + c * 16 + g4 * 4 + r > qrow) s[c][r] = -1e30f;
    }

    // ---- online softmax (exp2 domain; defer-max THR=8) ----
    float tm = -1e30f;
#pragma unroll
    for (int c = 0; c < 4; ++c)
#pragma unroll
      for (int r = 0; r < 4; ++r) tm = fmaxf(tm, s[c][r]);
    tm = fmaxf(tm, __shfl_xor(tm, 16));
    tm = fmaxf(tm, __shfl_xor(tm, 32));
    if (!__all(tm - mx <= 8.0f)) {        // wave-uniform; rare after warm-up
      const float mnew = fmaxf(mx, tm);
      const float sc = exp2f(mx - mnew);  // first tile: exp2(-inf)=0 zeroes L,o
      L *= sc;
      float scr[4];
#pragma unroll
      for (int r = 0; r < 4; ++r)
        scr[r] = __shfl(sc, (lane & 48) | (g4 * 4 + r));
#pragma unroll
      for (int nf = 0; nf < 4; ++nf)
#pragma unroll
        for (int r = 0; r < 4; ++r) o[nf][r] *= scr[r];
      mx = mnew;
    }
    float rs = 0.f;
#pragma unroll
    for (int c = 0; c < 4; ++c)
#pragma unroll
      for (int r = 0; r < 4; ++r) {
        s[c][r] = exp2f(s[c][r] - mx);    // bounded by 2^8
        rs += s[c][r];
      }
    rs += __shfl_xor(rs, 16);
    rs += __shfl_xor(rs, 32);
    L += rs;

    // ---- P -> PV A-fragments, in-lane (kappa ordering) ----
    bf16x8 ap0, ap1;
#pragma unroll
    for (int r = 0; r < 4; ++r) {
      ap0[r]     = f2bf(s[0][r]);
      ap0[4 + r] = f2bf(s[1][r]);
      ap1[r]     = f2bf(s[2][r]);
      ap1[4 + r] = f2bf(s[3][r]);
    }

    // ---- PV: o[q][d] += P V, keys in kappa order on both operands ----
#pragma unroll
    for (int nf = 0; nf < 4; ++nf) {
      const int d  = nf * 16 + l15;
      const int h3 = (2 * nf + (l15 >> 3)) & 7;   // (d>>3)&7
      bf16x8 vf0 = *(const bf16x8*)&Vt[d * PLD + ((g4 ^ h3) << 3)];
      bf16x8 vf1 = *(const bf16x8*)&Vt[d * PLD + (((g4 + 4) ^ h3) << 3)];
      o[nf] = __builtin_amdgcn_mfma_f32_16x16x32_bf16(ap0, vf0, o[nf], 0, 0, 0);
      o[nf] = __builtin_amdgcn_mfma_f32_16x16x32_bf16(ap1, vf1, o[nf], 0, 0, 0);
    }
  }

  const int bb = bh / H_, hh = bh % H_;
  float il[4];
#pragma unroll
  for (int r = 0; r < 4; ++r)
    il[r] = 1.0f / __shfl(L, (lane & 48) | (g4 * 4 + r));
#pragma unroll
  for (int nf = 0; nf < 4; ++nf)
#pragma unroll
    for (int r = 0; r < 4; ++r) {
      const int row = rowb + r;
      y[(size_t)(bb * T_ + row) * C_ + hh * D_ + nf * 16 + l15] = f2bf(o[nf][r] * il[r]);
    }
}

// ---------------- GEMM2: out = y @ w_proj + b_proj (fp32 out) ----------------
// 1D grid + XCD swizzle (256 = 8 XCD x 32; one n-tile per XCD)
__global__ __launch_bounds__(256) void proj_gemm(const bf16_t* __restrict__ yin,
                                                 const bf16_t* __restrict__ wT,
                                                 const float* __restrict__ bias,
                                                 float* __restrict__ out) {
  __shared__ __align__(16) bf16_t smem[4 * GTILE];
  f32x4 acc[4][4];
  const int bid = blockIdx.x;
  const int swz = (bid & 7) * 32 + (bid >> 3);
  const int m0 = (swz & 31) * 128, n0 = (swz >> 5) * 128;
  gemm_core(yin, wT, m0, n0, smem, acc);

  const int t = threadIdx.x;
  const int lane = t & 63, w = t >> 6;
  const int wr = (w >> 1) * 64, wc = (w & 1) * 64;
  const int l15 = lane & 15, g4 = lane >> 4;
  const int ng = n0 + wc;
#pragma unroll
  for (int mi = 0; mi < 4; ++mi) {
    const int rowb = m0 + wr + mi * 16 + g4 * 4;
#pragma unroll
    for (int ni = 0; ni < 4; ++ni) {
      const int n = ng + ni * 16 + l15;
      const float b1 = bias[n];
#pragma unroll
      for (int r = 0; r < 4; ++r)
        out[(size_t)(rowb + r) * C_ + n] = acc[mi][ni][r] + b1;
    }
  }
}

// ---------------- launch ----------------
extern "C" void kernel_launch(void* const* d_in, const int* in_sizes, int n_in,
                              void* d_out, int out_size, void* d_ws, size_t ws_size,
                              hipStream_t stream) {
  (void)in_sizes; (void)n_in; (void)out_size; (void)ws_size;
  const float* x      = (const float*)d_in[0];
  const float* w_attn = (const float*)d_in[1];
  const float* b_attn = (const float*)d_in[2];
  const float* w_proj = (const float*)d_in[3];
  const float* b_proj = (const float*)d_in[4];
  float* out = (float*)d_out;

  char* ws = (char*)d_ws;
  bf16_t* wTa = (bf16_t*)ws;  ws += (size_t)NQKV_ * C_ * 2;          // 6 MB
  bf16_t* wTp = (bf16_t*)ws;  ws += (size_t)C_ * C_ * 2;             // 2 MB
  bf16_t* qb  = (bf16_t*)ws;  ws += (size_t)B_ * H_ * T_ * D_ * 2;   // 8 MB
  bf16_t* kb  = (bf16_t*)ws;  ws += (size_t)B_ * H_ * T_ * D_ * 2;   // 8 MB
  bf16_t* vb  = (bf16_t*)ws;  ws += (size_t)B_ * H_ * T_ * D_ * 2;   // 8 MB
  bf16_t* yb  = (bf16_t*)ws;  ws += (size_t)B_ * T_ * C_ * 2;        // 8 MB
  float2* rtab = (float2*)ws; ws += (size_t)T_ * 32 * sizeof(float2);// 0.5 MB
  // x_bf aliases yb: x_bf is consumed by qkv_gemm (dispatch 4) strictly before
  // attn_fwd (dispatch 5) writes yb. Stream-ordered, deterministic.
  bf16_t* x_bf = yb;

  rope_tab_k<<<dim3(T_ * 32 / 256), 256, 0, stream>>>(rtab);
  transpose_f32_bf16<<<dim3(NQKV_ / 32, C_ / 32), 256, 0, stream>>>(w_attn, wTa, C_, NQKV_);
  transpose_f32_bf16<<<dim3(C_ / 32,   C_ / 32), 256, 0, stream>>>(w_proj, wTp, C_, C_);
  f32_to_bf16_k<<<dim3(M_ * C_ / (256 * 8)), 256, 0, stream>>>(x, x_bf);
  qkv_gemm<<<dim3((M_ / 256) * (NQKV_ / 256)), 512, 0, stream>>>(x_bf, wTa, b_attn, rtab, qb, kb, vb);
  attn_fwd<<<dim3(NQT2 * 32), 512, 0, stream>>>(qb, kb, vb, yb);
  proj_gemm<<<dim3((M_ / 128) * (C_ / 128)), 256, 0, stream>>>(yb, wTp, b_proj, out);
}

// Round 13
// 116.599 us; speedup vs baseline: 2.9657x; 1.0149x over previous
//
#include <hip/hip_runtime.h>
#include <hip/hip_bf16.h>

typedef __bf16 bf16_t;
typedef __bf16 bf16x8 __attribute__((ext_vector_type(8)));
typedef float f32x4 __attribute__((ext_vector_type(4)));
typedef float f32x8v __attribute__((ext_vector_type(8)));

#define B_    2
#define T_    2048
#define C_    1024
#define H_    16
#define D_    64
#define M_    4096      // B*T
#define NQKV_ 3072
#define PLD   72        // attn V^T LDS row stride
#define NQT2  16        // T_/128 q-tiles (attn)
#define GTILE (128 * 64)   // proj GEMM LDS tile (elements)
#define SLOTE 16384        // qkv ring slot elements (A 256x32 + B 256x32)

static __device__ __forceinline__ float  bf2f(bf16_t x) { return (float)x; }
static __device__ __forceinline__ bf16_t f2bf(float x)  { return (bf16_t)x; }

// async global->LDS, 16B per lane; LDS dest is wave-uniform base + lane*16 (HW rule)
typedef const __attribute__((address_space(1))) void gas_void;
typedef __attribute__((address_space(3))) void las_void;
static __device__ __forceinline__ void gld16(const void* g, void* l) {
  __builtin_amdgcn_global_load_lds((gas_void*)g, (las_void*)l, 16, 0, 0);
}

// ---------------- RoPE cos/sin table: [T][32] float2 ----------------
__global__ __launch_bounds__(256) void rope_tab_k(float2* __restrict__ tab) {
  int i = blockIdx.x * 256 + threadIdx.x;      // < T_*32
  int tpos = i >> 5, d = i & 31;
  float fr = exp2f(-(float)d * (13.287712379549449f / 32.0f));  // 10000^(-d/32)
  float ang = (float)tpos * fr;
  tab[i] = make_float2(cosf(ang), sinf(ang));
}

// ---------------- x: fp32 -> bf16 bulk convert ----------------
__global__ __launch_bounds__(256) void f32_to_bf16_k(const float* __restrict__ in,
                                                     bf16_t* __restrict__ out) {
  const int i = (blockIdx.x * 256 + threadIdx.x) * 8;
  f32x8v v = *(const f32x8v*)(in + i);
  bf16x8 h;
#pragma unroll
  for (int j = 0; j < 8; ++j) h[j] = f2bf(v[j]);
  *(bf16x8*)(out + i) = h;
}

// ---------------- transpose + fp32->bf16 (in: R x Ccols fp32 -> out: Ccols x R bf16) ----
__global__ __launch_bounds__(256) void transpose_f32_bf16(const float* __restrict__ in,
                                                          bf16_t* __restrict__ out,
                                                          int R, int Ccols) {
  __shared__ bf16_t tile[32][33];
  int tx = threadIdx.x & 31, ty = threadIdx.x >> 5;
  int c0 = blockIdx.x * 32, r0 = blockIdx.y * 32;
#pragma unroll
  for (int j = 0; j < 4; ++j)
    tile[ty + j * 8][tx] = f2bf(in[(size_t)(r0 + ty + j * 8) * Ccols + c0 + tx]);
  __syncthreads();
#pragma unroll
  for (int j = 0; j < 4; ++j)
    out[(size_t)(c0 + ty + j * 8) * R + r0 + tx] = tile[tx][ty + j * 8];
}

// ------- proj GEMM core (r11-verified): 128x128, dbuf global_load_lds, 2-barrier ----
__device__ __forceinline__ void gemm_core(const bf16_t* __restrict__ A,
                                          const bf16_t* __restrict__ Bt,
                                          int m0, int n0,
                                          bf16_t* sm,
                                          f32x4 acc[4][4]) {
  const int t    = threadIdx.x;
  const int lane = t & 63, w = t >> 6;
  const int wr = (w >> 1) * 64, wc = (w & 1) * 64;
  const int l15 = lane & 15, g4 = lane >> 4;

  const f32x4 z4 = {0.f, 0.f, 0.f, 0.f};
#pragma unroll
  for (int i = 0; i < 4; ++i)
#pragma unroll
    for (int j = 0; j < 4; ++j) acc[i][j] = z4;

  const int srow = w * 32 + (lane >> 3);
  const int sel8 = (lane & 7) * 8;
  const bf16_t* gA = A  + (size_t)(m0 + srow) * C_ + sel8;
  const bf16_t* gB = Bt + (size_t)(n0 + srow) * C_ + sel8;
  const int dOff = (w * 32) * 64;

#pragma unroll
  for (int j = 0; j < 4; ++j) {
    gld16(gA + (size_t)(j * 8) * C_, sm + dOff + j * 8 * 64);
    gld16(gB + (size_t)(j * 8) * C_, sm + GTILE + dOff + j * 8 * 64);
  }
  __syncthreads();

  int cur = 0;
  for (int kt = 0; kt < C_ / 64; ++kt) {
    if (kt + 1 < C_ / 64) {
      const int k0 = (kt + 1) * 64;
      bf16_t* nA = sm + (cur ^ 1) * (2 * GTILE);
      bf16_t* nB = nA + GTILE;
#pragma unroll
      for (int j = 0; j < 4; ++j) {
        gld16(gA + (size_t)(j * 8) * C_ + k0, nA + dOff + j * 8 * 64);
        gld16(gB + (size_t)(j * 8) * C_ + k0, nB + dOff + j * 8 * 64);
      }
    }
    const bf16_t* lA = sm + cur * (2 * GTILE);
    const bf16_t* lB = lA + GTILE;
#pragma unroll
    for (int ks = 0; ks < 2; ++ks) {
      bf16x8 af[4], bfv[4];
#pragma unroll
      for (int mi = 0; mi < 4; ++mi)
        af[mi] = *(const bf16x8*)&lA[(wr + mi * 16 + l15) * 64 + ks * 32 + g4 * 8];
#pragma unroll
      for (int ni = 0; ni < 4; ++ni)
        bfv[ni] = *(const bf16x8*)&lB[(wc + ni * 16 + l15) * 64 + ks * 32 + g4 * 8];
#pragma unroll
      for (int mi = 0; mi < 4; ++mi)
#pragma unroll
        for (int ni = 0; ni < 4; ++ni)
          acc[mi][ni] = __builtin_amdgcn_mfma_f32_16x16x32_bf16(af[mi], bfv[ni],
                                                                acc[mi][ni], 0, 0, 0);
    }
    __syncthreads();
    cur ^= 1;
  }
}

// ---------------- GEMM1: qkv, 256x256 tile, 4-slot LDS ring, counted vmcnt depth-2 ----
// + T2 XOR swizzle (both-sides, rule #21): physical 16B-chunk = logical ^ ((row>>1)&3).
//   Write side via pre-swizzled GLOBAL source (gld_lds dest stays linear);
//   read side applies the same XOR -> fragment reads drop 8-way -> 2-way (free).
__global__ __launch_bounds__(512, 2) void qkv_gemm(const bf16_t* __restrict__ x,
                                                   const bf16_t* __restrict__ wT,
                                                   const float* __restrict__ bias,
                                                   const float2* __restrict__ rtab,
                                                   bf16_t* __restrict__ qo,
                                                   bf16_t* __restrict__ ko,
                                                   bf16_t* __restrict__ vo) {
  __shared__ __align__(16) bf16_t sm[4 * SLOTE];       // 128 KB ring; reused as store stage
  const int t = threadIdx.x;
  const int lane = t & 63, w = t >> 6;                 // 8 waves
  const int l15 = lane & 15, g4 = lane >> 4;
  const int wr = (w >> 2) * 128, wc = (w & 3) * 64;    // 2M x 4N

  const int bid = blockIdx.x;                          // 192 = 16m x 12n tiles
  const int swz = (bid & 7) * 24 + (bid >> 3);         // XCD-chunked, n-major
  const int m0 = (swz & 15) * 256, n0 = (swz >> 4) * 256;

  const f32x4 z4 = {0.f, 0.f, 0.f, 0.f};
  f32x4 acc[8][4];
#pragma unroll
  for (int i = 0; i < 8; ++i)
#pragma unroll
    for (int j = 0; j < 4; ++j) acc[i][j] = z4;

  // staging: wave w covers rows w*32..w*32+31 of both A and B tiles.
  // Source col chunk pre-swizzled: c = (lane&3) ^ ((lane>>3)&3)  [= chunk ^ ((row>>1)&3)]
  const int sr  = (lane >> 2);            // row within 16-row gld16 group
  const int sc8 = (((lane & 3) ^ ((lane >> 3) & 3)) * 8);
  const bf16_t* gA = x  + (size_t)(m0 + w * 32 + sr) * C_ + sc8;
  const bf16_t* gB = wT + (size_t)(n0 + w * 32 + sr) * C_ + sc8;

#define QKV_STAGE(h)                                                            \
  {                                                                             \
    bf16_t* sl = sm + ((h) & 3) * SLOTE;                                        \
    const size_t kofs = (size_t)(h) * 32;                                       \
    gld16(gA + kofs,            sl + (w * 32) * 32);                            \
    gld16(gA + 16 * C_ + kofs,  sl + (w * 32 + 16) * 32);                       \
    gld16(gB + kofs,            sl + 8192 + (w * 32) * 32);                     \
    gld16(gB + 16 * C_ + kofs,  sl + 8192 + (w * 32 + 16) * 32);                \
  }

  QKV_STAGE(0);
  QKV_STAGE(1);

  const int csw = (l15 >> 1) & 3;         // read-side swizzle bits (row bits 1..2)

  for (int h = 0; h < 32; ++h) {
    if (h < 31) asm volatile("s_waitcnt vmcnt(4)" ::: "memory");
    else        asm volatile("s_waitcnt vmcnt(0)" ::: "memory");
    __builtin_amdgcn_sched_barrier(0);
    __builtin_amdgcn_s_barrier();
    __builtin_amdgcn_sched_barrier(0);
    if (h + 2 < 32) QKV_STAGE(h + 2);

    const bf16_t* sl = sm + (h & 3) * SLOTE;
    bf16x8 af[8], bfv[4];
#pragma unroll
    for (int mi = 0; mi < 8; ++mi)
      af[mi] = *(const bf16x8*)&sl[(wr + mi * 16 + l15) * 32 + ((g4 ^ csw) * 8)];
#pragma unroll
    for (int ni = 0; ni < 4; ++ni)
      bfv[ni] = *(const bf16x8*)&sl[8192 + (wc + ni * 16 + l15) * 32 + ((g4 ^ csw) * 8)];
#pragma unroll
    for (int mi = 0; mi < 8; ++mi)
#pragma unroll
      for (int ni = 0; ni < 4; ++ni)
        acc[mi][ni] = __builtin_amdgcn_mfma_f32_16x16x32_bf16(af[mi], bfv[ni],
                                                              acc[mi][ni], 0, 0, 0);
  }
#undef QKV_STAGE

  __syncthreads();                       // all compute done; reuse sm as store stage
  bf16_t* stg = sm + w * 8192;           // per-wave 128x64 stage

  const int ng  = n0 + wc;               // 64-aligned -> single (sel, head) per wave
  const int sel = ng >> 10;
  const int h2  = (ng & 1023) >> 6;

  if (sel < 2) {
    const float qs = (sel == 0) ? 0.125f * 1.4426950408889634f : 1.0f;
#pragma unroll
    for (int mi = 0; mi < 8; ++mi) {
#pragma unroll
      for (int ni = 0; ni < 2; ++ni) {
        const int d1 = ni * 16 + l15;
        const float b1 = bias[ng + d1];
        const float b2 = bias[ng + d1 + 32];
#pragma unroll
        for (int r = 0; r < 4; ++r) {
          const int lrow = mi * 16 + g4 * 4 + r;
          const int tpos = (m0 + wr + lrow) & (T_ - 1);
          const float2 cs = rtab[tpos * 32 + d1];
          const float x1 = acc[mi][ni][r]     + b1;
          const float x2 = acc[mi][ni + 2][r] + b2;
          stg[lrow * 64 + d1]      = f2bf((x1 * cs.x - x2 * cs.y) * qs);
          stg[lrow * 64 + d1 + 32] = f2bf((x1 * cs.y + x2 * cs.x) * qs);
        }
      }
    }
  } else {
#pragma unroll
    for (int mi = 0; mi < 8; ++mi)
#pragma unroll
      for (int ni = 0; ni < 4; ++ni) {
        const int d = ni * 16 + l15;
        const float b1 = bias[ng + d];
#pragma unroll
        for (int r = 0; r < 4; ++r)
          stg[(mi * 16 + g4 * 4 + r) * 64 + d] = f2bf(acc[mi][ni][r] + b1);
      }
  }

  bf16_t* outp = (sel == 0) ? qo : (sel == 1 ? ko : vo);
  const int a  = lane >> 3;
  const int b8 = (lane & 7) * 8;
#pragma unroll
  for (int p = 0; p < 16; ++p) {
    const int lrow = p * 8 + a;
    const int row  = m0 + wr + lrow;
    const int tpos = row & (T_ - 1);
    const int bb   = row >> 11;
    uint4 val = *(const uint4*)&stg[lrow * 64 + b8];
    *(uint4*)(outp + ((size_t)(bb * H_ + h2) * T_ + tpos) * D_ + b8) = val;
  }
}

// ---- flash attention, swapped-QK: 128 q-rows (8 waves x 16), KBLK=64 ----
// (unchanged from round 10 — verified)
__global__ __launch_bounds__(512) void attn_fwd(const bf16_t* __restrict__ q,
                                                const bf16_t* __restrict__ k,
                                                const bf16_t* __restrict__ v,
                                                bf16_t* __restrict__ y) {
  __shared__ __align__(16) bf16_t Ks[64 * 64];         // K rows [key][d], XOR-swizzled
  __shared__ __align__(16) bf16_t Vt[64 * PLD];        // V^T [d][slot(kappa,d)]
  const int t = threadIdx.x;
  const int lane = t & 63, w = t >> 6;                 // w: 0..7
  const int l15 = lane & 15, g4 = lane >> 4;

  const int f   = blockIdx.x;
  const int idx = f & 255;
  const int bh  = idx & 31;
  const int p   = idx >> 5;                            // 0..7
  const int qt  = (f >> 8) ? (15 - p) : p;             // bijective over 0..15
  const int qb  = qt * 128;
  const size_t hb = (size_t)bh * T_ * D_;

  const int qrow = qb + w * 16 + l15;
  bf16x8 qf[2];
  qf[0] = *(const bf16x8*)(q + hb + (size_t)qrow * D_ + g4 * 8);
  qf[1] = *(const bf16x8*)(q + hb + (size_t)qrow * D_ + 32 + g4 * 8);

  const f32x4 z4 = {0.f, 0.f, 0.f, 0.f};
  f32x4 o[4];
#pragma unroll
  for (int i = 0; i < 4; ++i) o[i] = z4;
  float mx = -1e30f, L = 0.f;

  const int skk = t >> 3;                  // key row 0..63 (full tile, one pass)
  const int sd0 = (t & 7) * 8;
  const int u   = t & 7;                   // = (d>>3)&7 for all this thread's d rows
  const int ksw = sd0 ^ ((skk & 7) * 8);   // Ks swizzled col
  // kappa slot for key=skk: slot = 32*c1 + 8*g + 4*c0 + r
  const int slot = ((skk >> 5) & 1) * 32 + ((skk >> 2) & 3) * 8 + ((skk >> 4) & 1) * 4 + (skk & 3);
  const int pos  = (((slot >> 3) ^ u) << 3) | (slot & 7);
  const int rowb = qb + w * 16 + g4 * 4;

  const int ntiles = 2 * qt + 2;

  // preload tile 0
  uint4 kv = *(const uint4*)(k + hb + (size_t)skk * D_ + sd0);
  uint4 vv = *(const uint4*)(v + hb + (size_t)skk * D_ + sd0);

  for (int it = 0; it < ntiles; ++it) {
    const int kb = it * 64;
    __syncthreads();
    *(uint4*)&Ks[skk * 64 + ksw] = kv;
    {
      const bf16_t* vb = (const bf16_t*)&vv;
#pragma unroll
      for (int i = 0; i < 8; ++i)
        Vt[(sd0 + i) * PLD + pos] = vb[i];
    }
    __syncthreads();

    if (it + 1 < ntiles) {
      const size_t nb = hb + (size_t)(kb + 64 + skk) * D_ + sd0;
      kv = *(const uint4*)(k + nb);
      vv = *(const uint4*)(v + nb);
    }

    const bool last = (it == ntiles - 1);
    if (last && w < 4) continue;          // rows < kb: fully masked tile (barriers stay aligned)

    // ---- QK^T swapped: s[c][r] = S[key=kb+c*16+g4*4+r][q=qrow] ----
    f32x4 s[4];
#pragma unroll
    for (int c = 0; c < 4; ++c) s[c] = z4;
#pragma unroll
    for (int ks = 0; ks < 2; ++ks)
#pragma unroll
      for (int c = 0; c < 4; ++c) {
        const int kr = c * 16 + l15;
        bf16x8 kf = *(const bf16x8*)&Ks[kr * 64 + ((ks * 32 + g4 * 8) ^ ((kr & 7) * 8))];
        s[c] = __builtin_amdgcn_mfma_f32_16x16x32_bf16(kf, qf[ks], s[c], 0, 0, 0);
      }

    // ---- causal mask: only the two diagonal-adjacent tiles can violate ----
    if (last || (it == ntiles - 2 && w < 4)) {
#pragma unroll
      for (int c = 0; c < 4; ++c)
#pragma unroll
        for (int r = 0; r < 4; ++r)
          if (kb + c * 16 + g4 * 4 + r > qrow) s[c][r] = -1e30f;
    }

    // ---- online softmax (exp2 domain; defer-max THR=8) ----
    float tm = -1e30f;
#pragma unroll
    for (int c = 0; c < 4; ++c)
#pragma unroll
      for (int r = 0; r < 4; ++r) tm = fmaxf(tm, s[c][r]);
    tm = fmaxf(tm, __shfl_xor(tm, 16));
    tm = fmaxf(tm, __shfl_xor(tm, 32));
    if (!__all(tm - mx <= 8.0f)) {        // wave-uniform; rare after warm-up
      const float mnew = fmaxf(mx, tm);
      const float sc = exp2f(mx - mnew);  // first tile: exp2(-inf)=0 zeroes L,o
      L *= sc;
      float scr[4];
#pragma unroll
      for (int r = 0; r < 4; ++r)
        scr[r] = __shfl(sc, (lane & 48) | (g4 * 4 + r));
#pragma unroll
      for (int nf = 0; nf < 4; ++nf)
#pragma unroll
        for (int r = 0; r < 4; ++r) o[nf][r] *= scr[r];
      mx = mnew;
    }
    float rs = 0.f;
#pragma unroll
    for (int c = 0; c < 4; ++c)
#pragma unroll
      for (int r = 0; r < 4; ++r) {
        s[c][r] = exp2f(s[c][r] - mx);    // bounded by 2^8
        rs += s[c][r];
      }
    rs += __shfl_xor(rs, 16);
    rs += __shfl_xor(rs, 32);
    L += rs;

    // ---- P -> PV A-fragments, in-lane (kappa ordering) ----
    bf16x8 ap0, ap1;
#pragma unroll
    for (int r = 0; r < 4; ++r) {
      ap0[r]     = f2bf(s[0][r]);
      ap0[4 + r] = f2bf(s[1][r]);
      ap1[r]     = f2bf(s[2][r]);
      ap1[4 + r] = f2bf(s[3][r]);
    }

    // ---- PV: o[q][d] += P V, keys in kappa order on both operands ----
#pragma unroll
    for (int nf = 0; nf < 4; ++nf) {
      const int d  = nf * 16 + l15;
      const int h3 = (2 * nf + (l15 >> 3)) & 7;   // (d>>3)&7
      bf16x8 vf0 = *(const bf16x8*)&Vt[d * PLD + ((g4 ^ h3) << 3)];
      bf16x8 vf1 = *(const bf16x8*)&Vt[d * PLD + (((g4 + 4) ^ h3) << 3)];
      o[nf] = __builtin_amdgcn_mfma_f32_16x16x32_bf16(ap0, vf0, o[nf], 0, 0, 0);
      o[nf] = __builtin_amdgcn_mfma_f32_16x16x32_bf16(ap1, vf1, o[nf], 0, 0, 0);
    }
  }

  const int bb = bh / H_, hh = bh % H_;
  float il[4];
#pragma unroll
  for (int r = 0; r < 4; ++r)
    il[r] = 1.0f / __shfl(L, (lane & 48) | (g4 * 4 + r));
#pragma unroll
  for (int nf = 0; nf < 4; ++nf)
#pragma unroll
    for (int r = 0; r < 4; ++r) {
      const int row = rowb + r;
      y[(size_t)(bb * T_ + row) * C_ + hh * D_ + nf * 16 + l15] = f2bf(o[nf][r] * il[r]);
    }
}

// ---------------- GEMM2: out = y @ w_proj + b_proj (fp32 out) ----------------
// 1D grid + XCD swizzle (256 = 8 XCD x 32; one n-tile per XCD)
__global__ __launch_bounds__(256) void proj_gemm(const bf16_t* __restrict__ yin,
                                                 const bf16_t* __restrict__ wT,
                                                 const float* __restrict__ bias,
                                                 float* __restrict__ out) {
  __shared__ __align__(16) bf16_t smem[4 * GTILE];
  f32x4 acc[4][4];
  const int bid = blockIdx.x;
  const int swz = (bid & 7) * 32 + (bid >> 3);
  const int m0 = (swz & 31) * 128, n0 = (swz >> 5) * 128;
  gemm_core(yin, wT, m0, n0, smem, acc);

  const int t = threadIdx.x;
  const int lane = t & 63, w = t >> 6;
  const int wr = (w >> 1) * 64, wc = (w & 1) * 64;
  const int l15 = lane & 15, g4 = lane >> 4;
  const int ng = n0 + wc;
#pragma unroll
  for (int mi = 0; mi < 4; ++mi) {
    const int rowb = m0 + wr + mi * 16 + g4 * 4;
#pragma unroll
    for (int ni = 0; ni < 4; ++ni) {
      const int n = ng + ni * 16 + l15;
      const float b1 = bias[n];
#pragma unroll
      for (int r = 0; r < 4; ++r)
        out[(size_t)(rowb + r) * C_ + n] = acc[mi][ni][r] + b1;
    }
  }
}

// ---------------- launch ----------------
extern "C" void kernel_launch(void* const* d_in, const int* in_sizes, int n_in,
                              void* d_out, int out_size, void* d_ws, size_t ws_size,
                              hipStream_t stream) {
  (void)in_sizes; (void)n_in; (void)out_size; (void)ws_size;
  const float* x      = (const float*)d_in[0];
  const float* w_attn = (const float*)d_in[1];
  const float* b_attn = (const float*)d_in[2];
  const float* w_proj = (const float*)d_in[3];
  const float* b_proj = (const float*)d_in[4];
  float* out = (float*)d_out;

  char* ws = (char*)d_ws;
  bf16_t* wTa = (bf16_t*)ws;  ws += (size_t)NQKV_ * C_ * 2;          // 6 MB
  bf16_t* wTp = (bf16_t*)ws;  ws += (size_t)C_ * C_ * 2;             // 2 MB
  bf16_t* qb  = (bf16_t*)ws;  ws += (size_t)B_ * H_ * T_ * D_ * 2;   // 8 MB
  bf16_t* kb  = (bf16_t*)ws;  ws += (size_t)B_ * H_ * T_ * D_ * 2;   // 8 MB
  bf16_t* vb  = (bf16_t*)ws;  ws += (size_t)B_ * H_ * T_ * D_ * 2;   // 8 MB
  bf16_t* yb  = (bf16_t*)ws;  ws += (size_t)B_ * T_ * C_ * 2;        // 8 MB
  float2* rtab = (float2*)ws; ws += (size_t)T_ * 32 * sizeof(float2);// 0.5 MB
  // x_bf aliases yb: x_bf is consumed by qkv_gemm (dispatch 4) strictly before
  // attn_fwd (dispatch 5) writes yb. Stream-ordered, deterministic.
  bf16_t* x_bf = yb;

  rope_tab_k<<<dim3(T_ * 32 / 256), 256, 0, stream>>>(rtab);
  transpose_f32_bf16<<<dim3(NQKV_ / 32, C_ / 32), 256, 0, stream>>>(w_attn, wTa, C_, NQKV_);
  transpose_f32_bf16<<<dim3(C_ / 32,   C_ / 32), 256, 0, stream>>>(w_proj, wTp, C_, C_);
  f32_to_bf16_k<<<dim3(M_ * C_ / (256 * 8)), 256, 0, stream>>>(x, x_bf);
  qkv_gemm<<<dim3((M_ / 256) * (NQKV_ / 256)), 512, 0, stream>>>(x_bf, wTa, b_attn, rtab, qb, kb, vb);
  attn_fwd<<<dim3(NQT2 * 32), 512, 0, stream>>>(qb, kb, vb, yb);
  proj_gemm<<<dim3((M_ / 128) * (C_ / 128)), 256, 0, stream>>>(yb, wTp, b_proj, out);
}